// Round 1
// baseline (1884.679 us; speedup 1.0000x reference)
//
#include <hip/hip_runtime.h>

#define C_ 256
#define G_ 4

// ---------------------------------------------------------------- prep ----
__global__ void k_prep(const float* __restrict__ off_w, float* __restrict__ wpad,
                       float* __restrict__ zeros) {
    int i = blockIdx.x * 256 + threadIdx.x;
    const int NW = 108 * 64 * 12;
    if (i < NW) {
        int r = i / 12, t = i % 12;
        wpad[i] = (t < 9) ? off_w[r * 9 + t] : 0.f;
    }
    int z = i - NW;
    if (z >= 0 && z < 8064) zeros[z] = 0.f;
}

// ------------------------------------------------------------ transpose ----
// NCHW -> NHWC, 32x32 (c,w) tiles through LDS
__global__ __launch_bounds__(256) void k_transpose(const float* __restrict__ x,
                                                   float* __restrict__ xt, int H, int W) {
    __shared__ float tile[32][33];
    int nh = blockIdx.x;
    int n = nh / H, h = nh % H;
    int w0 = blockIdx.y * 32, c0 = blockIdx.z * 32;
    int tid = threadIdx.x;
    int i = tid / 32, j = tid % 32;
#pragma unroll
    for (int r = 0; r < 4; r++) {
        int c = c0 + i + r * 8;
        int w = w0 + j;
        tile[i + r * 8][j] = (w < W) ? x[((size_t)(n * C_ + c) * H + h) * W + w] : 0.f;
    }
    __syncthreads();
    int wj = tid / 32, ci = tid % 32;
#pragma unroll
    for (int r = 0; r < 4; r++) {
        int w = w0 + wj + r * 8;
        if (w < W) xt[((size_t)(n * H + h) * W + w) * C_ + c0 + ci] = tile[ci][wj + r * 8];
    }
}

// -------------------------------------------------------- depthwise+SiLU ----
__global__ __launch_bounds__(256) void k_dw_silu(const float* __restrict__ xt,
                                                 const float* __restrict__ wd,
                                                 const float* __restrict__ sc,
                                                 const float* __restrict__ bi,
                                                 float* __restrict__ out, int H, int W) {
    int pix = blockIdx.x;
    int w = pix % W, h = (pix / W) % H, n = pix / (W * H);
    int c = threadIdx.x;
    float acc = 0.f;
#pragma unroll
    for (int ty = 0; ty < 3; ty++) {
        int hh = h + ty - 1;
        if (hh < 0 || hh >= H) continue;
#pragma unroll
        for (int tx = 0; tx < 3; tx++) {
            int ww = w + tx - 1;
            if (ww < 0 || ww >= W) continue;
            acc += wd[c * 9 + ty * 3 + tx] * xt[((size_t)(n * H + hh) * W + ww) * C_ + c];
        }
    }
    float y = acc * sc[c] + bi[c];
    out[(size_t)pix * C_ + c] = y / (1.f + __expf(-y));
}

// ------------------------------------------------- grouped offset/mask conv ----
// 256 -> 108 channels, 3x3, groups=4. Block = 128 threads, TH x TW output tile.
// For STRIDE=2 we directly compute only even src pixels (the [::2,::2] subsample).
template <int STRIDE, bool SOFTMAX, int TH, int TW>
__global__ __launch_bounds__(128) void k_offmask(const float* __restrict__ dw,
                                                 const float* __restrict__ wpad,
                                                 const float* __restrict__ bias,
                                                 float* __restrict__ off,
                                                 float* __restrict__ msk,
                                                 int Hs, int Ws, int Ho, int Wo) {
    constexpr int SR = STRIDE * (TH - 1) + 3;
    constexpr int SC = STRIDE * (TW - 1) + 3;
    constexpr int NV = SR * SC;
    constexpr int B4 = (NV + 3) / 4;
    constexpr int PITCH = ((B4 % 2) == 1) ? B4 * 4 : B4 * 4 + 4;  // odd # of float4 -> no bank cycle
    constexpr int TP = TH * TW;
    __shared__ float patch[C_ * PITCH];
    int tid = threadIdx.x;
    int n = blockIdx.x;
    int ho0 = blockIdx.y * TH, wo0 = blockIdx.z * TW;
    int hs0 = ho0 * STRIDE - 1, ws0 = wo0 * STRIDE - 1;
    // stage patch (c fastest -> coalesced)
    for (int flat = tid; flat < NV * C_; flat += 128) {
        int c = flat & (C_ - 1);
        int rc = flat >> 8;
        int r = rc / SC, col = rc % SC;
        int hh = hs0 + r, ww = ws0 + col;
        float v = 0.f;
        if (hh >= 0 && hh < Hs && ww >= 0 && ww < Ws)
            v = dw[((size_t)(n * Hs + hh) * Ws + ww) * C_ + c];
        patch[c * PITCH + rc] = v;
    }
    __syncthreads();
    float acc[TP];
    int oc = tid;
    if (oc < 108) {
        float bb = bias[oc];
#pragma unroll
        for (int p = 0; p < TP; p++) acc[p] = bb;
        int icb = (oc / 27) * 64;
        for (int ic = 0; ic < 64; ic++) {
            float pv[B4 * 4];
            const float4* src = (const float4*)(patch + (icb + ic) * PITCH);
#pragma unroll
            for (int v = 0; v < B4; v++) ((float4*)pv)[v] = src[v];
            const float4* wsrc = (const float4*)(wpad + (size_t)(oc * 64 + ic) * 12);
            float4 w0 = wsrc[0], w1 = wsrc[1], w2 = wsrc[2];
            float wt[9] = {w0.x, w0.y, w0.z, w0.w, w1.x, w1.y, w1.z, w1.w, w2.x};
#pragma unroll
            for (int pr = 0; pr < TH; pr++)
#pragma unroll
                for (int pc = 0; pc < TW; pc++)
#pragma unroll
                    for (int ty = 0; ty < 3; ty++)
#pragma unroll
                        for (int tx = 0; tx < 3; tx++)
                            acc[pr * TW + pc] +=
                                wt[ty * 3 + tx] * pv[(pr * STRIDE + ty) * SC + pc * STRIDE + tx];
        }
    }
    __syncthreads();
    float* omv = patch;  // overlay (patch no longer needed)
    if (oc < 108) {
#pragma unroll
        for (int p = 0; p < TP; p++) omv[p * 112 + oc] = acc[p];
    }
    __syncthreads();
    // offsets: channels 0..71 map directly to (g,k,comp)
    for (int flat = tid; flat < TP * 72; flat += 128) {
        int p = flat / 72, ch = flat % 72;
        int ho = ho0 + p / TW, wo = wo0 + p % TW;
        off[((size_t)(n * Ho + ho) * Wo + wo) * 72 + ch] = omv[p * 112 + ch];
    }
    if (SOFTMAX) {
        for (int flat = tid; flat < TP * G_; flat += 128) {
            int p = flat / G_, g = flat % G_;
            int ho = ho0 + p / TW, wo = wo0 + p % TW;
            float mx = -1e30f;
#pragma unroll
            for (int k = 0; k < 9; k++) mx = fmaxf(mx, omv[p * 112 + 72 + g * 9 + k]);
            float e[9], ssum = 0.f;
#pragma unroll
            for (int k = 0; k < 9; k++) {
                e[k] = __expf(omv[p * 112 + 72 + g * 9 + k] - mx);
                ssum += e[k];
            }
            float inv = 1.f / ssum;
            float* mp = msk + ((size_t)(n * Ho + ho) * Wo + wo) * 36 + g * 9;
#pragma unroll
            for (int k = 0; k < 9; k++) mp[k] = e[k] * inv;
        }
    } else {
        for (int flat = tid; flat < TP * 36; flat += 128) {
            int p = flat / 36, ch = flat % 36;
            int ho = ho0 + p / TW, wo = wo0 + p % TW;
            float v = omv[p * 112 + 72 + ch];
            msk[((size_t)(n * Ho + ho) * Wo + wo) * 36 + ch] = 1.f / (1.f + __expf(-v));
        }
    }
}

// ------------------------------------------------------------- DCNv3 sample ----
// block = 256 threads = 4 waves, wave g handles group g (64 ch/lane), 4 pixels/block.
// Fused GroupNorm sum/sumsq accumulation (16 gn-groups of 16 ch).
__global__ __launch_bounds__(256) void k_sample(const float* __restrict__ xt,
                                                const float* __restrict__ off,
                                                const float* __restrict__ msk,
                                                float* __restrict__ raw,
                                                float* __restrict__ stats,
                                                int Hs, int Ws, int Ho, int Wo, int stride) {
    int tid = threadIdx.x;
    int g = tid >> 6, lane = tid & 63;
    int pix0 = blockIdx.x * 4;
    int n = pix0 / (Ho * Wo);
    __shared__ float som[4][108];
    for (int flat = tid; flat < 432; flat += 256) {
        int p = flat / 108, ch = flat % 108;
        size_t pix = pix0 + p;
        som[p][ch] = (ch < 72) ? off[pix * 72 + ch] : msk[pix * 36 + (ch - 72)];
    }
    __syncthreads();
    float gs = 0.f, gss = 0.f;
    for (int p = 0; p < 4; p++) {
        int pix = pix0 + p;
        int wo = pix % Wo, ho = (pix / Wo) % Ho;
        float acc = 0.f;
#pragma unroll
        for (int k = 0; k < 9; k++) {
            float oy = som[p][g * 18 + 2 * k], ox = som[p][g * 18 + 2 * k + 1];
            float m = som[p][72 + g * 9 + k];
            float py = (float)(ho * stride + k / 3 - 1) + oy;
            float px = (float)(wo * stride + k % 3 - 1) + ox;
            float y0f = floorf(py), x0f = floorf(px);
            int y0 = (int)y0f, x0 = (int)x0f;
            float wy = py - y0f, wx = px - x0f;
#pragma unroll
            for (int dy = 0; dy < 2; dy++) {
                int yi = y0 + dy;
                if (yi < 0 || yi >= Hs) continue;
                float fy = dy ? wy : 1.f - wy;
#pragma unroll
                for (int dx = 0; dx < 2; dx++) {
                    int xi = x0 + dx;
                    if (xi < 0 || xi >= Ws) continue;
                    float w = fy * (dx ? wx : 1.f - wx) * m;
                    acc += w * xt[((size_t)(n * Hs + yi) * Ws + xi) * C_ + (g << 6) + lane];
                }
            }
        }
        raw[(size_t)pix * C_ + (g << 6) + lane] = acc;
        gs += acc;
        gss += acc * acc;
    }
#pragma unroll
    for (int o = 8; o; o >>= 1) {
        gs += __shfl_down(gs, o, 16);
        gss += __shfl_down(gss, o, 16);
    }
    if ((lane & 15) == 0) {
        int gg = (g << 2) + (lane >> 4);
        atomicAdd(&stats[(n * 16 + gg) * 2 + 0], gs);
        atomicAdd(&stats[(n * 16 + gg) * 2 + 1], gss);
    }
}

// ----------------------------------------- GN affine (+bilinear up) + ch-means ----
__global__ __launch_bounds__(256) void k_gnup(const float* __restrict__ raw,
                                              float* __restrict__ fin,
                                              const float* __restrict__ stats,
                                              float* __restrict__ cmean,
                                              const float* __restrict__ gamma,
                                              const float* __restrict__ beta,
                                              int Hr, int Wr, int Hf, int Wf) {
    int HWf = Hf * Wf;
    int spn = (HWf + 63) >> 6;
    int n = blockIdx.x / spn;
    int p0 = (blockIdx.x % spn) << 6;
    int c = threadIdx.x;
    int gg = c >> 4;
    float cnt = 16.f * Hr * Wr;
    float s1 = stats[(n * 16 + gg) * 2], s2 = stats[(n * 16 + gg) * 2 + 1];
    float mu = s1 / cnt;
    float var = s2 / cnt - mu * mu;
    float rs = rsqrtf(var + 1e-5f);
    float ga = gamma[c] * rs;
    float be = beta[c] - mu * ga;
    bool up = (Hf != Hr);
    float sys = up ? (float)((double)(Hr - 1) / (double)(Hf - 1)) : 0.f;
    float sxs = up ? (float)((double)(Wr - 1) / (double)(Wf - 1)) : 0.f;
    float csum = 0.f;
    for (int i = 0; i < 64; i++) {
        int p = p0 + i;
        if (p >= HWf) break;
        float v;
        if (up) {
            int ho = p / Wf, wo = p % Wf;
            float sy = ho * sys, sx = wo * sxs;
            int y0 = (int)sy, x0 = (int)sx;
            float fy = sy - y0, fx = sx - x0;
            int y1 = min(y0 + 1, Hr - 1), x1 = min(x0 + 1, Wr - 1);
            float v00 = raw[((size_t)(n * Hr + y0) * Wr + x0) * C_ + c];
            float v01 = raw[((size_t)(n * Hr + y0) * Wr + x1) * C_ + c];
            float v10 = raw[((size_t)(n * Hr + y1) * Wr + x0) * C_ + c];
            float v11 = raw[((size_t)(n * Hr + y1) * Wr + x1) * C_ + c];
            float ta = v00 * (1.f - fy) + v10 * fy;
            float tb = v01 * (1.f - fy) + v11 * fy;
            v = ta * (1.f - fx) + tb * fx;
        } else {
            v = raw[((size_t)n * HWf + p) * C_ + c];
        }
        float y = v * ga + be;
        fin[((size_t)n * HWf + p) * C_ + c] = y;
        csum += y;
    }
    atomicAdd(&cmean[n * C_ + c], csum);
}

// ---------------------------------- scale-attn combine + DyReLU + NCHW store ----
__global__ __launch_bounds__(256) void k_out(const float* __restrict__ fA,
                                             const float* __restrict__ fB,
                                             const float* __restrict__ fC,
                                             const float* __restrict__ cmA,
                                             const float* __restrict__ cmB,
                                             const float* __restrict__ cmC,
                                             int nf, float inv_nl,
                                             const float* __restrict__ sa_w,
                                             const float* __restrict__ sa_b,
                                             const float* __restrict__ fc1_w,
                                             const float* __restrict__ fc1_b,
                                             const float* __restrict__ fc2_w,
                                             const float* __restrict__ fc2_b,
                                             float* __restrict__ out, int H, int W) {
    int HW = H * W;
    int spn = (HW + 63) >> 6;
    int n = blockIdx.x / spn;
    int p0 = (blockIdx.x % spn) << 6;
    int c = threadIdx.x;
    __shared__ float red[256];
    __shared__ float meanv[256];
    __shared__ float hv[64];
    __shared__ float sa_a[3];
    __shared__ float ot[16 * 257];
    float inv_hw = 1.f / HW;
    const float* cms[3] = {cmA, cmB, cmC};
    float cm[3] = {0.f, 0.f, 0.f}, a[3] = {0.f, 0.f, 0.f};
    for (int f = 0; f < nf; f++) {
        cm[f] = cms[f][n * C_ + c] * inv_hw;
        red[c] = sa_w[c] * cm[f];
        __syncthreads();
        for (int s = 128; s; s >>= 1) {
            if (c < s) red[c] += red[c + s];
            __syncthreads();
        }
        if (c == 0) {
            float t = fmaxf(red[0] + sa_b[0], 0.f);
            sa_a[f] = fminf(fmaxf((t + 3.f) * (1.f / 6.f), 0.f), 1.f);
        }
        __syncthreads();
        a[f] = sa_a[f];
    }
    float mv = 0.f;
    for (int f = 0; f < nf; f++) mv += a[f] * cm[f];
    mv *= inv_nl;
    meanv[c] = mv;
    __syncthreads();
    int j = c & 63;
    float ha = fc1_b[j];
    for (int k = 0; k < 256; k++) ha += fc1_w[j * 256 + k] * meanv[k];
    if (c < 64) hv[c] = fmaxf(ha, 0.f);
    __syncthreads();
    float zz[4];
#pragma unroll
    for (int i = 0; i < 4; i++) {
        float z = fc2_b[i * 256 + c];
        for (int k = 0; k < 64; k++) z += fc2_w[(size_t)(i * 256 + c) * 64 + k] * hv[k];
        zz[i] = fminf(fmaxf(z + 3.f, 0.f), 6.f) * (1.f / 6.f);
    }
    float a1 = (zz[0] - 0.5f) * 2.f + 1.f;
    float b1 = zz[1] - 0.5f;
    float a2 = (zz[2] - 0.5f) * 2.f;
    float b2 = zz[3] - 0.5f;
    for (int chk = 0; chk < 4; chk++) {
        __syncthreads();
        for (int i = 0; i < 16; i++) {
            int p = p0 + chk * 16 + i;
            if (p >= HW) continue;
            float fv = a[0] * fA[((size_t)n * HW + p) * C_ + c];
            if (nf > 1) fv += a[1] * fB[((size_t)n * HW + p) * C_ + c];
            if (nf > 2) fv += a[2] * fC[((size_t)n * HW + p) * C_ + c];
            fv *= inv_nl;
            ot[i * 257 + c] = fmaxf(fv * a1 + b1, fv * a2 + b2);
        }
        __syncthreads();
        int px = c & 15, cr0 = c >> 4;
        for (int pass = 0; pass < 16; pass++) {
            int cc = pass * 16 + cr0;
            int p = p0 + chk * 16 + px;
            if (p < HW) out[((size_t)n * C_ + cc) * HW + p] = ot[px * 257 + cc];
        }
    }
}

// --------------------------------------------------------------------- host ----
extern "C" void kernel_launch(void* const* d_in, const int* in_sizes, int n_in,
                              void* d_out, int out_size, void* d_ws, size_t ws_size,
                              hipStream_t stream) {
    (void)in_sizes; (void)n_in; (void)out_size; (void)ws_size;
    const float* x0 = (const float*)d_in[0];
    const float* x1 = (const float*)d_in[1];
    const float* x2 = (const float*)d_in[2];
    const float* dw_w_h = (const float*)d_in[3];
    const float* dw_s_h = (const float*)d_in[4];
    const float* dw_b_h = (const float*)d_in[5];
    const float* dw_w_m = (const float*)d_in[6];
    const float* dw_s_m = (const float*)d_in[7];
    const float* dw_b_m = (const float*)d_in[8];
    const float* dw_w_l = (const float*)d_in[9];
    const float* dw_s_l = (const float*)d_in[10];
    const float* dw_b_l = (const float*)d_in[11];
    const float* off_w = (const float*)d_in[12];
    const float* off_b = (const float*)d_in[13];
    const float* gn_g_h = (const float*)d_in[14];
    const float* gn_b_h = (const float*)d_in[15];
    const float* gn_g_m = (const float*)d_in[16];
    const float* gn_b_m = (const float*)d_in[17];
    const float* gn_g_l = (const float*)d_in[18];
    const float* gn_b_l = (const float*)d_in[19];
    const float* sa_w = (const float*)d_in[20];
    const float* sa_b = (const float*)d_in[21];
    const float* fc1_w = (const float*)d_in[22];
    const float* fc1_b = (const float*)d_in[23];
    const float* fc2_w = (const float*)d_in[24];
    const float* fc2_b = (const float*)d_in[25];

    float* ws = (float*)d_ws;
    float* XT0 = ws + 0;              // 4*80*80*256
    float* XT1 = ws + 6553600;        // 4*40*40*256
    float* XT2 = ws + 8192000;        // 4*20*20*256
    float* SH = ws + 8601600;         // dw / raw shared, 6553600
    float* OFF = ws + 15155200;       // 1843200
    float* MSK = ws + 16998400;       // 921600
    float* FINA = ws + 17920000;      // 6553600
    float* FINB = ws + 24473600;      // 6553600
    float* FINC = ws + 31027200;      // 1638400
    float* WPAD = ws + 32665600;      // 82944
    float* STATS = ws + 32748544;     // 7*128
    float* CMEAN = ws + 32749440;     // 7*1024

    float* out0 = (float*)d_out;
    float* out1 = out0 + 6553600;
    float* out2 = out0 + 8192000;

    k_prep<<<(108 * 64 * 12 + 8064 + 255) / 256, 256, 0, stream>>>(off_w, WPAD, STATS);

    k_transpose<<<dim3(4 * 80, 3, 8), 256, 0, stream>>>(x0, XT0, 80, 80);
    k_transpose<<<dim3(4 * 40, 2, 8), 256, 0, stream>>>(x1, XT1, 40, 40);
    k_transpose<<<dim3(4 * 20, 1, 8), 256, 0, stream>>>(x2, XT2, 20, 20);

    auto run_feat = [&](const float* xt, int Hs, int Ws, int stride, bool softmax,
                        const float* dww, const float* dws, const float* dwb,
                        const float* gng, const float* gnb, int slot, float* fin, int Hf,
                        int Wf) {
        int Ho = Hs / stride, Wo = Ws / stride;
        k_dw_silu<<<4 * Hs * Ws, 256, 0, stream>>>(xt, dww, dws, dwb, SH, Hs, Ws);
        if (stride == 1) {
            if (softmax)
                k_offmask<1, true, 4, 4><<<dim3(4, Ho / 4, Wo / 4), 128, 0, stream>>>(
                    SH, WPAD, off_b, OFF, MSK, Hs, Ws, Ho, Wo);
            else
                k_offmask<1, false, 4, 4><<<dim3(4, Ho / 4, Wo / 4), 128, 0, stream>>>(
                    SH, WPAD, off_b, OFF, MSK, Hs, Ws, Ho, Wo);
        } else {
            k_offmask<2, true, 2, 4><<<dim3(4, Ho / 2, Wo / 4), 128, 0, stream>>>(
                SH, WPAD, off_b, OFF, MSK, Hs, Ws, Ho, Wo);
        }
        k_sample<<<4 * Ho * Wo / 4, 256, 0, stream>>>(xt, OFF, MSK, SH, STATS + slot * 128,
                                                      Hs, Ws, Ho, Wo, stride);
        int spn = (Hf * Wf + 63) / 64;
        k_gnup<<<4 * spn, 256, 0, stream>>>(SH, fin, STATS + slot * 128, CMEAN + slot * 1024,
                                            gng, gnb, Ho, Wo, Hf, Wf);
    };

    // ---- level 0 (80x80): mid(x0) + high(x1 up) ----
    run_feat(XT0, 80, 80, 1, false, dw_w_m, dw_s_m, dw_b_m, gn_g_m, gn_b_m, 0, FINA, 80, 80);
    run_feat(XT1, 40, 40, 1, true, dw_w_h, dw_s_h, dw_b_h, gn_g_h, gn_b_h, 1, FINB, 80, 80);
    k_out<<<4 * 100, 256, 0, stream>>>(FINA, FINB, nullptr, CMEAN, CMEAN + 1024, nullptr, 2,
                                       0.5f, sa_w, sa_b, fc1_w, fc1_b, fc2_w, fc2_b, out0, 80,
                                       80);
    // ---- level 1 (40x40): mid(x1) + low(x0 s2) + high(x2 up) ----
    run_feat(XT1, 40, 40, 1, false, dw_w_m, dw_s_m, dw_b_m, gn_g_m, gn_b_m, 2, FINA, 40, 40);
    run_feat(XT0, 80, 80, 2, true, dw_w_l, dw_s_l, dw_b_l, gn_g_l, gn_b_l, 3, FINB, 40, 40);
    run_feat(XT2, 20, 20, 1, true, dw_w_h, dw_s_h, dw_b_h, gn_g_h, gn_b_h, 4, FINC, 40, 40);
    k_out<<<4 * 25, 256, 0, stream>>>(FINA, FINB, FINC, CMEAN + 2 * 1024, CMEAN + 3 * 1024,
                                      CMEAN + 4 * 1024, 3, 1.f / 3.f, sa_w, sa_b, fc1_w,
                                      fc1_b, fc2_w, fc2_b, out1, 40, 40);
    // ---- level 2 (20x20): mid(x2) + low(x1 s2) ----
    run_feat(XT2, 20, 20, 1, false, dw_w_m, dw_s_m, dw_b_m, gn_g_m, gn_b_m, 5, FINA, 20, 20);
    run_feat(XT1, 40, 40, 2, true, dw_w_l, dw_s_l, dw_b_l, gn_g_l, gn_b_l, 6, FINB, 20, 20);
    k_out<<<4 * 7, 256, 0, stream>>>(FINA, FINB, nullptr, CMEAN + 5 * 1024, CMEAN + 6 * 1024,
                                     nullptr, 2, 0.5f, sa_w, sa_b, fc1_w, fc1_b, fc2_w, fc2_b,
                                     out2, 20, 20);
}

// Round 3
// 1221.879 us; speedup vs baseline: 1.5424x; 1.5424x over previous
//
#include <hip/hip_runtime.h>

#define C_ 256
#define G_ 4

// ---------------------------------------------------------------- prep ----
// wpad: offset conv weights padded to 12/row. dwt: depthwise weights transposed
// to [9][256] for each of h/m/l. zeros: STATS+CMEAN region (8064 floats).
__global__ void k_prep(const float* __restrict__ off_w, const float* __restrict__ dwh,
                       const float* __restrict__ dwm, const float* __restrict__ dwl,
                       float* __restrict__ wpad, float* __restrict__ dwt,
                       float* __restrict__ zeros) {
    int i = blockIdx.x * 256 + threadIdx.x;
    const int NW = 108 * 64 * 12;
    if (i < NW) {
        int r = i / 12, t = i % 12;
        wpad[i] = (t < 9) ? off_w[r * 9 + t] : 0.f;
    }
    int j = i - NW;
    if (j >= 0 && j < 3 * 2304) {
        int which = j / 2304, rem = j % 2304;
        int t = rem / 256, c = rem % 256;
        const float* src = (which == 0) ? dwh : (which == 1) ? dwm : dwl;
        dwt[j] = src[c * 9 + t];
    }
    int z = i - NW - 3 * 2304;
    if (z >= 0 && z < 8064) zeros[z] = 0.f;
}

// ------------------------------------------------------------ transpose ----
__global__ __launch_bounds__(256) void k_transpose(const float* __restrict__ x,
                                                   float* __restrict__ xt, int H, int W) {
    __shared__ float tile[32][33];
    int nh = blockIdx.x;
    int n = nh / H, h = nh % H;
    int w0 = blockIdx.y * 32, c0 = blockIdx.z * 32;
    int tid = threadIdx.x;
    int i = tid / 32, j = tid % 32;
#pragma unroll
    for (int r = 0; r < 4; r++) {
        int c = c0 + i + r * 8;
        int w = w0 + j;
        tile[i + r * 8][j] = (w < W) ? x[((size_t)(n * C_ + c) * H + h) * W + w] : 0.f;
    }
    __syncthreads();
    int wj = tid / 32, ci = tid % 32;
#pragma unroll
    for (int r = 0; r < 4; r++) {
        int w = w0 + wj + r * 8;
        if (w < W) xt[((size_t)(n * H + h) * W + w) * C_ + c0 + ci] = tile[ci][wj + r * 8];
    }
}

// -------------------------------------------------------- depthwise+SiLU ----
// block = 256 thr = 4 pixels x 64 lanes; lane handles 4 channels (float4).
__global__ __launch_bounds__(256) void k_dw_silu(const float* __restrict__ xt,
                                                 const float* __restrict__ wdt,
                                                 const float* __restrict__ sc,
                                                 const float* __restrict__ bi,
                                                 float* __restrict__ out, int H, int W) {
    int tid = threadIdx.x;
    int pw = tid >> 6, lane = tid & 63;
    int ch4 = lane << 2;
    int pix = blockIdx.x * 4 + pw;
    int w = pix % W, h = (pix / W) % H, n = pix / (W * H);
    const float4 s4 = *(const float4*)(sc + ch4);
    const float4 b4 = *(const float4*)(bi + ch4);
    const float* xb = xt + (size_t)n * H * W * C_ + ch4;
    float4 acc = {0.f, 0.f, 0.f, 0.f};
#pragma unroll
    for (int t = 0; t < 9; t++) {
        int hh = h + t / 3 - 1, ww = w + t % 3 - 1;
        if (hh >= 0 && hh < H && ww >= 0 && ww < W) {
            float4 wt = *(const float4*)(wdt + t * 256 + ch4);
            float4 xv = *(const float4*)(xb + (size_t)(hh * W + ww) * C_);
            acc.x += wt.x * xv.x;
            acc.y += wt.y * xv.y;
            acc.z += wt.z * xv.z;
            acc.w += wt.w * xv.w;
        }
    }
    float4 y;
    y.x = acc.x * s4.x + b4.x;
    y.y = acc.y * s4.y + b4.y;
    y.z = acc.z * s4.z + b4.z;
    y.w = acc.w * s4.w + b4.w;
    y.x = y.x / (1.f + __expf(-y.x));
    y.y = y.y / (1.f + __expf(-y.y));
    y.z = y.z / (1.f + __expf(-y.z));
    y.w = y.w / (1.f + __expf(-y.w));
    *(float4*)(out + (size_t)pix * C_ + ch4) = y;
}

// ------------------------------------------------- grouped offset/mask conv ----
template <int STRIDE, bool SOFTMAX, int TH, int TW>
__global__ __launch_bounds__(128) void k_offmask(const float* __restrict__ dw,
                                                 const float* __restrict__ wpad,
                                                 const float* __restrict__ bias,
                                                 float* __restrict__ off,
                                                 float* __restrict__ msk,
                                                 int Hs, int Ws, int Ho, int Wo) {
    constexpr int SR = STRIDE * (TH - 1) + 3;
    constexpr int SC = STRIDE * (TW - 1) + 3;
    constexpr int NV = SR * SC;
    constexpr int B4 = (NV + 3) / 4;
    constexpr int PITCH = ((B4 % 2) == 1) ? B4 * 4 : B4 * 4 + 4;
    constexpr int TP = TH * TW;
    __shared__ float patch[C_ * PITCH];
    int tid = threadIdx.x;
    int n = blockIdx.x;
    int ho0 = blockIdx.y * TH, wo0 = blockIdx.z * TW;
    int hs0 = ho0 * STRIDE - 1, ws0 = wo0 * STRIDE - 1;
    for (int flat = tid; flat < NV * C_; flat += 128) {
        int c = flat & (C_ - 1);
        int rc = flat >> 8;
        int r = rc / SC, col = rc % SC;
        int hh = hs0 + r, ww = ws0 + col;
        float v = 0.f;
        if (hh >= 0 && hh < Hs && ww >= 0 && ww < Ws)
            v = dw[((size_t)(n * Hs + hh) * Ws + ww) * C_ + c];
        patch[c * PITCH + rc] = v;
    }
    __syncthreads();
    float acc[TP];
    int oc = tid;
    if (oc < 108) {
        float bb = bias[oc];
#pragma unroll
        for (int p = 0; p < TP; p++) acc[p] = bb;
        int icb = (oc / 27) * 64;
        for (int ic = 0; ic < 64; ic++) {
            float pv[B4 * 4];
            const float4* src = (const float4*)(patch + (icb + ic) * PITCH);
#pragma unroll
            for (int v = 0; v < B4; v++) ((float4*)pv)[v] = src[v];
            const float4* wsrc = (const float4*)(wpad + (size_t)(oc * 64 + ic) * 12);
            float4 w0 = wsrc[0], w1 = wsrc[1], w2 = wsrc[2];
            float wt[9] = {w0.x, w0.y, w0.z, w0.w, w1.x, w1.y, w1.z, w1.w, w2.x};
#pragma unroll
            for (int pr = 0; pr < TH; pr++)
#pragma unroll
                for (int pc = 0; pc < TW; pc++)
#pragma unroll
                    for (int ty = 0; ty < 3; ty++)
#pragma unroll
                        for (int tx = 0; tx < 3; tx++)
                            acc[pr * TW + pc] +=
                                wt[ty * 3 + tx] * pv[(pr * STRIDE + ty) * SC + pc * STRIDE + tx];
        }
    }
    __syncthreads();
    float* omv = patch;
    if (oc < 108) {
#pragma unroll
        for (int p = 0; p < TP; p++) omv[p * 112 + oc] = acc[p];
    }
    __syncthreads();
    for (int flat = tid; flat < TP * 72; flat += 128) {
        int p = flat / 72, ch = flat % 72;
        int ho = ho0 + p / TW, wo = wo0 + p % TW;
        off[((size_t)(n * Ho + ho) * Wo + wo) * 72 + ch] = omv[p * 112 + ch];
    }
    if (SOFTMAX) {
        for (int flat = tid; flat < TP * G_; flat += 128) {
            int p = flat / G_, g = flat % G_;
            int ho = ho0 + p / TW, wo = wo0 + p % TW;
            float mx = -1e30f;
#pragma unroll
            for (int k = 0; k < 9; k++) mx = fmaxf(mx, omv[p * 112 + 72 + g * 9 + k]);
            float e[9], ssum = 0.f;
#pragma unroll
            for (int k = 0; k < 9; k++) {
                e[k] = __expf(omv[p * 112 + 72 + g * 9 + k] - mx);
                ssum += e[k];
            }
            float inv = 1.f / ssum;
            float* mp = msk + ((size_t)(n * Ho + ho) * Wo + wo) * 36 + g * 9;
#pragma unroll
            for (int k = 0; k < 9; k++) mp[k] = e[k] * inv;
        }
    } else {
        for (int flat = tid; flat < TP * 36; flat += 128) {
            int p = flat / 36, ch = flat % 36;
            int ho = ho0 + p / TW, wo = wo0 + p % TW;
            float v = omv[p * 112 + 72 + ch];
            msk[((size_t)(n * Ho + ho) * Wo + wo) * 36 + ch] = 1.f / (1.f + __expf(-v));
        }
    }
}

// ------------------------------------------------------------- DCNv3 sample ----
// block = 256 thr = 4 waves; wave = one pixel, lane = 4 channels (float4),
// group g = lane>>4. Branchless bilinear (clamped idx * validity weight).
__global__ __launch_bounds__(256) void k_sample(const float* __restrict__ xt,
                                                const float* __restrict__ off,
                                                const float* __restrict__ msk,
                                                float* __restrict__ raw,
                                                float* __restrict__ stats,
                                                int Hs, int Ws, int Ho, int Wo, int stride) {
    int tid = threadIdx.x;
    int wv = tid >> 6, lane = tid & 63;
    int g = lane >> 4;
    int ch4 = lane << 2;
    int pix0 = blockIdx.x * 4;
    int pix = pix0 + wv;
    int n = pix0 / (Ho * Wo);
    __shared__ float som[4][108];
    __shared__ float lstat[32];
    for (int flat = tid; flat < 432; flat += 256) {
        int p = flat / 108, ch = flat % 108;
        size_t px_ = pix0 + p;
        som[p][ch] = (ch < 72) ? off[px_ * 72 + ch] : msk[px_ * 36 + (ch - 72)];
    }
    if (tid < 32) lstat[tid] = 0.f;
    __syncthreads();
    int wo = pix % Wo, ho = (pix / Wo) % Ho;
    const float* xb = xt + (size_t)n * Hs * Ws * C_ + ch4;
    float4 acc = {0.f, 0.f, 0.f, 0.f};
#pragma unroll
    for (int k = 0; k < 9; k++) {
        float oy = som[wv][g * 18 + 2 * k], ox = som[wv][g * 18 + 2 * k + 1];
        float m = som[wv][72 + g * 9 + k];
        float py = (float)(ho * stride + k / 3 - 1) + oy;
        float px = (float)(wo * stride + k % 3 - 1) + ox;
        float y0f = floorf(py), x0f = floorf(px);
        int y0 = (int)y0f, x0 = (int)x0f;
        float wy = py - y0f, wx = px - x0f;
        int y1 = y0 + 1, x1 = x0 + 1;
        float v0y = (y0 >= 0 && y0 < Hs) ? 1.f : 0.f;
        float v1y = (y1 >= 0 && y1 < Hs) ? 1.f : 0.f;
        float v0x = (x0 >= 0 && x0 < Ws) ? 1.f : 0.f;
        float v1x = (x1 >= 0 && x1 < Ws) ? 1.f : 0.f;
        int y0c = min(max(y0, 0), Hs - 1), y1c = min(max(y1, 0), Hs - 1);
        int x0c = min(max(x0, 0), Ws - 1), x1c = min(max(x1, 0), Ws - 1);
        float w00 = (1.f - wy) * (1.f - wx) * v0y * v0x * m;
        float w01 = (1.f - wy) * wx * v0y * v1x * m;
        float w10 = wy * (1.f - wx) * v1y * v0x * m;
        float w11 = wy * wx * v1y * v1x * m;
        const float4 a00 = *(const float4*)(xb + (size_t)(y0c * Ws + x0c) * C_);
        const float4 a01 = *(const float4*)(xb + (size_t)(y0c * Ws + x1c) * C_);
        const float4 a10 = *(const float4*)(xb + (size_t)(y1c * Ws + x0c) * C_);
        const float4 a11 = *(const float4*)(xb + (size_t)(y1c * Ws + x1c) * C_);
        acc.x += w00 * a00.x + w01 * a01.x + w10 * a10.x + w11 * a11.x;
        acc.y += w00 * a00.y + w01 * a01.y + w10 * a10.y + w11 * a11.y;
        acc.z += w00 * a00.z + w01 * a01.z + w10 * a10.z + w11 * a11.z;
        acc.w += w00 * a00.w + w01 * a01.w + w10 * a10.w + w11 * a11.w;
    }
    *(float4*)(raw + (size_t)pix * C_ + ch4) = acc;
    float gs = acc.x + acc.y + acc.z + acc.w;
    float gss = acc.x * acc.x + acc.y * acc.y + acc.z * acc.z + acc.w * acc.w;
#pragma unroll
    for (int o = 2; o; o >>= 1) {
        gs += __shfl_down(gs, o, 4);
        gss += __shfl_down(gss, o, 4);
    }
    if ((lane & 3) == 0) {
        atomicAdd(&lstat[(lane >> 2) * 2 + 0], gs);
        atomicAdd(&lstat[(lane >> 2) * 2 + 1], gss);
    }
    __syncthreads();
    if (tid < 32) atomicAdd(&stats[n * 32 + tid], lstat[tid]);
}

// ----------------------------------------- GN affine (+bilinear up) + ch-means ----
// block = 256 thr = 4 waves; lane = 4 channels (float4); 64 pixels per block.
__global__ __launch_bounds__(256) void k_gnup(const float* __restrict__ raw,
                                              float* __restrict__ fin,
                                              const float* __restrict__ stats,
                                              float* __restrict__ cmean,
                                              const float* __restrict__ gamma,
                                              const float* __restrict__ beta,
                                              int Hr, int Wr, int Hf, int Wf) {
    int HWf = Hf * Wf;
    int spn = (HWf + 63) >> 6;
    int n = blockIdx.x / spn;
    int p0 = (blockIdx.x % spn) << 6;
    int tid = threadIdx.x;
    int wv = tid >> 6, lane = tid & 63;
    int ch4 = lane << 2;
    int gg = lane >> 2;
    float cnt = 16.f * Hr * Wr;
    float s1 = stats[(n * 16 + gg) * 2], s2 = stats[(n * 16 + gg) * 2 + 1];
    float mu = s1 / cnt;
    float var = s2 / cnt - mu * mu;
    float rs = rsqrtf(var + 1e-5f);
    float4 g4 = *(const float4*)(gamma + ch4);
    float4 b4 = *(const float4*)(beta + ch4);
    float4 ga, be;
    ga.x = g4.x * rs; be.x = b4.x - mu * ga.x;
    ga.y = g4.y * rs; be.y = b4.y - mu * ga.y;
    ga.z = g4.z * rs; be.z = b4.z - mu * ga.z;
    ga.w = g4.w * rs; be.w = b4.w - mu * ga.w;
    bool up = (Hf != Hr);
    float sys = up ? (float)((double)(Hr - 1) / (double)(Hf - 1)) : 0.f;
    float sxs = up ? (float)((double)(Wr - 1) / (double)(Wf - 1)) : 0.f;
    float4 csum = {0.f, 0.f, 0.f, 0.f};
    __shared__ float cs[4][256];
    const float* rb = raw + (size_t)n * Hr * Wr * C_ + ch4;
    for (int i = wv; i < 64; i += 4) {
        int p = p0 + i;
        if (p < HWf) {
            float4 v;
            if (up) {
                int ho = p / Wf, wo = p % Wf;
                float sy = ho * sys, sx = wo * sxs;
                int y0 = (int)sy, x0 = (int)sx;
                float fy = sy - y0, fx = sx - x0;
                int y1 = min(y0 + 1, Hr - 1), x1 = min(x0 + 1, Wr - 1);
                float4 v00 = *(const float4*)(rb + (size_t)(y0 * Wr + x0) * C_);
                float4 v01 = *(const float4*)(rb + (size_t)(y0 * Wr + x1) * C_);
                float4 v10 = *(const float4*)(rb + (size_t)(y1 * Wr + x0) * C_);
                float4 v11 = *(const float4*)(rb + (size_t)(y1 * Wr + x1) * C_);
                v.x = (v00.x * (1.f - fy) + v10.x * fy) * (1.f - fx) + (v01.x * (1.f - fy) + v11.x * fy) * fx;
                v.y = (v00.y * (1.f - fy) + v10.y * fy) * (1.f - fx) + (v01.y * (1.f - fy) + v11.y * fy) * fx;
                v.z = (v00.z * (1.f - fy) + v10.z * fy) * (1.f - fx) + (v01.z * (1.f - fy) + v11.z * fy) * fx;
                v.w = (v00.w * (1.f - fy) + v10.w * fy) * (1.f - fx) + (v01.w * (1.f - fy) + v11.w * fy) * fx;
            } else {
                v = *(const float4*)(raw + ((size_t)n * HWf + p) * C_ + ch4);
            }
            float4 y4;
            y4.x = v.x * ga.x + be.x;
            y4.y = v.y * ga.y + be.y;
            y4.z = v.z * ga.z + be.z;
            y4.w = v.w * ga.w + be.w;
            *(float4*)(fin + ((size_t)n * HWf + p) * C_ + ch4) = y4;
            csum.x += y4.x; csum.y += y4.y; csum.z += y4.z; csum.w += y4.w;
        }
    }
    cs[wv][ch4 + 0] = csum.x;
    cs[wv][ch4 + 1] = csum.y;
    cs[wv][ch4 + 2] = csum.z;
    cs[wv][ch4 + 3] = csum.w;
    __syncthreads();
    if (wv == 0) {
        float t0 = 0.f, t1 = 0.f, t2 = 0.f, t3 = 0.f;
#pragma unroll
        for (int r = 0; r < 4; r++) {
            t0 += cs[r][ch4 + 0];
            t1 += cs[r][ch4 + 1];
            t2 += cs[r][ch4 + 2];
            t3 += cs[r][ch4 + 3];
        }
        atomicAdd(&cmean[n * C_ + ch4 + 0], t0);
        atomicAdd(&cmean[n * C_ + ch4 + 1], t1);
        atomicAdd(&cmean[n * C_ + ch4 + 2], t2);
        atomicAdd(&cmean[n * C_ + ch4 + 3], t3);
    }
}

// ---------------------------------- scale-attn combine + DyReLU + NCHW store ----
__global__ __launch_bounds__(256) void k_out(const float* __restrict__ fA,
                                             const float* __restrict__ fB,
                                             const float* __restrict__ fC,
                                             const float* __restrict__ cmA,
                                             const float* __restrict__ cmB,
                                             const float* __restrict__ cmC,
                                             int nf, float inv_nl,
                                             const float* __restrict__ sa_w,
                                             const float* __restrict__ sa_b,
                                             const float* __restrict__ fc1_w,
                                             const float* __restrict__ fc1_b,
                                             const float* __restrict__ fc2_w,
                                             const float* __restrict__ fc2_b,
                                             float* __restrict__ out, int H, int W) {
    int HW = H * W;
    int spn = (HW + 63) >> 6;
    int n = blockIdx.x / spn;
    int p0 = (blockIdx.x % spn) << 6;
    int c = threadIdx.x;
    __shared__ float red[256];
    __shared__ float meanv[256];
    __shared__ float hv[64];
    __shared__ float sa_a[3];
    __shared__ float ot[16 * 257];
    float inv_hw = 1.f / HW;
    const float* cms[3] = {cmA, cmB, cmC};
    float cm[3] = {0.f, 0.f, 0.f}, a[3] = {0.f, 0.f, 0.f};
    for (int f = 0; f < nf; f++) {
        cm[f] = cms[f][n * C_ + c] * inv_hw;
        red[c] = sa_w[c] * cm[f];
        __syncthreads();
        for (int s = 128; s; s >>= 1) {
            if (c < s) red[c] += red[c + s];
            __syncthreads();
        }
        if (c == 0) {
            float t = fmaxf(red[0] + sa_b[0], 0.f);
            sa_a[f] = fminf(fmaxf((t + 3.f) * (1.f / 6.f), 0.f), 1.f);
        }
        __syncthreads();
        a[f] = sa_a[f];
    }
    float mv = 0.f;
    for (int f = 0; f < nf; f++) mv += a[f] * cm[f];
    mv *= inv_nl;
    meanv[c] = mv;
    __syncthreads();
    int j = c & 63;
    float ha = fc1_b[j];
    for (int k = 0; k < 256; k++) ha += fc1_w[j * 256 + k] * meanv[k];
    if (c < 64) hv[c] = fmaxf(ha, 0.f);
    __syncthreads();
    float zz[4];
#pragma unroll
    for (int i = 0; i < 4; i++) {
        float z = fc2_b[i * 256 + c];
        for (int k = 0; k < 64; k++) z += fc2_w[(size_t)(i * 256 + c) * 64 + k] * hv[k];
        zz[i] = fminf(fmaxf(z + 3.f, 0.f), 6.f) * (1.f / 6.f);
    }
    float a1 = (zz[0] - 0.5f) * 2.f + 1.f;
    float b1 = zz[1] - 0.5f;
    float a2 = (zz[2] - 0.5f) * 2.f;
    float b2 = zz[3] - 0.5f;
    for (int chk = 0; chk < 4; chk++) {
        __syncthreads();
        for (int i = 0; i < 16; i++) {
            int p = p0 + chk * 16 + i;
            if (p >= HW) continue;
            float fv = a[0] * fA[((size_t)n * HW + p) * C_ + c];
            if (nf > 1) fv += a[1] * fB[((size_t)n * HW + p) * C_ + c];
            if (nf > 2) fv += a[2] * fC[((size_t)n * HW + p) * C_ + c];
            fv *= inv_nl;
            ot[i * 257 + c] = fmaxf(fv * a1 + b1, fv * a2 + b2);
        }
        __syncthreads();
        int px = c & 15, cr0 = c >> 4;
        for (int pass = 0; pass < 16; pass++) {
            int cc = pass * 16 + cr0;
            int p = p0 + chk * 16 + px;
            if (p < HW) out[((size_t)n * C_ + cc) * HW + p] = ot[px * 257 + cc];
        }
    }
}

// --------------------------------------------------------------------- host ----
extern "C" void kernel_launch(void* const* d_in, const int* in_sizes, int n_in,
                              void* d_out, int out_size, void* d_ws, size_t ws_size,
                              hipStream_t stream) {
    (void)in_sizes; (void)n_in; (void)out_size; (void)ws_size;
    const float* x0 = (const float*)d_in[0];
    const float* x1 = (const float*)d_in[1];
    const float* x2 = (const float*)d_in[2];
    const float* dw_w_h = (const float*)d_in[3];
    const float* dw_s_h = (const float*)d_in[4];
    const float* dw_b_h = (const float*)d_in[5];
    const float* dw_w_m = (const float*)d_in[6];
    const float* dw_s_m = (const float*)d_in[7];
    const float* dw_b_m = (const float*)d_in[8];
    const float* dw_w_l = (const float*)d_in[9];
    const float* dw_s_l = (const float*)d_in[10];
    const float* dw_b_l = (const float*)d_in[11];
    const float* off_w = (const float*)d_in[12];
    const float* off_b = (const float*)d_in[13];
    const float* gn_g_h = (const float*)d_in[14];
    const float* gn_b_h = (const float*)d_in[15];
    const float* gn_g_m = (const float*)d_in[16];
    const float* gn_b_m = (const float*)d_in[17];
    const float* gn_g_l = (const float*)d_in[18];
    const float* gn_b_l = (const float*)d_in[19];
    const float* sa_w = (const float*)d_in[20];
    const float* sa_b = (const float*)d_in[21];
    const float* fc1_w = (const float*)d_in[22];
    const float* fc1_b = (const float*)d_in[23];
    const float* fc2_w = (const float*)d_in[24];
    const float* fc2_b = (const float*)d_in[25];

    float* ws = (float*)d_ws;
    float* XT0 = ws + 0;              // 6553600
    float* XT1 = ws + 6553600;        // 1638400
    float* XT2 = ws + 8192000;        // 409600
    float* SH = ws + 8601600;         // 6553600
    float* OFF = ws + 15155200;       // 1843200
    float* MSK = ws + 16998400;       // 921600
    float* FINA = ws + 17920000;      // 6553600
    float* FINB = ws + 24473600;      // 6553600
    float* FINC = ws + 31027200;      // 1638400
    float* WPAD = ws + 32665600;      // 82944
    float* DWT = ws + 32748544;       // 6912
    float* STATS = ws + 32755456;     // 896  (7 slots x 128)
    float* CMEAN = ws + 32756352;     // 7168 (7 slots x 1024)

    float* out0 = (float*)d_out;
    float* out1 = out0 + 6553600;
    float* out2 = out0 + 8192000;

    k_prep<<<(108 * 64 * 12 + 6912 + 8064 + 255) / 256, 256, 0, stream>>>(
        off_w, dw_w_h, dw_w_m, dw_w_l, WPAD, DWT, STATS);

    k_transpose<<<dim3(4 * 80, 3, 8), 256, 0, stream>>>(x0, XT0, 80, 80);
    k_transpose<<<dim3(4 * 40, 2, 8), 256, 0, stream>>>(x1, XT1, 40, 40);
    k_transpose<<<dim3(4 * 20, 1, 8), 256, 0, stream>>>(x2, XT2, 20, 20);

    auto run_feat = [&](const float* xt, int Hs, int Ws, int stride, bool softmax,
                        const float* dwt, const float* dws, const float* dwb,
                        const float* gng, const float* gnb, int slot, float* fin, int Hf,
                        int Wf) {
        int Ho = Hs / stride, Wo = Ws / stride;
        k_dw_silu<<<4 * Hs * Ws / 4, 256, 0, stream>>>(xt, dwt, dws, dwb, SH, Hs, Ws);
        if (stride == 1) {
            if (softmax)
                k_offmask<1, true, 4, 4><<<dim3(4, Ho / 4, Wo / 4), 128, 0, stream>>>(
                    SH, WPAD, off_b, OFF, MSK, Hs, Ws, Ho, Wo);
            else
                k_offmask<1, false, 4, 4><<<dim3(4, Ho / 4, Wo / 4), 128, 0, stream>>>(
                    SH, WPAD, off_b, OFF, MSK, Hs, Ws, Ho, Wo);
        } else {
            k_offmask<2, true, 2, 4><<<dim3(4, Ho / 2, Wo / 4), 128, 0, stream>>>(
                SH, WPAD, off_b, OFF, MSK, Hs, Ws, Ho, Wo);
        }
        // STATS slot stride is 128 floats (4 batches x 16 gn-groups x {sum,sumsq})
        k_sample<<<4 * Ho * Wo / 4, 256, 0, stream>>>(xt, OFF, MSK, SH, STATS + slot * 128,
                                                      Hs, Ws, Ho, Wo, stride);
        int spn = (Hf * Wf + 63) / 64;
        k_gnup<<<4 * spn, 256, 0, stream>>>(SH, fin, STATS + slot * 128, CMEAN + slot * 1024,
                                            gng, gnb, Ho, Wo, Hf, Wf);
    };

    // ---- level 0 (80x80): mid(x0) + high(x1 up) ----
    run_feat(XT0, 80, 80, 1, false, DWT + 1 * 2304, dw_s_m, dw_b_m, gn_g_m, gn_b_m, 0, FINA, 80, 80);
    run_feat(XT1, 40, 40, 1, true, DWT + 0 * 2304, dw_s_h, dw_b_h, gn_g_h, gn_b_h, 1, FINB, 80, 80);
    k_out<<<4 * 100, 256, 0, stream>>>(FINA, FINB, nullptr, CMEAN, CMEAN + 1024, nullptr, 2,
                                       0.5f, sa_w, sa_b, fc1_w, fc1_b, fc2_w, fc2_b, out0, 80,
                                       80);
    // ---- level 1 (40x40): mid(x1) + low(x0 s2) + high(x2 up) ----
    run_feat(XT1, 40, 40, 1, false, DWT + 1 * 2304, dw_s_m, dw_b_m, gn_g_m, gn_b_m, 2, FINA, 40, 40);
    run_feat(XT0, 80, 80, 2, true, DWT + 2 * 2304, dw_s_l, dw_b_l, gn_g_l, gn_b_l, 3, FINB, 40, 40);
    run_feat(XT2, 20, 20, 1, true, DWT + 0 * 2304, dw_s_h, dw_b_h, gn_g_h, gn_b_h, 4, FINC, 40, 40);
    k_out<<<4 * 25, 256, 0, stream>>>(FINA, FINB, FINC, CMEAN + 2 * 1024, CMEAN + 3 * 1024,
                                      CMEAN + 4 * 1024, 3, 1.f / 3.f, sa_w, sa_b, fc1_w,
                                      fc1_b, fc2_w, fc2_b, out1, 40, 40);
    // ---- level 2 (20x20): mid(x2) + low(x1 s2) ----
    run_feat(XT2, 20, 20, 1, false, DWT + 1 * 2304, dw_s_m, dw_b_m, gn_g_m, gn_b_m, 5, FINA, 20, 20);
    run_feat(XT1, 40, 40, 2, true, DWT + 2 * 2304, dw_s_l, dw_b_l, gn_g_l, gn_b_l, 6, FINB, 20, 20);
    k_out<<<4 * 7, 256, 0, stream>>>(FINA, FINB, nullptr, CMEAN + 5 * 1024, CMEAN + 6 * 1024,
                                     nullptr, 2, 0.5f, sa_w, sa_b, fc1_w, fc1_b, fc2_w, fc2_b,
                                     out2, 20, 20);
}

// Round 4
// 828.835 us; speedup vs baseline: 2.2739x; 1.4742x over previous
//
#include <hip/hip_runtime.h>
#include <hip/hip_bf16.h>

#define C_ 256
#define G_ 4

typedef __attribute__((ext_vector_type(8))) short bf16x8;
typedef __attribute__((ext_vector_type(4))) float f32x4;

static __device__ __forceinline__ unsigned short f2bf(float x) {
    __hip_bfloat16 h = __float2bfloat16(x);
    return *(unsigned short*)&h;
}

// ---------------------------------------------------------------- prep ----
// wmf: bf16 MFMA-A-layout weights [g][32 oc-padded][576 k], k = tap*64+ic.
// dwt: depthwise weights transposed to [9][256] for h/m/l. zeros: STATS+CMEAN.
__global__ void k_prep(const float* __restrict__ off_w, const float* __restrict__ dwh,
                       const float* __restrict__ dwm, const float* __restrict__ dwl,
                       unsigned short* __restrict__ wmf, float* __restrict__ dwt,
                       float* __restrict__ zeros) {
    int i = blockIdx.x * 256 + threadIdx.x;
    const int NWM = 4 * 32 * 576;
    if (i < NWM) {
        int g = i / (32 * 576), rem = i % (32 * 576);
        int ol = rem / 576, kk = rem % 576;
        int tap = kk / 64, ic = kk % 64;
        float v = (ol < 27) ? off_w[((size_t)((g * 27 + ol) * 64 + ic)) * 9 + tap] : 0.f;
        wmf[i] = f2bf(v);
    }
    int j = i - NWM;
    if (j >= 0 && j < 3 * 2304) {
        int which = j / 2304, rem = j % 2304;
        int t = rem / 256, c = rem % 256;
        const float* src = (which == 0) ? dwh : (which == 1) ? dwm : dwl;
        dwt[j] = src[c * 9 + t];
    }
    int z = i - NWM - 3 * 2304;
    if (z >= 0 && z < 8064) zeros[z] = 0.f;
}

// ------------------------------------------------------------ transpose ----
__global__ __launch_bounds__(256) void k_transpose(const float* __restrict__ x,
                                                   float* __restrict__ xt, int H, int W) {
    __shared__ float tile[32][33];
    int nh = blockIdx.x;
    int n = nh / H, h = nh % H;
    int w0 = blockIdx.y * 32, c0 = blockIdx.z * 32;
    int tid = threadIdx.x;
    int i = tid / 32, j = tid % 32;
#pragma unroll
    for (int r = 0; r < 4; r++) {
        int c = c0 + i + r * 8;
        int w = w0 + j;
        tile[i + r * 8][j] = (w < W) ? x[((size_t)(n * C_ + c) * H + h) * W + w] : 0.f;
    }
    __syncthreads();
    int wj = tid / 32, ci = tid % 32;
#pragma unroll
    for (int r = 0; r < 4; r++) {
        int w = w0 + wj + r * 8;
        if (w < W) xt[((size_t)(n * H + h) * W + w) * C_ + c0 + ci] = tile[ci][wj + r * 8];
    }
}

// -------------------------------------------------------- depthwise+SiLU ----
// block = 256 thr = 4 pixels x 64 lanes; lane handles 4 channels. bf16 output.
__global__ __launch_bounds__(256) void k_dw_silu(const float* __restrict__ xt,
                                                 const float* __restrict__ wdt,
                                                 const float* __restrict__ sc,
                                                 const float* __restrict__ bi,
                                                 unsigned short* __restrict__ out, int H,
                                                 int W) {
    int tid = threadIdx.x;
    int pw = tid >> 6, lane = tid & 63;
    int ch4 = lane << 2;
    int pix = blockIdx.x * 4 + pw;
    int w = pix % W, h = (pix / W) % H, n = pix / (W * H);
    const float4 s4 = *(const float4*)(sc + ch4);
    const float4 b4 = *(const float4*)(bi + ch4);
    const float* xb = xt + (size_t)n * H * W * C_ + ch4;
    float4 acc = {0.f, 0.f, 0.f, 0.f};
#pragma unroll
    for (int t = 0; t < 9; t++) {
        int hh = h + t / 3 - 1, ww = w + t % 3 - 1;
        if (hh >= 0 && hh < H && ww >= 0 && ww < W) {
            float4 wt = *(const float4*)(wdt + t * 256 + ch4);
            float4 xv = *(const float4*)(xb + (size_t)(hh * W + ww) * C_);
            acc.x += wt.x * xv.x;
            acc.y += wt.y * xv.y;
            acc.z += wt.z * xv.z;
            acc.w += wt.w * xv.w;
        }
    }
    float4 y;
    y.x = acc.x * s4.x + b4.x;
    y.y = acc.y * s4.y + b4.y;
    y.z = acc.z * s4.z + b4.z;
    y.w = acc.w * s4.w + b4.w;
    y.x = y.x / (1.f + __expf(-y.x));
    y.y = y.y / (1.f + __expf(-y.y));
    y.z = y.z / (1.f + __expf(-y.z));
    y.w = y.w / (1.f + __expf(-y.w));
    ushort4 o;
    o.x = f2bf(y.x);
    o.y = f2bf(y.y);
    o.z = f2bf(y.z);
    o.w = f2bf(y.w);
    *(ushort4*)(out + (size_t)pix * C_ + ch4) = o;
}

// ------------------------------------------------- grouped offset/mask conv ----
// MFMA bf16 GEMM: per group D[27][pix] = W[27][576] * P[576][pix].
// Block 256 thr / 4 waves; TP=TH*TW pixels; NT = TP/16 N-tiles.
template <int STRIDE, bool SOFTMAX, int TH, int TW>
__global__ __launch_bounds__(256) void k_offmask(const unsigned short* __restrict__ dwb,
                                                 const unsigned short* __restrict__ wmf,
                                                 const float* __restrict__ bias,
                                                 float* __restrict__ off,
                                                 float* __restrict__ msk,
                                                 int Hs, int Ws, int Ho, int Wo) {
    constexpr int SR = STRIDE * (TH - 1) + 3;
    constexpr int SC = STRIDE * (TW - 1) + 3;
    constexpr int NV = SR * SC;
    constexpr int CP = 264;  // bf16 pitch: 16B-aligned rows, balanced banks
    constexpr int TP = TH * TW;
    constexpr int NT = TP / 16;
    constexpr int MTW = 2 * NT;  // m-tiles per wave (8 total across waves/NT)
    constexpr int PATCH_B = NV * CP * 2;
    constexpr int OMV_B = TP * 112 * 4;
    constexpr int LDS_B = PATCH_B > OMV_B ? PATCH_B : OMV_B;
    __shared__ __align__(16) char smem[LDS_B];
    unsigned short* patch = (unsigned short*)smem;
    float* omv = (float*)smem;

    int tid = threadIdx.x;
    int wv = tid >> 6, lane = tid & 63;
    int n16 = lane & 15, q = lane >> 4;
    int n = blockIdx.x;
    int ho0 = blockIdx.y * TH, wo0 = blockIdx.z * TW;
    int hs0 = ho0 * STRIDE - 1, ws0 = wo0 * STRIDE - 1;

    // stage patch (16B per thread, coalesced; zero-pad borders)
    for (int idx = tid; idx < NV * 32; idx += 256) {
        int pp = idx >> 5;
        int c8 = (idx & 31) << 3;
        int hh = hs0 + pp / SC, ww = ws0 + pp % SC;
        uint4 v = {0u, 0u, 0u, 0u};
        if (hh >= 0 && hh < Hs && ww >= 0 && ww < Ws)
            v = *(const uint4*)(dwb + ((size_t)(n * Hs + hh) * Ws + ww) * C_ + c8);
        *(uint4*)(patch + pp * CP + c8) = v;
    }
    __syncthreads();

    int ntile = wv % NT;
    int mstart = (wv / NT) * MTW;
    int p = ntile * 16 + n16;
    int pr = p / TW, pc = p % TW;
    int pixbase = (pr * STRIDE) * SC + pc * STRIDE;
    int bchan = q << 3;

    f32x4 acc[MTW];
#pragma unroll
    for (int l = 0; l < MTW; l++) acc[l] = (f32x4){0.f, 0.f, 0.f, 0.f};

    for (int kk = 0; kk < 18; kk++) {
        int tap = kk >> 1;
        int ic0 = (kk & 1) << 5;
        int ty = tap / 3, tx = tap % 3;
        int ppix = pixbase + ty * SC + tx;
#pragma unroll
        for (int gi = 0; gi < MTW / 2; gi++) {
            int g = (mstart >> 1) + gi;
            bf16x8 b = *(const bf16x8*)(patch + ppix * CP + g * 64 + ic0 + bchan);
#pragma unroll
            for (int s = 0; s < 2; s++) {
                int row = g * 32 + s * 16 + n16;
                bf16x8 a = *(const bf16x8*)(wmf + (size_t)row * 576 + kk * 32 + bchan);
                acc[gi * 2 + s] =
                    __builtin_amdgcn_mfma_f32_16x16x32_bf16(a, b, acc[gi * 2 + s], 0, 0, 0);
            }
        }
    }
    __syncthreads();  // patch reads done; overlay omv

    // C/D layout: col = lane&15 (pixel), row = q*4 + reg (oc within 16-tile)
#pragma unroll
    for (int l = 0; l < MTW; l++) {
        int mt = mstart + l;
        int g = mt >> 1;
        int olbase = (mt & 1) * 16 + q * 4;
#pragma unroll
        for (int r = 0; r < 4; r++) {
            int ol = olbase + r;
            if (ol < 27) omv[p * 112 + g * 27 + ol] = acc[l][r];
        }
    }
    __syncthreads();

    // epilogue: offsets 0..71 (+bias), masks 72..107 (+bias, sigmoid/softmax)
    for (int flat = tid; flat < TP * 72; flat += 256) {
        int pp = flat / 72, ch = flat % 72;
        int ho = ho0 + pp / TW, wo = wo0 + pp % TW;
        off[((size_t)(n * Ho + ho) * Wo + wo) * 72 + ch] = omv[pp * 112 + ch] + bias[ch];
    }
    if (SOFTMAX) {
        for (int flat = tid; flat < TP * G_; flat += 256) {
            int pp = flat / G_, g = flat % G_;
            int ho = ho0 + pp / TW, wo = wo0 + pp % TW;
            float lg[9], mx = -1e30f;
#pragma unroll
            for (int k = 0; k < 9; k++) {
                lg[k] = omv[pp * 112 + 72 + g * 9 + k] + bias[72 + g * 9 + k];
                mx = fmaxf(mx, lg[k]);
            }
            float e[9], ssum = 0.f;
#pragma unroll
            for (int k = 0; k < 9; k++) {
                e[k] = __expf(lg[k] - mx);
                ssum += e[k];
            }
            float inv = 1.f / ssum;
            float* mp = msk + ((size_t)(n * Ho + ho) * Wo + wo) * 36 + g * 9;
#pragma unroll
            for (int k = 0; k < 9; k++) mp[k] = e[k] * inv;
        }
    } else {
        for (int flat = tid; flat < TP * 36; flat += 256) {
            int pp = flat / 36, ch = flat % 36;
            int ho = ho0 + pp / TW, wo = wo0 + pp % TW;
            float v = omv[pp * 112 + 72 + ch] + bias[72 + ch];
            msk[((size_t)(n * Ho + ho) * Wo + wo) * 36 + ch] = 1.f / (1.f + __expf(-v));
        }
    }
}

// ------------------------------------------------------------- DCNv3 sample ----
__global__ __launch_bounds__(256) void k_sample(const float* __restrict__ xt,
                                                const float* __restrict__ off,
                                                const float* __restrict__ msk,
                                                float* __restrict__ raw,
                                                float* __restrict__ stats,
                                                int Hs, int Ws, int Ho, int Wo, int stride) {
    int tid = threadIdx.x;
    int wv = tid >> 6, lane = tid & 63;
    int g = lane >> 4;
    int ch4 = lane << 2;
    int pix0 = blockIdx.x * 4;
    int pix = pix0 + wv;
    int n = pix0 / (Ho * Wo);
    __shared__ float som[4][108];
    __shared__ float lstat[32];
    for (int flat = tid; flat < 432; flat += 256) {
        int p = flat / 108, ch = flat % 108;
        size_t px_ = pix0 + p;
        som[p][ch] = (ch < 72) ? off[px_ * 72 + ch] : msk[px_ * 36 + (ch - 72)];
    }
    if (tid < 32) lstat[tid] = 0.f;
    __syncthreads();
    int wo = pix % Wo, ho = (pix / Wo) % Ho;
    const float* xb = xt + (size_t)n * Hs * Ws * C_ + ch4;
    float4 acc = {0.f, 0.f, 0.f, 0.f};
#pragma unroll
    for (int k = 0; k < 9; k++) {
        float oy = som[wv][g * 18 + 2 * k], ox = som[wv][g * 18 + 2 * k + 1];
        float m = som[wv][72 + g * 9 + k];
        float py = (float)(ho * stride + k / 3 - 1) + oy;
        float px = (float)(wo * stride + k % 3 - 1) + ox;
        float y0f = floorf(py), x0f = floorf(px);
        int y0 = (int)y0f, x0 = (int)x0f;
        float wy = py - y0f, wx = px - x0f;
        int y1 = y0 + 1, x1 = x0 + 1;
        float v0y = (y0 >= 0 && y0 < Hs) ? 1.f : 0.f;
        float v1y = (y1 >= 0 && y1 < Hs) ? 1.f : 0.f;
        float v0x = (x0 >= 0 && x0 < Ws) ? 1.f : 0.f;
        float v1x = (x1 >= 0 && x1 < Ws) ? 1.f : 0.f;
        int y0c = min(max(y0, 0), Hs - 1), y1c = min(max(y1, 0), Hs - 1);
        int x0c = min(max(x0, 0), Ws - 1), x1c = min(max(x1, 0), Ws - 1);
        float w00 = (1.f - wy) * (1.f - wx) * v0y * v0x * m;
        float w01 = (1.f - wy) * wx * v0y * v1x * m;
        float w10 = wy * (1.f - wx) * v1y * v0x * m;
        float w11 = wy * wx * v1y * v1x * m;
        const float4 a00 = *(const float4*)(xb + (size_t)(y0c * Ws + x0c) * C_);
        const float4 a01 = *(const float4*)(xb + (size_t)(y0c * Ws + x1c) * C_);
        const float4 a10 = *(const float4*)(xb + (size_t)(y1c * Ws + x0c) * C_);
        const float4 a11 = *(const float4*)(xb + (size_t)(y1c * Ws + x1c) * C_);
        acc.x += w00 * a00.x + w01 * a01.x + w10 * a10.x + w11 * a11.x;
        acc.y += w00 * a00.y + w01 * a01.y + w10 * a10.y + w11 * a11.y;
        acc.z += w00 * a00.z + w01 * a01.z + w10 * a10.z + w11 * a11.z;
        acc.w += w00 * a00.w + w01 * a01.w + w10 * a10.w + w11 * a11.w;
    }
    *(float4*)(raw + (size_t)pix * C_ + ch4) = acc;
    float gs = acc.x + acc.y + acc.z + acc.w;
    float gss = acc.x * acc.x + acc.y * acc.y + acc.z * acc.z + acc.w * acc.w;
#pragma unroll
    for (int o = 2; o; o >>= 1) {
        gs += __shfl_down(gs, o, 4);
        gss += __shfl_down(gss, o, 4);
    }
    if ((lane & 3) == 0) {
        atomicAdd(&lstat[(lane >> 2) * 2 + 0], gs);
        atomicAdd(&lstat[(lane >> 2) * 2 + 1], gss);
    }
    __syncthreads();
    if (tid < 32) atomicAdd(&stats[n * 32 + tid], lstat[tid]);
}

// ----------------------------------------- GN affine (+bilinear up) + ch-means ----
__global__ __launch_bounds__(256) void k_gnup(const float* __restrict__ raw,
                                              float* __restrict__ fin,
                                              const float* __restrict__ stats,
                                              float* __restrict__ cmean,
                                              const float* __restrict__ gamma,
                                              const float* __restrict__ beta,
                                              int Hr, int Wr, int Hf, int Wf) {
    int HWf = Hf * Wf;
    int spn = (HWf + 63) >> 6;
    int n = blockIdx.x / spn;
    int p0 = (blockIdx.x % spn) << 6;
    int tid = threadIdx.x;
    int wv = tid >> 6, lane = tid & 63;
    int ch4 = lane << 2;
    int gg = lane >> 2;
    float cnt = 16.f * Hr * Wr;
    float s1 = stats[(n * 16 + gg) * 2], s2 = stats[(n * 16 + gg) * 2 + 1];
    float mu = s1 / cnt;
    float var = s2 / cnt - mu * mu;
    float rs = rsqrtf(var + 1e-5f);
    float4 g4 = *(const float4*)(gamma + ch4);
    float4 b4 = *(const float4*)(beta + ch4);
    float4 ga, be;
    ga.x = g4.x * rs; be.x = b4.x - mu * ga.x;
    ga.y = g4.y * rs; be.y = b4.y - mu * ga.y;
    ga.z = g4.z * rs; be.z = b4.z - mu * ga.z;
    ga.w = g4.w * rs; be.w = b4.w - mu * ga.w;
    bool up = (Hf != Hr);
    float sys = up ? (float)((double)(Hr - 1) / (double)(Hf - 1)) : 0.f;
    float sxs = up ? (float)((double)(Wr - 1) / (double)(Wf - 1)) : 0.f;
    float4 csum = {0.f, 0.f, 0.f, 0.f};
    __shared__ float cs[4][256];
    const float* rb = raw + (size_t)n * Hr * Wr * C_ + ch4;
    for (int i = wv; i < 64; i += 4) {
        int p = p0 + i;
        if (p < HWf) {
            float4 v;
            if (up) {
                int ho = p / Wf, wo = p % Wf;
                float sy = ho * sys, sx = wo * sxs;
                int y0 = (int)sy, x0 = (int)sx;
                float fy = sy - y0, fx = sx - x0;
                int y1 = min(y0 + 1, Hr - 1), x1 = min(x0 + 1, Wr - 1);
                float4 v00 = *(const float4*)(rb + (size_t)(y0 * Wr + x0) * C_);
                float4 v01 = *(const float4*)(rb + (size_t)(y0 * Wr + x1) * C_);
                float4 v10 = *(const float4*)(rb + (size_t)(y1 * Wr + x0) * C_);
                float4 v11 = *(const float4*)(rb + (size_t)(y1 * Wr + x1) * C_);
                v.x = (v00.x * (1.f - fy) + v10.x * fy) * (1.f - fx) + (v01.x * (1.f - fy) + v11.x * fy) * fx;
                v.y = (v00.y * (1.f - fy) + v10.y * fy) * (1.f - fx) + (v01.y * (1.f - fy) + v11.y * fy) * fx;
                v.z = (v00.z * (1.f - fy) + v10.z * fy) * (1.f - fx) + (v01.z * (1.f - fy) + v11.z * fy) * fx;
                v.w = (v00.w * (1.f - fy) + v10.w * fy) * (1.f - fx) + (v01.w * (1.f - fy) + v11.w * fy) * fx;
            } else {
                v = *(const float4*)(raw + ((size_t)n * HWf + p) * C_ + ch4);
            }
            float4 y4;
            y4.x = v.x * ga.x + be.x;
            y4.y = v.y * ga.y + be.y;
            y4.z = v.z * ga.z + be.z;
            y4.w = v.w * ga.w + be.w;
            *(float4*)(fin + ((size_t)n * HWf + p) * C_ + ch4) = y4;
            csum.x += y4.x; csum.y += y4.y; csum.z += y4.z; csum.w += y4.w;
        }
    }
    cs[wv][ch4 + 0] = csum.x;
    cs[wv][ch4 + 1] = csum.y;
    cs[wv][ch4 + 2] = csum.z;
    cs[wv][ch4 + 3] = csum.w;
    __syncthreads();
    if (wv == 0) {
        float t0 = 0.f, t1 = 0.f, t2 = 0.f, t3 = 0.f;
#pragma unroll
        for (int r = 0; r < 4; r++) {
            t0 += cs[r][ch4 + 0];
            t1 += cs[r][ch4 + 1];
            t2 += cs[r][ch4 + 2];
            t3 += cs[r][ch4 + 3];
        }
        atomicAdd(&cmean[n * C_ + ch4 + 0], t0);
        atomicAdd(&cmean[n * C_ + ch4 + 1], t1);
        atomicAdd(&cmean[n * C_ + ch4 + 2], t2);
        atomicAdd(&cmean[n * C_ + ch4 + 3], t3);
    }
}

// ---------------------------------- scale-attn combine + DyReLU + NCHW store ----
__global__ __launch_bounds__(256) void k_out(const float* __restrict__ fA,
                                             const float* __restrict__ fB,
                                             const float* __restrict__ fC,
                                             const float* __restrict__ cmA,
                                             const float* __restrict__ cmB,
                                             const float* __restrict__ cmC,
                                             int nf, float inv_nl,
                                             const float* __restrict__ sa_w,
                                             const float* __restrict__ sa_b,
                                             const float* __restrict__ fc1_w,
                                             const float* __restrict__ fc1_b,
                                             const float* __restrict__ fc2_w,
                                             const float* __restrict__ fc2_b,
                                             float* __restrict__ out, int H, int W) {
    int HW = H * W;
    int spn = (HW + 63) >> 6;
    int n = blockIdx.x / spn;
    int p0 = (blockIdx.x % spn) << 6;
    int c = threadIdx.x;
    __shared__ float red[256];
    __shared__ float meanv[256];
    __shared__ float hv[64];
    __shared__ float sa_a[3];
    __shared__ float ot[16 * 257];
    float inv_hw = 1.f / HW;
    const float* cms[3] = {cmA, cmB, cmC};
    float cm[3] = {0.f, 0.f, 0.f}, a[3] = {0.f, 0.f, 0.f};
    for (int f = 0; f < nf; f++) {
        cm[f] = cms[f][n * C_ + c] * inv_hw;
        red[c] = sa_w[c] * cm[f];
        __syncthreads();
        for (int s = 128; s; s >>= 1) {
            if (c < s) red[c] += red[c + s];
            __syncthreads();
        }
        if (c == 0) {
            float t = fmaxf(red[0] + sa_b[0], 0.f);
            sa_a[f] = fminf(fmaxf((t + 3.f) * (1.f / 6.f), 0.f), 1.f);
        }
        __syncthreads();
        a[f] = sa_a[f];
    }
    float mv = 0.f;
    for (int f = 0; f < nf; f++) mv += a[f] * cm[f];
    mv *= inv_nl;
    meanv[c] = mv;
    __syncthreads();
    int j = c & 63;
    float ha = fc1_b[j];
    for (int k = 0; k < 256; k++) ha += fc1_w[j * 256 + k] * meanv[k];
    if (c < 64) hv[c] = fmaxf(ha, 0.f);
    __syncthreads();
    float zz[4];
#pragma unroll
    for (int i = 0; i < 4; i++) {
        float z = fc2_b[i * 256 + c];
        for (int k = 0; k < 64; k++) z += fc2_w[(size_t)(i * 256 + c) * 64 + k] * hv[k];
        zz[i] = fminf(fmaxf(z + 3.f, 0.f), 6.f) * (1.f / 6.f);
    }
    float a1 = (zz[0] - 0.5f) * 2.f + 1.f;
    float b1 = zz[1] - 0.5f;
    float a2 = (zz[2] - 0.5f) * 2.f;
    float b2 = zz[3] - 0.5f;
    for (int chk = 0; chk < 4; chk++) {
        __syncthreads();
        for (int i = 0; i < 16; i++) {
            int p = p0 + chk * 16 + i;
            if (p >= HW) continue;
            float fv = a[0] * fA[((size_t)n * HW + p) * C_ + c];
            if (nf > 1) fv += a[1] * fB[((size_t)n * HW + p) * C_ + c];
            if (nf > 2) fv += a[2] * fC[((size_t)n * HW + p) * C_ + c];
            fv *= inv_nl;
            ot[i * 257 + c] = fmaxf(fv * a1 + b1, fv * a2 + b2);
        }
        __syncthreads();
        int px = c & 15, cr0 = c >> 4;
        for (int pass = 0; pass < 16; pass++) {
            int cc = pass * 16 + cr0;
            int p = p0 + chk * 16 + px;
            if (p < HW) out[((size_t)n * C_ + cc) * HW + p] = ot[px * 257 + cc];
        }
    }
}

// --------------------------------------------------------------------- host ----
extern "C" void kernel_launch(void* const* d_in, const int* in_sizes, int n_in,
                              void* d_out, int out_size, void* d_ws, size_t ws_size,
                              hipStream_t stream) {
    (void)in_sizes; (void)n_in; (void)out_size; (void)ws_size;
    const float* x0 = (const float*)d_in[0];
    const float* x1 = (const float*)d_in[1];
    const float* x2 = (const float*)d_in[2];
    const float* dw_w_h = (const float*)d_in[3];
    const float* dw_s_h = (const float*)d_in[4];
    const float* dw_b_h = (const float*)d_in[5];
    const float* dw_w_m = (const float*)d_in[6];
    const float* dw_s_m = (const float*)d_in[7];
    const float* dw_b_m = (const float*)d_in[8];
    const float* dw_w_l = (const float*)d_in[9];
    const float* dw_s_l = (const float*)d_in[10];
    const float* dw_b_l = (const float*)d_in[11];
    const float* off_w = (const float*)d_in[12];
    const float* off_b = (const float*)d_in[13];
    const float* gn_g_h = (const float*)d_in[14];
    const float* gn_b_h = (const float*)d_in[15];
    const float* gn_g_m = (const float*)d_in[16];
    const float* gn_b_m = (const float*)d_in[17];
    const float* gn_g_l = (const float*)d_in[18];
    const float* gn_b_l = (const float*)d_in[19];
    const float* sa_w = (const float*)d_in[20];
    const float* sa_b = (const float*)d_in[21];
    const float* fc1_w = (const float*)d_in[22];
    const float* fc1_b = (const float*)d_in[23];
    const float* fc2_w = (const float*)d_in[24];
    const float* fc2_b = (const float*)d_in[25];

    float* ws = (float*)d_ws;
    float* XT0 = ws + 0;              // 6553600
    float* XT1 = ws + 6553600;        // 1638400
    float* XT2 = ws + 8192000;        // 409600
    float* SH = ws + 8601600;         // 6553600 (bf16 dw out overlays / f32 raw)
    float* OFF = ws + 15155200;       // 1843200
    float* MSK = ws + 16998400;       // 921600
    float* FINA = ws + 17920000;      // 6553600
    float* FINB = ws + 24473600;      // 6553600
    float* FINC = ws + 31027200;      // 1638400
    float* WMF = ws + 32665600;       // 36864 (73728 bf16)
    float* DWT = ws + 32702464;       // 6912
    float* STATS = ws + 32709376;     // 896  (7 slots x 128)
    float* CMEAN = ws + 32710272;     // 7168 (7 slots x 1024)

    unsigned short* SHB = (unsigned short*)SH;
    unsigned short* WMFB = (unsigned short*)WMF;

    float* out0 = (float*)d_out;
    float* out1 = out0 + 6553600;
    float* out2 = out0 + 8192000;

    k_prep<<<(4 * 32 * 576 + 6912 + 8064 + 255) / 256, 256, 0, stream>>>(
        off_w, dw_w_h, dw_w_m, dw_w_l, WMFB, DWT, STATS);

    k_transpose<<<dim3(4 * 80, 3, 8), 256, 0, stream>>>(x0, XT0, 80, 80);
    k_transpose<<<dim3(4 * 40, 2, 8), 256, 0, stream>>>(x1, XT1, 40, 40);
    k_transpose<<<dim3(4 * 20, 1, 8), 256, 0, stream>>>(x2, XT2, 20, 20);

    auto run_feat = [&](const float* xt, int Hs, int Ws, int stride, bool softmax,
                        const float* dwt, const float* dws, const float* dwb,
                        const float* gng, const float* gnb, int slot, float* fin, int Hf,
                        int Wf) {
        int Ho = Hs / stride, Wo = Ws / stride;
        k_dw_silu<<<4 * Hs * Ws / 4, 256, 0, stream>>>(xt, dwt, dws, dwb, SHB, Hs, Ws);
        if (stride == 1) {
            if (Hs >= 40) {
                if (softmax)
                    k_offmask<1, true, 8, 8><<<dim3(4, Ho / 8, Wo / 8), 256, 0, stream>>>(
                        SHB, WMFB, off_b, OFF, MSK, Hs, Ws, Ho, Wo);
                else
                    k_offmask<1, false, 8, 8><<<dim3(4, Ho / 8, Wo / 8), 256, 0, stream>>>(
                        SHB, WMFB, off_b, OFF, MSK, Hs, Ws, Ho, Wo);
            } else {
                if (softmax)
                    k_offmask<1, true, 4, 4><<<dim3(4, Ho / 4, Wo / 4), 256, 0, stream>>>(
                        SHB, WMFB, off_b, OFF, MSK, Hs, Ws, Ho, Wo);
                else
                    k_offmask<1, false, 4, 4><<<dim3(4, Ho / 4, Wo / 4), 256, 0, stream>>>(
                        SHB, WMFB, off_b, OFF, MSK, Hs, Ws, Ho, Wo);
            }
        } else {
            k_offmask<2, true, 4, 4><<<dim3(4, Ho / 4, Wo / 4), 256, 0, stream>>>(
                SHB, WMFB, off_b, OFF, MSK, Hs, Ws, Ho, Wo);
        }
        k_sample<<<4 * Ho * Wo / 4, 256, 0, stream>>>(xt, OFF, MSK, SH, STATS + slot * 128,
                                                      Hs, Ws, Ho, Wo, stride);
        int spn = (Hf * Wf + 63) / 64;
        k_gnup<<<4 * spn, 256, 0, stream>>>(SH, fin, STATS + slot * 128, CMEAN + slot * 1024,
                                            gng, gnb, Ho, Wo, Hf, Wf);
    };

    // ---- level 0 (80x80): mid(x0) + high(x1 up) ----
    run_feat(XT0, 80, 80, 1, false, DWT + 1 * 2304, dw_s_m, dw_b_m, gn_g_m, gn_b_m, 0, FINA, 80, 80);
    run_feat(XT1, 40, 40, 1, true, DWT + 0 * 2304, dw_s_h, dw_b_h, gn_g_h, gn_b_h, 1, FINB, 80, 80);
    k_out<<<4 * 100, 256, 0, stream>>>(FINA, FINB, nullptr, CMEAN, CMEAN + 1024, nullptr, 2,
                                       0.5f, sa_w, sa_b, fc1_w, fc1_b, fc2_w, fc2_b, out0, 80,
                                       80);
    // ---- level 1 (40x40): mid(x1) + low(x0 s2) + high(x2 up) ----
    run_feat(XT1, 40, 40, 1, false, DWT + 1 * 2304, dw_s_m, dw_b_m, gn_g_m, gn_b_m, 2, FINA, 40, 40);
    run_feat(XT0, 80, 80, 2, true, DWT + 2 * 2304, dw_s_l, dw_b_l, gn_g_l, gn_b_l, 3, FINB, 40, 40);
    run_feat(XT2, 20, 20, 1, true, DWT + 0 * 2304, dw_s_h, dw_b_h, gn_g_h, gn_b_h, 4, FINC, 40, 40);
    k_out<<<4 * 25, 256, 0, stream>>>(FINA, FINB, FINC, CMEAN + 2 * 1024, CMEAN + 3 * 1024,
                                      CMEAN + 4 * 1024, 3, 1.f / 3.f, sa_w, sa_b, fc1_w,
                                      fc1_b, fc2_w, fc2_b, out1, 40, 40);
    // ---- level 2 (20x20): mid(x2) + low(x1 s2) ----
    run_feat(XT2, 20, 20, 1, false, DWT + 1 * 2304, dw_s_m, dw_b_m, gn_g_m, gn_b_m, 5, FINA, 20, 20);
    run_feat(XT1, 40, 40, 2, true, DWT + 2 * 2304, dw_s_l, dw_b_l, gn_g_l, gn_b_l, 6, FINB, 20, 20);
    k_out<<<4 * 7, 256, 0, stream>>>(FINA, FINB, nullptr, CMEAN + 5 * 1024, CMEAN + 6 * 1024,
                                     nullptr, 2, 0.5f, sa_w, sa_b, fc1_w, fc1_b, fc2_w, fc2_b,
                                     out2, 20, 20);
}

// Round 5
// 814.250 us; speedup vs baseline: 2.3146x; 1.0179x over previous
//
#include <hip/hip_runtime.h>
#include <hip/hip_bf16.h>

#define C_ 256
#define G_ 4

typedef __attribute__((ext_vector_type(8))) short bf16x8;
typedef __attribute__((ext_vector_type(4))) float f32x4;

static __device__ __forceinline__ unsigned short f2bf(float x) {
    __hip_bfloat16 h = __float2bfloat16(x);
    return *(unsigned short*)&h;
}

// ---------------------------------------------------------------- prep ----
// wmf: bf16 MFMA-A-layout weights [g][32 oc-padded][576 k], k = tap*64+ic.
// dwt: depthwise weights transposed to [9][256] for h/m/l. zeros: STATS+CMEAN.
__global__ void k_prep(const float* __restrict__ off_w, const float* __restrict__ dwh,
                       const float* __restrict__ dwm, const float* __restrict__ dwl,
                       unsigned short* __restrict__ wmf, float* __restrict__ dwt,
                       float* __restrict__ zeros) {
    int i = blockIdx.x * 256 + threadIdx.x;
    const int NWM = 4 * 32 * 576;
    if (i < NWM) {
        int g = i / (32 * 576), rem = i % (32 * 576);
        int ol = rem / 576, kk = rem % 576;
        int tap = kk / 64, ic = kk % 64;
        float v = (ol < 27) ? off_w[((size_t)((g * 27 + ol) * 64 + ic)) * 9 + tap] : 0.f;
        wmf[i] = f2bf(v);
    }
    int j = i - NWM;
    if (j >= 0 && j < 3 * 2304) {
        int which = j / 2304, rem = j % 2304;
        int t = rem / 256, c = rem % 256;
        const float* src = (which == 0) ? dwh : (which == 1) ? dwm : dwl;
        dwt[j] = src[c * 9 + t];
    }
    int z = i - NWM - 3 * 2304;
    if (z >= 0 && z < 8064) zeros[z] = 0.f;
}

// ------------------------------------------------------------ transpose ----
__global__ __launch_bounds__(256) void k_transpose(const float* __restrict__ x,
                                                   float* __restrict__ xt, int H, int W) {
    __shared__ float tile[32][33];
    int nh = blockIdx.x;
    int n = nh / H, h = nh % H;
    int w0 = blockIdx.y * 32, c0 = blockIdx.z * 32;
    int tid = threadIdx.x;
    int i = tid / 32, j = tid % 32;
#pragma unroll
    for (int r = 0; r < 4; r++) {
        int c = c0 + i + r * 8;
        int w = w0 + j;
        tile[i + r * 8][j] = (w < W) ? x[((size_t)(n * C_ + c) * H + h) * W + w] : 0.f;
    }
    __syncthreads();
    int wj = tid / 32, ci = tid % 32;
#pragma unroll
    for (int r = 0; r < 4; r++) {
        int w = w0 + wj + r * 8;
        if (w < W) xt[((size_t)(n * H + h) * W + w) * C_ + c0 + ci] = tile[ci][wj + r * 8];
    }
}

// -------------------------------------------------------- depthwise+SiLU ----
__global__ __launch_bounds__(256) void k_dw_silu(const float* __restrict__ xt,
                                                 const float* __restrict__ wdt,
                                                 const float* __restrict__ sc,
                                                 const float* __restrict__ bi,
                                                 unsigned short* __restrict__ out, int H,
                                                 int W) {
    int tid = threadIdx.x;
    int pw = tid >> 6, lane = tid & 63;
    int ch4 = lane << 2;
    int pix = blockIdx.x * 4 + pw;
    int w = pix % W, h = (pix / W) % H, n = pix / (W * H);
    const float4 s4 = *(const float4*)(sc + ch4);
    const float4 b4 = *(const float4*)(bi + ch4);
    const float* xb = xt + (size_t)n * H * W * C_ + ch4;
    float4 acc = {0.f, 0.f, 0.f, 0.f};
#pragma unroll
    for (int t = 0; t < 9; t++) {
        int hh = h + t / 3 - 1, ww = w + t % 3 - 1;
        if (hh >= 0 && hh < H && ww >= 0 && ww < W) {
            float4 wt = *(const float4*)(wdt + t * 256 + ch4);
            float4 xv = *(const float4*)(xb + (size_t)(hh * W + ww) * C_);
            acc.x += wt.x * xv.x;
            acc.y += wt.y * xv.y;
            acc.z += wt.z * xv.z;
            acc.w += wt.w * xv.w;
        }
    }
    float4 y;
    y.x = acc.x * s4.x + b4.x;
    y.y = acc.y * s4.y + b4.y;
    y.z = acc.z * s4.z + b4.z;
    y.w = acc.w * s4.w + b4.w;
    y.x = y.x / (1.f + __expf(-y.x));
    y.y = y.y / (1.f + __expf(-y.y));
    y.z = y.z / (1.f + __expf(-y.z));
    y.w = y.w / (1.f + __expf(-y.w));
    ushort4 o;
    o.x = f2bf(y.x);
    o.y = f2bf(y.y);
    o.z = f2bf(y.z);
    o.w = f2bf(y.w);
    *(ushort4*)(out + (size_t)pix * C_ + ch4) = o;
}

// ------------------------------------------------- grouped offset/mask conv ----
// MFMA bf16 GEMM + fused gather-metadata epilogue.
// Emits per (pixel,g,tap): float4 premultiplied bilinear weights (w*mask*valid)
// and ushort4 clamped flat source-pixel indices.
template <int STRIDE, bool SOFTMAX, int TH, int TW>
__global__ __launch_bounds__(256) void k_offmask(const unsigned short* __restrict__ dwb,
                                                 const unsigned short* __restrict__ wmf,
                                                 const float* __restrict__ bias,
                                                 float4* __restrict__ wmeta,
                                                 ushort4* __restrict__ imeta,
                                                 int Hs, int Ws, int Ho, int Wo) {
    constexpr int SR = STRIDE * (TH - 1) + 3;
    constexpr int SC = STRIDE * (TW - 1) + 3;
    constexpr int NV = SR * SC;
    constexpr int CP = 264;
    constexpr int TP = TH * TW;
    constexpr int NT = TP / 16;
    constexpr int MTW = 2 * NT;
    constexpr int PATCH_B = NV * CP * 2;
    constexpr int OMV_B = TP * 112 * 4;
    constexpr int LDS_B = PATCH_B > OMV_B ? PATCH_B : OMV_B;
    __shared__ __align__(16) char smem[LDS_B];
    unsigned short* patch = (unsigned short*)smem;
    float* omv = (float*)smem;

    int tid = threadIdx.x;
    int wv = tid >> 6, lane = tid & 63;
    int n16 = lane & 15, q = lane >> 4;
    int n = blockIdx.x;
    int ho0 = blockIdx.y * TH, wo0 = blockIdx.z * TW;
    int hs0 = ho0 * STRIDE - 1, ws0 = wo0 * STRIDE - 1;

    for (int idx = tid; idx < NV * 32; idx += 256) {
        int pp = idx >> 5;
        int c8 = (idx & 31) << 3;
        int hh = hs0 + pp / SC, ww = ws0 + pp % SC;
        uint4 v = {0u, 0u, 0u, 0u};
        if (hh >= 0 && hh < Hs && ww >= 0 && ww < Ws)
            v = *(const uint4*)(dwb + ((size_t)(n * Hs + hh) * Ws + ww) * C_ + c8);
        *(uint4*)(patch + pp * CP + c8) = v;
    }
    __syncthreads();

    int ntile = wv % NT;
    int mstart = (wv / NT) * MTW;
    int p = ntile * 16 + n16;
    int pr = p / TW, pc = p % TW;
    int pixbase = (pr * STRIDE) * SC + pc * STRIDE;
    int bchan = q << 3;

    f32x4 acc[MTW];
#pragma unroll
    for (int l = 0; l < MTW; l++) acc[l] = (f32x4){0.f, 0.f, 0.f, 0.f};

    for (int kk = 0; kk < 18; kk++) {
        int tap = kk >> 1;
        int ic0 = (kk & 1) << 5;
        int ty = tap / 3, tx = tap % 3;
        int ppix = pixbase + ty * SC + tx;
#pragma unroll
        for (int gi = 0; gi < MTW / 2; gi++) {
            int g = (mstart >> 1) + gi;
            bf16x8 b = *(const bf16x8*)(patch + ppix * CP + g * 64 + ic0 + bchan);
#pragma unroll
            for (int s = 0; s < 2; s++) {
                int row = g * 32 + s * 16 + n16;
                bf16x8 a = *(const bf16x8*)(wmf + (size_t)row * 576 + kk * 32 + bchan);
                acc[gi * 2 + s] =
                    __builtin_amdgcn_mfma_f32_16x16x32_bf16(a, b, acc[gi * 2 + s], 0, 0, 0);
            }
        }
    }
    __syncthreads();

#pragma unroll
    for (int l = 0; l < MTW; l++) {
        int mt = mstart + l;
        int g = mt >> 1;
        int olbase = (mt & 1) * 16 + q * 4;
#pragma unroll
        for (int r = 0; r < 4; r++) {
            int ol = olbase + r;
            if (ol < 27) omv[p * 112 + g * 27 + ol] = acc[l][r];
        }
    }
    __syncthreads();

    // metadata epilogue: one thread per (pixel, group)
    for (int flat = tid; flat < TP * G_; flat += 256) {
        int pp = flat >> 2, g = flat & 3;
        int ho = ho0 + pp / TW, wo = wo0 + pp % TW;
        size_t pix = (size_t)(n * Ho + ho) * Wo + wo;
        float mv[9];
        if (SOFTMAX) {
            float mx = -1e30f;
#pragma unroll
            for (int k = 0; k < 9; k++) {
                mv[k] = omv[pp * 112 + 72 + g * 9 + k] + bias[72 + g * 9 + k];
                mx = fmaxf(mx, mv[k]);
            }
            float ssum = 0.f;
#pragma unroll
            for (int k = 0; k < 9; k++) {
                mv[k] = __expf(mv[k] - mx);
                ssum += mv[k];
            }
            float inv = 1.f / ssum;
#pragma unroll
            for (int k = 0; k < 9; k++) mv[k] *= inv;
        } else {
#pragma unroll
            for (int k = 0; k < 9; k++) {
                float v = omv[pp * 112 + 72 + g * 9 + k] + bias[72 + g * 9 + k];
                mv[k] = 1.f / (1.f + __expf(-v));
            }
        }
#pragma unroll
        for (int k = 0; k < 9; k++) {
            float oy = omv[pp * 112 + g * 18 + 2 * k] + bias[g * 18 + 2 * k];
            float ox = omv[pp * 112 + g * 18 + 2 * k + 1] + bias[g * 18 + 2 * k + 1];
            float py = (float)(ho * STRIDE + k / 3 - 1) + oy;
            float px = (float)(wo * STRIDE + k % 3 - 1) + ox;
            float y0f = floorf(py), x0f = floorf(px);
            int y0 = (int)y0f, x0 = (int)x0f;
            float wy = py - y0f, wx = px - x0f;
            int y1 = y0 + 1, x1 = x0 + 1;
            float v0y = (y0 >= 0 && y0 < Hs) ? 1.f : 0.f;
            float v1y = (y1 >= 0 && y1 < Hs) ? 1.f : 0.f;
            float v0x = (x0 >= 0 && x0 < Ws) ? 1.f : 0.f;
            float v1x = (x1 >= 0 && x1 < Ws) ? 1.f : 0.f;
            int y0c = min(max(y0, 0), Hs - 1), y1c = min(max(y1, 0), Hs - 1);
            int x0c = min(max(x0, 0), Ws - 1), x1c = min(max(x1, 0), Ws - 1);
            float m_ = mv[k];
            float4 w4;
            w4.x = (1.f - wy) * (1.f - wx) * v0y * v0x * m_;
            w4.y = (1.f - wy) * wx * v0y * v1x * m_;
            w4.z = wy * (1.f - wx) * v1y * v0x * m_;
            w4.w = wy * wx * v1y * v1x * m_;
            ushort4 i4;
            i4.x = (unsigned short)(y0c * Ws + x0c);
            i4.y = (unsigned short)(y0c * Ws + x1c);
            i4.z = (unsigned short)(y1c * Ws + x0c);
            i4.w = (unsigned short)(y1c * Ws + x1c);
            wmeta[pix * 36 + g * 9 + k] = w4;
            imeta[pix * 36 + g * 9 + k] = i4;
        }
    }
}

// ------------------------------------------------------------- DCNv3 sample ----
// block = 256 thr = 4 waves; 8 pixels/block, wave handles 2 pixels interleaved.
// All weight/index math precomputed (meta); lane = 4 channels (float4).
__global__ __launch_bounds__(256) void k_sample(const float* __restrict__ xt,
                                                const float4* __restrict__ wmeta,
                                                const ushort4* __restrict__ imeta,
                                                float* __restrict__ raw,
                                                float* __restrict__ stats,
                                                int Hs, int Ws, int HoWo) {
    int tid = threadIdx.x;
    int wv = tid >> 6, lane = tid & 63;
    int g = lane >> 4;
    int ch4 = lane << 2;
    int pix0 = blockIdx.x * 8;
    int n = pix0 / HoWo;
    __shared__ float4 lw[288];
    __shared__ ushort4 li[288];
    __shared__ float lstat[32];
    const float4* wsrc = wmeta + (size_t)pix0 * 36;
    for (int idx = tid; idx < 288; idx += 256) lw[idx] = wsrc[idx];
    const uint4* isrc = (const uint4*)imeta + (size_t)pix0 * 18;
    if (tid < 144) ((uint4*)li)[tid] = isrc[tid];
    if (tid < 32) lstat[tid] = 0.f;
    __syncthreads();

    int pA = wv * 2, pB = wv * 2 + 1;
    const float* xb = xt + (size_t)n * Hs * Ws * C_ + ch4;
    float4 aA = {0.f, 0.f, 0.f, 0.f}, aB = {0.f, 0.f, 0.f, 0.f};
#pragma unroll
    for (int k = 0; k < 9; k++) {
        float4 wA = lw[pA * 36 + g * 9 + k];
        ushort4 iA = li[pA * 36 + g * 9 + k];
        float4 wB = lw[pB * 36 + g * 9 + k];
        ushort4 iB = li[pB * 36 + g * 9 + k];
        const float4 vA0 = *(const float4*)(xb + ((size_t)iA.x << 8));
        const float4 vA1 = *(const float4*)(xb + ((size_t)iA.y << 8));
        const float4 vA2 = *(const float4*)(xb + ((size_t)iA.z << 8));
        const float4 vA3 = *(const float4*)(xb + ((size_t)iA.w << 8));
        const float4 vB0 = *(const float4*)(xb + ((size_t)iB.x << 8));
        const float4 vB1 = *(const float4*)(xb + ((size_t)iB.y << 8));
        const float4 vB2 = *(const float4*)(xb + ((size_t)iB.z << 8));
        const float4 vB3 = *(const float4*)(xb + ((size_t)iB.w << 8));
        aA.x += wA.x * vA0.x + wA.y * vA1.x + wA.z * vA2.x + wA.w * vA3.x;
        aA.y += wA.x * vA0.y + wA.y * vA1.y + wA.z * vA2.y + wA.w * vA3.y;
        aA.z += wA.x * vA0.z + wA.y * vA1.z + wA.z * vA2.z + wA.w * vA3.z;
        aA.w += wA.x * vA0.w + wA.y * vA1.w + wA.z * vA2.w + wA.w * vA3.w;
        aB.x += wB.x * vB0.x + wB.y * vB1.x + wB.z * vB2.x + wB.w * vB3.x;
        aB.y += wB.x * vB0.y + wB.y * vB1.y + wB.z * vB2.y + wB.w * vB3.y;
        aB.z += wB.x * vB0.z + wB.y * vB1.z + wB.z * vB2.z + wB.w * vB3.z;
        aB.w += wB.x * vB0.w + wB.y * vB1.w + wB.z * vB2.w + wB.w * vB3.w;
    }
    *(float4*)(raw + (size_t)(pix0 + pA) * C_ + ch4) = aA;
    *(float4*)(raw + (size_t)(pix0 + pB) * C_ + ch4) = aB;
    float gs = aA.x + aA.y + aA.z + aA.w + aB.x + aB.y + aB.z + aB.w;
    float gss = aA.x * aA.x + aA.y * aA.y + aA.z * aA.z + aA.w * aA.w + aB.x * aB.x +
                aB.y * aB.y + aB.z * aB.z + aB.w * aB.w;
#pragma unroll
    for (int o = 2; o; o >>= 1) {
        gs += __shfl_down(gs, o, 4);
        gss += __shfl_down(gss, o, 4);
    }
    if ((lane & 3) == 0) {
        atomicAdd(&lstat[(lane >> 2) * 2 + 0], gs);
        atomicAdd(&lstat[(lane >> 2) * 2 + 1], gss);
    }
    __syncthreads();
    if (tid < 32) atomicAdd(&stats[n * 32 + tid], lstat[tid]);
}

// ----------------------------------------- GN affine (+bilinear up) + ch-means ----
__global__ __launch_bounds__(256) void k_gnup(const float* __restrict__ raw,
                                              float* __restrict__ fin,
                                              const float* __restrict__ stats,
                                              float* __restrict__ cmean,
                                              const float* __restrict__ gamma,
                                              const float* __restrict__ beta,
                                              int Hr, int Wr, int Hf, int Wf) {
    int HWf = Hf * Wf;
    int spn = (HWf + 63) >> 6;
    int n = blockIdx.x / spn;
    int p0 = (blockIdx.x % spn) << 6;
    int tid = threadIdx.x;
    int wv = tid >> 6, lane = tid & 63;
    int ch4 = lane << 2;
    int gg = lane >> 2;
    float cnt = 16.f * Hr * Wr;
    float s1 = stats[(n * 16 + gg) * 2], s2 = stats[(n * 16 + gg) * 2 + 1];
    float mu = s1 / cnt;
    float var = s2 / cnt - mu * mu;
    float rs = rsqrtf(var + 1e-5f);
    float4 g4 = *(const float4*)(gamma + ch4);
    float4 b4 = *(const float4*)(beta + ch4);
    float4 ga, be;
    ga.x = g4.x * rs; be.x = b4.x - mu * ga.x;
    ga.y = g4.y * rs; be.y = b4.y - mu * ga.y;
    ga.z = g4.z * rs; be.z = b4.z - mu * ga.z;
    ga.w = g4.w * rs; be.w = b4.w - mu * ga.w;
    bool up = (Hf != Hr);
    float sys = up ? (float)((double)(Hr - 1) / (double)(Hf - 1)) : 0.f;
    float sxs = up ? (float)((double)(Wr - 1) / (double)(Wf - 1)) : 0.f;
    float4 csum = {0.f, 0.f, 0.f, 0.f};
    __shared__ float cs[4][256];
    const float* rb = raw + (size_t)n * Hr * Wr * C_ + ch4;
    for (int i = wv; i < 64; i += 4) {
        int p = p0 + i;
        if (p < HWf) {
            float4 v;
            if (up) {
                int ho = p / Wf, wo = p % Wf;
                float sy = ho * sys, sx = wo * sxs;
                int y0 = (int)sy, x0 = (int)sx;
                float fy = sy - y0, fx = sx - x0;
                int y1 = min(y0 + 1, Hr - 1), x1 = min(x0 + 1, Wr - 1);
                float4 v00 = *(const float4*)(rb + (size_t)(y0 * Wr + x0) * C_);
                float4 v01 = *(const float4*)(rb + (size_t)(y0 * Wr + x1) * C_);
                float4 v10 = *(const float4*)(rb + (size_t)(y1 * Wr + x0) * C_);
                float4 v11 = *(const float4*)(rb + (size_t)(y1 * Wr + x1) * C_);
                v.x = (v00.x * (1.f - fy) + v10.x * fy) * (1.f - fx) + (v01.x * (1.f - fy) + v11.x * fy) * fx;
                v.y = (v00.y * (1.f - fy) + v10.y * fy) * (1.f - fx) + (v01.y * (1.f - fy) + v11.y * fy) * fx;
                v.z = (v00.z * (1.f - fy) + v10.z * fy) * (1.f - fx) + (v01.z * (1.f - fy) + v11.z * fy) * fx;
                v.w = (v00.w * (1.f - fy) + v10.w * fy) * (1.f - fx) + (v01.w * (1.f - fy) + v11.w * fy) * fx;
            } else {
                v = *(const float4*)(raw + ((size_t)n * HWf + p) * C_ + ch4);
            }
            float4 y4;
            y4.x = v.x * ga.x + be.x;
            y4.y = v.y * ga.y + be.y;
            y4.z = v.z * ga.z + be.z;
            y4.w = v.w * ga.w + be.w;
            *(float4*)(fin + ((size_t)n * HWf + p) * C_ + ch4) = y4;
            csum.x += y4.x; csum.y += y4.y; csum.z += y4.z; csum.w += y4.w;
        }
    }
    cs[wv][ch4 + 0] = csum.x;
    cs[wv][ch4 + 1] = csum.y;
    cs[wv][ch4 + 2] = csum.z;
    cs[wv][ch4 + 3] = csum.w;
    __syncthreads();
    if (wv == 0) {
        float t0 = 0.f, t1 = 0.f, t2 = 0.f, t3 = 0.f;
#pragma unroll
        for (int r = 0; r < 4; r++) {
            t0 += cs[r][ch4 + 0];
            t1 += cs[r][ch4 + 1];
            t2 += cs[r][ch4 + 2];
            t3 += cs[r][ch4 + 3];
        }
        atomicAdd(&cmean[n * C_ + ch4 + 0], t0);
        atomicAdd(&cmean[n * C_ + ch4 + 1], t1);
        atomicAdd(&cmean[n * C_ + ch4 + 2], t2);
        atomicAdd(&cmean[n * C_ + ch4 + 3], t3);
    }
}

// ---------------------------------- scale-attn combine + DyReLU + NCHW store ----
__global__ __launch_bounds__(256) void k_out(const float* __restrict__ fA,
                                             const float* __restrict__ fB,
                                             const float* __restrict__ fC,
                                             const float* __restrict__ cmA,
                                             const float* __restrict__ cmB,
                                             const float* __restrict__ cmC,
                                             int nf, float inv_nl,
                                             const float* __restrict__ sa_w,
                                             const float* __restrict__ sa_b,
                                             const float* __restrict__ fc1_w,
                                             const float* __restrict__ fc1_b,
                                             const float* __restrict__ fc2_w,
                                             const float* __restrict__ fc2_b,
                                             float* __restrict__ out, int H, int W) {
    int HW = H * W;
    int spn = (HW + 63) >> 6;
    int n = blockIdx.x / spn;
    int p0 = (blockIdx.x % spn) << 6;
    int c = threadIdx.x;
    __shared__ float red[256];
    __shared__ float meanv[256];
    __shared__ float hv[64];
    __shared__ float sa_a[3];
    __shared__ float ot[16 * 257];
    float inv_hw = 1.f / HW;
    const float* cms[3] = {cmA, cmB, cmC};
    float cm[3] = {0.f, 0.f, 0.f}, a[3] = {0.f, 0.f, 0.f};
    for (int f = 0; f < nf; f++) {
        cm[f] = cms[f][n * C_ + c] * inv_hw;
        red[c] = sa_w[c] * cm[f];
        __syncthreads();
        for (int s = 128; s; s >>= 1) {
            if (c < s) red[c] += red[c + s];
            __syncthreads();
        }
        if (c == 0) {
            float t = fmaxf(red[0] + sa_b[0], 0.f);
            sa_a[f] = fminf(fmaxf((t + 3.f) * (1.f / 6.f), 0.f), 1.f);
        }
        __syncthreads();
        a[f] = sa_a[f];
    }
    float mv = 0.f;
    for (int f = 0; f < nf; f++) mv += a[f] * cm[f];
    mv *= inv_nl;
    meanv[c] = mv;
    __syncthreads();
    int j = c & 63;
    float ha = fc1_b[j];
    for (int k = 0; k < 256; k++) ha += fc1_w[j * 256 + k] * meanv[k];
    if (c < 64) hv[c] = fmaxf(ha, 0.f);
    __syncthreads();
    float zz[4];
#pragma unroll
    for (int i = 0; i < 4; i++) {
        float z = fc2_b[i * 256 + c];
        for (int k = 0; k < 64; k++) z += fc2_w[(size_t)(i * 256 + c) * 64 + k] * hv[k];
        zz[i] = fminf(fmaxf(z + 3.f, 0.f), 6.f) * (1.f / 6.f);
    }
    float a1 = (zz[0] - 0.5f) * 2.f + 1.f;
    float b1 = zz[1] - 0.5f;
    float a2 = (zz[2] - 0.5f) * 2.f;
    float b2 = zz[3] - 0.5f;
    for (int chk = 0; chk < 4; chk++) {
        __syncthreads();
        for (int i = 0; i < 16; i++) {
            int p = p0 + chk * 16 + i;
            if (p >= HW) continue;
            float fv = a[0] * fA[((size_t)n * HW + p) * C_ + c];
            if (nf > 1) fv += a[1] * fB[((size_t)n * HW + p) * C_ + c];
            if (nf > 2) fv += a[2] * fC[((size_t)n * HW + p) * C_ + c];
            fv *= inv_nl;
            ot[i * 257 + c] = fmaxf(fv * a1 + b1, fv * a2 + b2);
        }
        __syncthreads();
        int px = c & 15, cr0 = c >> 4;
        for (int pass = 0; pass < 16; pass++) {
            int cc = pass * 16 + cr0;
            int p = p0 + chk * 16 + px;
            if (p < HW) out[((size_t)n * C_ + cc) * HW + p] = ot[px * 257 + cc];
        }
    }
}

// --------------------------------------------------------------------- host ----
extern "C" void kernel_launch(void* const* d_in, const int* in_sizes, int n_in,
                              void* d_out, int out_size, void* d_ws, size_t ws_size,
                              hipStream_t stream) {
    (void)in_sizes; (void)n_in; (void)out_size; (void)ws_size;
    const float* x0 = (const float*)d_in[0];
    const float* x1 = (const float*)d_in[1];
    const float* x2 = (const float*)d_in[2];
    const float* dw_w_h = (const float*)d_in[3];
    const float* dw_s_h = (const float*)d_in[4];
    const float* dw_b_h = (const float*)d_in[5];
    const float* dw_w_m = (const float*)d_in[6];
    const float* dw_s_m = (const float*)d_in[7];
    const float* dw_b_m = (const float*)d_in[8];
    const float* dw_w_l = (const float*)d_in[9];
    const float* dw_s_l = (const float*)d_in[10];
    const float* dw_b_l = (const float*)d_in[11];
    const float* off_w = (const float*)d_in[12];
    const float* off_b = (const float*)d_in[13];
    const float* gn_g_h = (const float*)d_in[14];
    const float* gn_b_h = (const float*)d_in[15];
    const float* gn_g_m = (const float*)d_in[16];
    const float* gn_b_m = (const float*)d_in[17];
    const float* gn_g_l = (const float*)d_in[18];
    const float* gn_b_l = (const float*)d_in[19];
    const float* sa_w = (const float*)d_in[20];
    const float* sa_b = (const float*)d_in[21];
    const float* fc1_w = (const float*)d_in[22];
    const float* fc1_b = (const float*)d_in[23];
    const float* fc2_w = (const float*)d_in[24];
    const float* fc2_b = (const float*)d_in[25];

    float* ws = (float*)d_ws;
    float* XT0 = ws + 0;              // 6553600
    float* XT1 = ws + 6553600;        // 1638400
    float* XT2 = ws + 8192000;        // 409600
    float* SH = ws + 8601600;         // 6553600 (bf16 dw out overlays / f32 raw)
    float* FINA = ws + 17920000;      // 6553600
    float* FINB = ws + 24473600;      // 6553600
    float* FINC = ws + 31027200;      // 1638400
    float* WMF = ws + 32665600;       // 36864 (73728 bf16)
    float* DWT = ws + 32702464;       // 6912
    float* STATS = ws + 32709376;     // 896  (7 slots x 128)
    float* CMEAN = ws + 32710272;     // 7168 (7 slots x 1024)

    unsigned short* SHB = (unsigned short*)SH;
    unsigned short* WMFB = (unsigned short*)WMF;

    float* out0 = (float*)d_out;
    float* out1 = out0 + 6553600;
    float* out2 = out0 + 8192000;

    // meta scratch carved from the (not-yet-written) output regions.
    // level L meta: wmeta = float4[maxpix*36] at outL, imeta = ushort4 after.
    float4* WM0 = (float4*)out0;
    ushort4* IM0 = (ushort4*)(out0 + 25600 * 144);  // 25600*216 = 5529600 <= 6553600
    float4* WM1 = (float4*)out1;
    ushort4* IM1 = (ushort4*)(out1 + 6400 * 144);   // 6400*216 = 1382400 <= 1638400
    float4* WM2 = (float4*)out2;
    ushort4* IM2 = (ushort4*)(out2 + 1600 * 144);   // 1600*216 = 345600 <= 409600

    k_prep<<<(4 * 32 * 576 + 6912 + 8064 + 255) / 256, 256, 0, stream>>>(
        off_w, dw_w_h, dw_w_m, dw_w_l, WMFB, DWT, STATS);

    k_transpose<<<dim3(4 * 80, 3, 8), 256, 0, stream>>>(x0, XT0, 80, 80);
    k_transpose<<<dim3(4 * 40, 2, 8), 256, 0, stream>>>(x1, XT1, 40, 40);
    k_transpose<<<dim3(4 * 20, 1, 8), 256, 0, stream>>>(x2, XT2, 20, 20);

    auto run_feat = [&](const float* xt, int Hs, int Ws, int stride, bool softmax,
                        const float* dwt, const float* dws, const float* dwb,
                        const float* gng, const float* gnb, int slot, float* fin, int Hf,
                        int Wf, float4* wm, ushort4* im) {
        int Ho = Hs / stride, Wo = Ws / stride;
        k_dw_silu<<<4 * Hs * Ws / 4, 256, 0, stream>>>(xt, dwt, dws, dwb, SHB, Hs, Ws);
        if (stride == 1) {
            if (Hs >= 40) {
                if (softmax)
                    k_offmask<1, true, 8, 8><<<dim3(4, Ho / 8, Wo / 8), 256, 0, stream>>>(
                        SHB, WMFB, off_b, wm, im, Hs, Ws, Ho, Wo);
                else
                    k_offmask<1, false, 8, 8><<<dim3(4, Ho / 8, Wo / 8), 256, 0, stream>>>(
                        SHB, WMFB, off_b, wm, im, Hs, Ws, Ho, Wo);
            } else {
                if (softmax)
                    k_offmask<1, true, 4, 4><<<dim3(4, Ho / 4, Wo / 4), 256, 0, stream>>>(
                        SHB, WMFB, off_b, wm, im, Hs, Ws, Ho, Wo);
                else
                    k_offmask<1, false, 4, 4><<<dim3(4, Ho / 4, Wo / 4), 256, 0, stream>>>(
                        SHB, WMFB, off_b, wm, im, Hs, Ws, Ho, Wo);
            }
        } else {
            k_offmask<2, true, 4, 4><<<dim3(4, Ho / 4, Wo / 4), 256, 0, stream>>>(
                SHB, WMFB, off_b, wm, im, Hs, Ws, Ho, Wo);
        }
        k_sample<<<4 * Ho * Wo / 8, 256, 0, stream>>>(xt, wm, im, SH, STATS + slot * 128,
                                                      Hs, Ws, Ho * Wo);
        int spn = (Hf * Wf + 63) / 64;
        k_gnup<<<4 * spn, 256, 0, stream>>>(SH, fin, STATS + slot * 128, CMEAN + slot * 1024,
                                            gng, gnb, Ho, Wo, Hf, Wf);
    };

    // ---- level 0 (80x80): mid(x0) + high(x1 up) ----
    run_feat(XT0, 80, 80, 1, false, DWT + 1 * 2304, dw_s_m, dw_b_m, gn_g_m, gn_b_m, 0, FINA,
             80, 80, WM0, IM0);
    run_feat(XT1, 40, 40, 1, true, DWT + 0 * 2304, dw_s_h, dw_b_h, gn_g_h, gn_b_h, 1, FINB,
             80, 80, WM0, IM0);
    k_out<<<4 * 100, 256, 0, stream>>>(FINA, FINB, nullptr, CMEAN, CMEAN + 1024, nullptr, 2,
                                       0.5f, sa_w, sa_b, fc1_w, fc1_b, fc2_w, fc2_b, out0, 80,
                                       80);
    // ---- level 1 (40x40): mid(x1) + low(x0 s2) + high(x2 up) ----
    run_feat(XT1, 40, 40, 1, false, DWT + 1 * 2304, dw_s_m, dw_b_m, gn_g_m, gn_b_m, 2, FINA,
             40, 40, WM1, IM1);
    run_feat(XT0, 80, 80, 2, true, DWT + 2 * 2304, dw_s_l, dw_b_l, gn_g_l, gn_b_l, 3, FINB,
             40, 40, WM1, IM1);
    run_feat(XT2, 20, 20, 1, true, DWT + 0 * 2304, dw_s_h, dw_b_h, gn_g_h, gn_b_h, 4, FINC,
             40, 40, WM1, IM1);
    k_out<<<4 * 25, 256, 0, stream>>>(FINA, FINB, FINC, CMEAN + 2 * 1024, CMEAN + 3 * 1024,
                                      CMEAN + 4 * 1024, 3, 1.f / 3.f, sa_w, sa_b, fc1_w,
                                      fc1_b, fc2_w, fc2_b, out1, 40, 40);
    // ---- level 2 (20x20): mid(x2) + low(x1 s2) ----
    run_feat(XT2, 20, 20, 1, false, DWT + 1 * 2304, dw_s_m, dw_b_m, gn_g_m, gn_b_m, 5, FINA,
             20, 20, WM2, IM2);
    run_feat(XT1, 40, 40, 2, true, DWT + 2 * 2304, dw_s_l, dw_b_l, gn_g_l, gn_b_l, 6, FINB,
             20, 20, WM2, IM2);
    k_out<<<4 * 7, 256, 0, stream>>>(FINA, FINB, nullptr, CMEAN + 5 * 1024, CMEAN + 6 * 1024,
                                     nullptr, 2, 0.5f, sa_w, sa_b, fc1_w, fc1_b, fc2_w, fc2_b,
                                     out2, 20, 20);
}

// Round 6
// 688.769 us; speedup vs baseline: 2.7363x; 1.1822x over previous
//
#include <hip/hip_runtime.h>
#include <hip/hip_bf16.h>

#define C_ 256
#define G_ 4

typedef __attribute__((ext_vector_type(8))) short bf16x8;
typedef __attribute__((ext_vector_type(4))) float f32x4;

static __device__ __forceinline__ unsigned short f2bf(float x) {
    __hip_bfloat16 h = __float2bfloat16(x);
    return *(unsigned short*)&h;
}

// ---------------------------------------------------------------- prep ----
__global__ void k_prep(const float* __restrict__ off_w, const float* __restrict__ dwh,
                       const float* __restrict__ dwm, const float* __restrict__ dwl,
                       unsigned short* __restrict__ wmf, float* __restrict__ dwt,
                       float* __restrict__ zeros) {
    int i = blockIdx.x * 256 + threadIdx.x;
    const int NWM = 4 * 32 * 576;
    if (i < NWM) {
        int g = i / (32 * 576), rem = i % (32 * 576);
        int ol = rem / 576, kk = rem % 576;
        int tap = kk / 64, ic = kk % 64;
        float v = (ol < 27) ? off_w[((size_t)((g * 27 + ol) * 64 + ic)) * 9 + tap] : 0.f;
        wmf[i] = f2bf(v);
    }
    int j = i - NWM;
    if (j >= 0 && j < 3 * 2304) {
        int which = j / 2304, rem = j % 2304;
        int t = rem / 256, c = rem % 256;
        const float* src = (which == 0) ? dwh : (which == 1) ? dwm : dwl;
        dwt[j] = src[c * 9 + t];
    }
    int z = i - NWM - 3 * 2304;
    if (z >= 0 && z < 8064) zeros[z] = 0.f;
}

// ------------------------------------------------------------ transpose ----
__global__ __launch_bounds__(256) void k_transpose(const float* __restrict__ x,
                                                   float* __restrict__ xt, int H, int W) {
    __shared__ float tile[32][33];
    int nh = blockIdx.x;
    int n = nh / H, h = nh % H;
    int w0 = blockIdx.y * 32, c0 = blockIdx.z * 32;
    int tid = threadIdx.x;
    int i = tid / 32, j = tid % 32;
#pragma unroll
    for (int r = 0; r < 4; r++) {
        int c = c0 + i + r * 8;
        int w = w0 + j;
        tile[i + r * 8][j] = (w < W) ? x[((size_t)(n * C_ + c) * H + h) * W + w] : 0.f;
    }
    __syncthreads();
    int wj = tid / 32, ci = tid % 32;
#pragma unroll
    for (int r = 0; r < 4; r++) {
        int w = w0 + wj + r * 8;
        if (w < W) xt[((size_t)(n * H + h) * W + w) * C_ + c0 + ci] = tile[ci][wj + r * 8];
    }
}

// -------------------------------------------------------- depthwise+SiLU ----
__global__ __launch_bounds__(256) void k_dw_silu(const float* __restrict__ xt,
                                                 const float* __restrict__ wdt,
                                                 const float* __restrict__ sc,
                                                 const float* __restrict__ bi,
                                                 unsigned short* __restrict__ out, int H,
                                                 int W) {
    int tid = threadIdx.x;
    int pw = tid >> 6, lane = tid & 63;
    int ch4 = lane << 2;
    int pix = blockIdx.x * 4 + pw;
    int w = pix % W, h = (pix / W) % H, n = pix / (W * H);
    const float4 s4 = *(const float4*)(sc + ch4);
    const float4 b4 = *(const float4*)(bi + ch4);
    const float* xb = xt + (size_t)n * H * W * C_ + ch4;
    float4 acc = {0.f, 0.f, 0.f, 0.f};
#pragma unroll
    for (int t = 0; t < 9; t++) {
        int hh = h + t / 3 - 1, ww = w + t % 3 - 1;
        if (hh >= 0 && hh < H && ww >= 0 && ww < W) {
            float4 wt = *(const float4*)(wdt + t * 256 + ch4);
            float4 xv = *(const float4*)(xb + (size_t)(hh * W + ww) * C_);
            acc.x += wt.x * xv.x;
            acc.y += wt.y * xv.y;
            acc.z += wt.z * xv.z;
            acc.w += wt.w * xv.w;
        }
    }
    float4 y;
    y.x = acc.x * s4.x + b4.x;
    y.y = acc.y * s4.y + b4.y;
    y.z = acc.z * s4.z + b4.z;
    y.w = acc.w * s4.w + b4.w;
    y.x = y.x / (1.f + __expf(-y.x));
    y.y = y.y / (1.f + __expf(-y.y));
    y.z = y.z / (1.f + __expf(-y.z));
    y.w = y.w / (1.f + __expf(-y.w));
    ushort4 o;
    o.x = f2bf(y.x);
    o.y = f2bf(y.y);
    o.z = f2bf(y.z);
    o.w = f2bf(y.w);
    *(ushort4*)(out + (size_t)pix * C_ + ch4) = o;
}

// ------------------------------------------------- grouped offset/mask conv ----
template <int STRIDE, bool SOFTMAX, int TH, int TW>
__global__ __launch_bounds__(256) void k_offmask(const unsigned short* __restrict__ dwb,
                                                 const unsigned short* __restrict__ wmf,
                                                 const float* __restrict__ bias,
                                                 float4* __restrict__ wmeta,
                                                 ushort4* __restrict__ imeta,
                                                 int Hs, int Ws, int Ho, int Wo) {
    constexpr int SR = STRIDE * (TH - 1) + 3;
    constexpr int SC = STRIDE * (TW - 1) + 3;
    constexpr int NV = SR * SC;
    constexpr int CP = 264;
    constexpr int TP = TH * TW;
    constexpr int NT = TP / 16;
    constexpr int MTW = 2 * NT;
    constexpr int PATCH_B = NV * CP * 2;
    constexpr int OMV_B = TP * 112 * 4;
    constexpr int LDS_B = PATCH_B > OMV_B ? PATCH_B : OMV_B;
    __shared__ __align__(16) char smem[LDS_B];
    unsigned short* patch = (unsigned short*)smem;
    float* omv = (float*)smem;

    int tid = threadIdx.x;
    int wv = tid >> 6, lane = tid & 63;
    int n16 = lane & 15, q = lane >> 4;
    int n = blockIdx.x;
    int ho0 = blockIdx.y * TH, wo0 = blockIdx.z * TW;
    int hs0 = ho0 * STRIDE - 1, ws0 = wo0 * STRIDE - 1;

    for (int idx = tid; idx < NV * 32; idx += 256) {
        int pp = idx >> 5;
        int c8 = (idx & 31) << 3;
        int hh = hs0 + pp / SC, ww = ws0 + pp % SC;
        uint4 v = {0u, 0u, 0u, 0u};
        if (hh >= 0 && hh < Hs && ww >= 0 && ww < Ws)
            v = *(const uint4*)(dwb + ((size_t)(n * Hs + hh) * Ws + ww) * C_ + c8);
        *(uint4*)(patch + pp * CP + c8) = v;
    }
    __syncthreads();

    int ntile = wv % NT;
    int mstart = (wv / NT) * MTW;
    int p = ntile * 16 + n16;
    int pr = p / TW, pc = p % TW;
    int pixbase = (pr * STRIDE) * SC + pc * STRIDE;
    int bchan = q << 3;

    f32x4 acc[MTW];
#pragma unroll
    for (int l = 0; l < MTW; l++) acc[l] = (f32x4){0.f, 0.f, 0.f, 0.f};

    for (int kk = 0; kk < 18; kk++) {
        int tap = kk >> 1;
        int ic0 = (kk & 1) << 5;
        int ty = tap / 3, tx = tap % 3;
        int ppix = pixbase + ty * SC + tx;
#pragma unroll
        for (int gi = 0; gi < MTW / 2; gi++) {
            int g = (mstart >> 1) + gi;
            bf16x8 b = *(const bf16x8*)(patch + ppix * CP + g * 64 + ic0 + bchan);
#pragma unroll
            for (int s = 0; s < 2; s++) {
                int row = g * 32 + s * 16 + n16;
                bf16x8 a = *(const bf16x8*)(wmf + (size_t)row * 576 + kk * 32 + bchan);
                acc[gi * 2 + s] =
                    __builtin_amdgcn_mfma_f32_16x16x32_bf16(a, b, acc[gi * 2 + s], 0, 0, 0);
            }
        }
    }
    __syncthreads();

#pragma unroll
    for (int l = 0; l < MTW; l++) {
        int mt = mstart + l;
        int g = mt >> 1;
        int olbase = (mt & 1) * 16 + q * 4;
#pragma unroll
        for (int r = 0; r < 4; r++) {
            int ol = olbase + r;
            if (ol < 27) omv[p * 112 + g * 27 + ol] = acc[l][r];
        }
    }
    __syncthreads();

    for (int flat = tid; flat < TP * G_; flat += 256) {
        int pp = flat >> 2, g = flat & 3;
        int ho = ho0 + pp / TW, wo = wo0 + pp % TW;
        size_t pix = (size_t)(n * Ho + ho) * Wo + wo;
        float mv[9];
        if (SOFTMAX) {
            float mx = -1e30f;
#pragma unroll
            for (int k = 0; k < 9; k++) {
                mv[k] = omv[pp * 112 + 72 + g * 9 + k] + bias[72 + g * 9 + k];
                mx = fmaxf(mx, mv[k]);
            }
            float ssum = 0.f;
#pragma unroll
            for (int k = 0; k < 9; k++) {
                mv[k] = __expf(mv[k] - mx);
                ssum += mv[k];
            }
            float inv = 1.f / ssum;
#pragma unroll
            for (int k = 0; k < 9; k++) mv[k] *= inv;
        } else {
#pragma unroll
            for (int k = 0; k < 9; k++) {
                float v = omv[pp * 112 + 72 + g * 9 + k] + bias[72 + g * 9 + k];
                mv[k] = 1.f / (1.f + __expf(-v));
            }
        }
#pragma unroll
        for (int k = 0; k < 9; k++) {
            float oy = omv[pp * 112 + g * 18 + 2 * k] + bias[g * 18 + 2 * k];
            float ox = omv[pp * 112 + g * 18 + 2 * k + 1] + bias[g * 18 + 2 * k + 1];
            float py = (float)(ho * STRIDE + k / 3 - 1) + oy;
            float px = (float)(wo * STRIDE + k % 3 - 1) + ox;
            float y0f = floorf(py), x0f = floorf(px);
            int y0 = (int)y0f, x0 = (int)x0f;
            float wy = py - y0f, wx = px - x0f;
            int y1 = y0 + 1, x1 = x0 + 1;
            float v0y = (y0 >= 0 && y0 < Hs) ? 1.f : 0.f;
            float v1y = (y1 >= 0 && y1 < Hs) ? 1.f : 0.f;
            float v0x = (x0 >= 0 && x0 < Ws) ? 1.f : 0.f;
            float v1x = (x1 >= 0 && x1 < Ws) ? 1.f : 0.f;
            int y0c = min(max(y0, 0), Hs - 1), y1c = min(max(y1, 0), Hs - 1);
            int x0c = min(max(x0, 0), Ws - 1), x1c = min(max(x1, 0), Ws - 1);
            float m_ = mv[k];
            float4 w4;
            w4.x = (1.f - wy) * (1.f - wx) * v0y * v0x * m_;
            w4.y = (1.f - wy) * wx * v0y * v1x * m_;
            w4.z = wy * (1.f - wx) * v1y * v0x * m_;
            w4.w = wy * wx * v1y * v1x * m_;
            ushort4 i4;
            i4.x = (unsigned short)(y0c * Ws + x0c);
            i4.y = (unsigned short)(y0c * Ws + x1c);
            i4.z = (unsigned short)(y1c * Ws + x0c);
            i4.w = (unsigned short)(y1c * Ws + x1c);
            wmeta[pix * 36 + g * 9 + k] = w4;
            imeta[pix * 36 + g * 9 + k] = i4;
        }
    }
}

// ------------------------------------------------------------- DCNv3 sample ----
__global__ __launch_bounds__(256) void k_sample(const float* __restrict__ xt,
                                                const float4* __restrict__ wmeta,
                                                const ushort4* __restrict__ imeta,
                                                float* __restrict__ raw,
                                                float* __restrict__ stats,
                                                int Hs, int Ws, int HoWo) {
    int tid = threadIdx.x;
    int wv = tid >> 6, lane = tid & 63;
    int g = lane >> 4;
    int ch4 = lane << 2;
    int pix0 = blockIdx.x * 8;
    int n = pix0 / HoWo;
    __shared__ float4 lw[288];
    __shared__ ushort4 li[288];
    __shared__ float lstat[32];
    const float4* wsrc = wmeta + (size_t)pix0 * 36;
    for (int idx = tid; idx < 288; idx += 256) lw[idx] = wsrc[idx];
    const uint4* isrc = (const uint4*)imeta + (size_t)pix0 * 18;
    if (tid < 144) ((uint4*)li)[tid] = isrc[tid];
    if (tid < 32) lstat[tid] = 0.f;
    __syncthreads();

    int pA = wv * 2, pB = wv * 2 + 1;
    const float* xb = xt + (size_t)n * Hs * Ws * C_ + ch4;
    float4 aA = {0.f, 0.f, 0.f, 0.f}, aB = {0.f, 0.f, 0.f, 0.f};
#pragma unroll
    for (int k = 0; k < 9; k++) {
        float4 wA = lw[pA * 36 + g * 9 + k];
        ushort4 iA = li[pA * 36 + g * 9 + k];
        float4 wB = lw[pB * 36 + g * 9 + k];
        ushort4 iB = li[pB * 36 + g * 9 + k];
        const float4 vA0 = *(const float4*)(xb + ((size_t)iA.x << 8));
        const float4 vA1 = *(const float4*)(xb + ((size_t)iA.y << 8));
        const float4 vA2 = *(const float4*)(xb + ((size_t)iA.z << 8));
        const float4 vA3 = *(const float4*)(xb + ((size_t)iA.w << 8));
        const float4 vB0 = *(const float4*)(xb + ((size_t)iB.x << 8));
        const float4 vB1 = *(const float4*)(xb + ((size_t)iB.y << 8));
        const float4 vB2 = *(const float4*)(xb + ((size_t)iB.z << 8));
        const float4 vB3 = *(const float4*)(xb + ((size_t)iB.w << 8));
        aA.x += wA.x * vA0.x + wA.y * vA1.x + wA.z * vA2.x + wA.w * vA3.x;
        aA.y += wA.x * vA0.y + wA.y * vA1.y + wA.z * vA2.y + wA.w * vA3.y;
        aA.z += wA.x * vA0.z + wA.y * vA1.z + wA.z * vA2.z + wA.w * vA3.z;
        aA.w += wA.x * vA0.w + wA.y * vA1.w + wA.z * vA2.w + wA.w * vA3.w;
        aB.x += wB.x * vB0.x + wB.y * vB1.x + wB.z * vB2.x + wB.w * vB3.x;
        aB.y += wB.x * vB0.y + wB.y * vB1.y + wB.z * vB2.y + wB.w * vB3.y;
        aB.z += wB.x * vB0.z + wB.y * vB1.z + wB.z * vB2.z + wB.w * vB3.z;
        aB.w += wB.x * vB0.w + wB.y * vB1.w + wB.z * vB2.w + wB.w * vB3.w;
    }
    *(float4*)(raw + (size_t)(pix0 + pA) * C_ + ch4) = aA;
    *(float4*)(raw + (size_t)(pix0 + pB) * C_ + ch4) = aB;
    float gs = aA.x + aA.y + aA.z + aA.w + aB.x + aB.y + aB.z + aB.w;
    float gss = aA.x * aA.x + aA.y * aA.y + aA.z * aA.z + aA.w * aA.w + aB.x * aB.x +
                aB.y * aB.y + aB.z * aB.z + aB.w * aB.w;
#pragma unroll
    for (int o = 2; o; o >>= 1) {
        gs += __shfl_down(gs, o, 4);
        gss += __shfl_down(gss, o, 4);
    }
    if ((lane & 3) == 0) {
        atomicAdd(&lstat[(lane >> 2) * 2 + 0], gs);
        atomicAdd(&lstat[(lane >> 2) * 2 + 1], gss);
    }
    __syncthreads();
    if (tid < 32) atomicAdd(&stats[n * 32 + tid], lstat[tid]);
}

// ----------------------------------------- GN affine (+bilinear up) + ch-means ----
__global__ __launch_bounds__(256) void k_gnup(const float* __restrict__ raw,
                                              float* __restrict__ fin,
                                              const float* __restrict__ stats,
                                              float* __restrict__ cmean,
                                              const float* __restrict__ gamma,
                                              const float* __restrict__ beta,
                                              int Hr, int Wr, int Hf, int Wf) {
    int HWf = Hf * Wf;
    int spn = (HWf + 63) >> 6;
    int n = blockIdx.x / spn;
    int p0 = (blockIdx.x % spn) << 6;
    int tid = threadIdx.x;
    int wv = tid >> 6, lane = tid & 63;
    int ch4 = lane << 2;
    int gg = lane >> 2;
    float cnt = 16.f * Hr * Wr;
    float s1 = stats[(n * 16 + gg) * 2], s2 = stats[(n * 16 + gg) * 2 + 1];
    float mu = s1 / cnt;
    float var = s2 / cnt - mu * mu;
    float rs = rsqrtf(var + 1e-5f);
    float4 g4 = *(const float4*)(gamma + ch4);
    float4 b4 = *(const float4*)(beta + ch4);
    float4 ga, be;
    ga.x = g4.x * rs; be.x = b4.x - mu * ga.x;
    ga.y = g4.y * rs; be.y = b4.y - mu * ga.y;
    ga.z = g4.z * rs; be.z = b4.z - mu * ga.z;
    ga.w = g4.w * rs; be.w = b4.w - mu * ga.w;
    bool up = (Hf != Hr);
    float sys = up ? (float)((double)(Hr - 1) / (double)(Hf - 1)) : 0.f;
    float sxs = up ? (float)((double)(Wr - 1) / (double)(Wf - 1)) : 0.f;
    float4 csum = {0.f, 0.f, 0.f, 0.f};
    __shared__ float cs[4][256];
    const float* rb = raw + (size_t)n * Hr * Wr * C_ + ch4;
    for (int i = wv; i < 64; i += 4) {
        int p = p0 + i;
        if (p < HWf) {
            float4 v;
            if (up) {
                int ho = p / Wf, wo = p % Wf;
                float sy = ho * sys, sx = wo * sxs;
                int y0 = (int)sy, x0 = (int)sx;
                float fy = sy - y0, fx = sx - x0;
                int y1 = min(y0 + 1, Hr - 1), x1 = min(x0 + 1, Wr - 1);
                float4 v00 = *(const float4*)(rb + (size_t)(y0 * Wr + x0) * C_);
                float4 v01 = *(const float4*)(rb + (size_t)(y0 * Wr + x1) * C_);
                float4 v10 = *(const float4*)(rb + (size_t)(y1 * Wr + x0) * C_);
                float4 v11 = *(const float4*)(rb + (size_t)(y1 * Wr + x1) * C_);
                v.x = (v00.x * (1.f - fy) + v10.x * fy) * (1.f - fx) + (v01.x * (1.f - fy) + v11.x * fy) * fx;
                v.y = (v00.y * (1.f - fy) + v10.y * fy) * (1.f - fx) + (v01.y * (1.f - fy) + v11.y * fy) * fx;
                v.z = (v00.z * (1.f - fy) + v10.z * fy) * (1.f - fx) + (v01.z * (1.f - fy) + v11.z * fy) * fx;
                v.w = (v00.w * (1.f - fy) + v10.w * fy) * (1.f - fx) + (v01.w * (1.f - fy) + v11.w * fy) * fx;
            } else {
                v = *(const float4*)(raw + ((size_t)n * HWf + p) * C_ + ch4);
            }
            float4 y4;
            y4.x = v.x * ga.x + be.x;
            y4.y = v.y * ga.y + be.y;
            y4.z = v.z * ga.z + be.z;
            y4.w = v.w * ga.w + be.w;
            *(float4*)(fin + ((size_t)n * HWf + p) * C_ + ch4) = y4;
            csum.x += y4.x; csum.y += y4.y; csum.z += y4.z; csum.w += y4.w;
        }
    }
    cs[wv][ch4 + 0] = csum.x;
    cs[wv][ch4 + 1] = csum.y;
    cs[wv][ch4 + 2] = csum.z;
    cs[wv][ch4 + 3] = csum.w;
    __syncthreads();
    if (wv == 0) {
        float t0 = 0.f, t1 = 0.f, t2 = 0.f, t3 = 0.f;
#pragma unroll
        for (int r = 0; r < 4; r++) {
            t0 += cs[r][ch4 + 0];
            t1 += cs[r][ch4 + 1];
            t2 += cs[r][ch4 + 2];
            t3 += cs[r][ch4 + 3];
        }
        atomicAdd(&cmean[n * C_ + ch4 + 0], t0);
        atomicAdd(&cmean[n * C_ + ch4 + 1], t1);
        atomicAdd(&cmean[n * C_ + ch4 + 2], t2);
        atomicAdd(&cmean[n * C_ + ch4 + 3], t3);
    }
}

// ------------------------- per-(n,level) scale-attn + DyReLU coefficients ----
// grid = 4 blocks (one per n), 256 thr. Writes af[n][4] (= a_f * inv_nl) and
// coef[n][4*256] = {a1,b1,a2,b2} per channel.
__global__ __launch_bounds__(256) void k_coef(const float* __restrict__ cmA,
                                              const float* __restrict__ cmB,
                                              const float* __restrict__ cmC,
                                              int nf, float inv_nl, float inv_hw,
                                              const float* __restrict__ sa_w,
                                              const float* __restrict__ sa_b,
                                              const float* __restrict__ fc1_w,
                                              const float* __restrict__ fc1_b,
                                              const float* __restrict__ fc2_w,
                                              const float* __restrict__ fc2_b,
                                              float* __restrict__ coef,
                                              float* __restrict__ af) {
    int n = blockIdx.x;
    int c = threadIdx.x;
    __shared__ float red[256];
    __shared__ float meanv[256];
    __shared__ float hv[64];
    __shared__ float sa_a[3];
    const float* cms[3] = {cmA, cmB, cmC};
    float cm[3] = {0.f, 0.f, 0.f};
    for (int f = 0; f < nf; f++) {
        cm[f] = cms[f][n * C_ + c] * inv_hw;
        red[c] = sa_w[c] * cm[f];
        __syncthreads();
        for (int s = 128; s; s >>= 1) {
            if (c < s) red[c] += red[c + s];
            __syncthreads();
        }
        if (c == 0) {
            float t = fmaxf(red[0] + sa_b[0], 0.f);
            sa_a[f] = fminf(fmaxf((t + 3.f) * (1.f / 6.f), 0.f), 1.f);
        }
        __syncthreads();
    }
    float mv = 0.f;
    for (int f = 0; f < nf; f++) mv += sa_a[f] * cm[f];
    mv *= inv_nl;
    meanv[c] = mv;
    __syncthreads();
    int j = c >> 2, t = c & 3;
    float partial = 0.f;
    for (int k = t * 64; k < t * 64 + 64; k++) partial += fc1_w[j * 256 + k] * meanv[k];
    partial += __shfl_down(partial, 2, 4);
    partial += __shfl_down(partial, 1, 4);
    if (t == 0) hv[j] = fmaxf(partial + fc1_b[j], 0.f);
    __syncthreads();
    float zz[4];
#pragma unroll
    for (int i = 0; i < 4; i++) {
        float z = fc2_b[i * 256 + c];
        for (int k = 0; k < 64; k++) z += fc2_w[(size_t)(i * 256 + c) * 64 + k] * hv[k];
        zz[i] = fminf(fmaxf(z + 3.f, 0.f), 6.f) * (1.f / 6.f);
    }
    coef[n * 1024 + 0 * 256 + c] = (zz[0] - 0.5f) * 2.f + 1.f;
    coef[n * 1024 + 1 * 256 + c] = zz[1] - 0.5f;
    coef[n * 1024 + 2 * 256 + c] = (zz[2] - 0.5f) * 2.f;
    coef[n * 1024 + 3 * 256 + c] = zz[3] - 0.5f;
    if (c < 4) af[n * 4 + c] = (c < nf) ? sa_a[c] * inv_nl : 0.f;
}

// ------------------- streaming combine + DyReLU + NHWC->NCHW store ----
// grid = (4n, ceil(HW/64), 4 ch-chunks); block 256. 64pix x 64ch LDS tile.
__global__ __launch_bounds__(256) void k_store(const float* __restrict__ fA,
                                               const float* __restrict__ fB,
                                               const float* __restrict__ fC,
                                               int nf, const float* __restrict__ coef,
                                               const float* __restrict__ af,
                                               float* __restrict__ out, int HW) {
    __shared__ float tile[64][65];
    int n = blockIdx.x;
    int pt = blockIdx.y;
    int c0 = blockIdx.z * 64;
    int tid = threadIdx.x;
    int lane16 = tid & 15, prow = tid >> 4;
    int ch4 = c0 + lane16 * 4;
    float a0 = af[n * 4 + 0], a1f = af[n * 4 + 1], a2f = af[n * 4 + 2];
    float4 ca1 = *(const float4*)(coef + n * 1024 + 0 + ch4);
    float4 cb1 = *(const float4*)(coef + n * 1024 + 256 + ch4);
    float4 ca2 = *(const float4*)(coef + n * 1024 + 512 + ch4);
    float4 cb2 = *(const float4*)(coef + n * 1024 + 768 + ch4);
#pragma unroll
    for (int pass = 0; pass < 4; pass++) {
        int px = pass * 16 + prow;
        int p = pt * 64 + px;
        if (p < HW) {
            size_t base = ((size_t)n * HW + p) * C_ + ch4;
            float4 v = *(const float4*)(fA + base);
            float4 fv;
            fv.x = v.x * a0;
            fv.y = v.y * a0;
            fv.z = v.z * a0;
            fv.w = v.w * a0;
            if (nf > 1) {
                float4 vb = *(const float4*)(fB + base);
                fv.x += vb.x * a1f;
                fv.y += vb.y * a1f;
                fv.z += vb.z * a1f;
                fv.w += vb.w * a1f;
            }
            if (nf > 2) {
                float4 vc = *(const float4*)(fC + base);
                fv.x += vc.x * a2f;
                fv.y += vc.y * a2f;
                fv.z += vc.z * a2f;
                fv.w += vc.w * a2f;
            }
            int cr = lane16 * 4;
            tile[cr + 0][px] = fmaxf(fv.x * ca1.x + cb1.x, fv.x * ca2.x + cb2.x);
            tile[cr + 1][px] = fmaxf(fv.y * ca1.y + cb1.y, fv.y * ca2.y + cb2.y);
            tile[cr + 2][px] = fmaxf(fv.z * ca1.z + cb1.z, fv.z * ca2.z + cb2.z);
            tile[cr + 3][px] = fmaxf(fv.w * ca1.w + cb1.w, fv.w * ca2.w + cb2.w);
        }
    }
    __syncthreads();
#pragma unroll
    for (int wp = 0; wp < 4; wp++) {
        int row = wp * 16 + (tid >> 4);
        int px4 = (tid & 15) * 4;
        int p = pt * 64 + px4;
        if (p < HW) {
            float4 r;
            r.x = tile[row][px4 + 0];
            r.y = tile[row][px4 + 1];
            r.z = tile[row][px4 + 2];
            r.w = tile[row][px4 + 3];
            *(float4*)(out + (size_t)(n * C_ + c0 + row) * HW + p) = r;
        }
    }
}

// --------------------------------------------------------------------- host ----
extern "C" void kernel_launch(void* const* d_in, const int* in_sizes, int n_in,
                              void* d_out, int out_size, void* d_ws, size_t ws_size,
                              hipStream_t stream) {
    (void)in_sizes; (void)n_in; (void)out_size; (void)ws_size;
    const float* x0 = (const float*)d_in[0];
    const float* x1 = (const float*)d_in[1];
    const float* x2 = (const float*)d_in[2];
    const float* dw_w_h = (const float*)d_in[3];
    const float* dw_s_h = (const float*)d_in[4];
    const float* dw_b_h = (const float*)d_in[5];
    const float* dw_w_m = (const float*)d_in[6];
    const float* dw_s_m = (const float*)d_in[7];
    const float* dw_b_m = (const float*)d_in[8];
    const float* dw_w_l = (const float*)d_in[9];
    const float* dw_s_l = (const float*)d_in[10];
    const float* dw_b_l = (const float*)d_in[11];
    const float* off_w = (const float*)d_in[12];
    const float* off_b = (const float*)d_in[13];
    const float* gn_g_h = (const float*)d_in[14];
    const float* gn_b_h = (const float*)d_in[15];
    const float* gn_g_m = (const float*)d_in[16];
    const float* gn_b_m = (const float*)d_in[17];
    const float* gn_g_l = (const float*)d_in[18];
    const float* gn_b_l = (const float*)d_in[19];
    const float* sa_w = (const float*)d_in[20];
    const float* sa_b = (const float*)d_in[21];
    const float* fc1_w = (const float*)d_in[22];
    const float* fc1_b = (const float*)d_in[23];
    const float* fc2_w = (const float*)d_in[24];
    const float* fc2_b = (const float*)d_in[25];

    float* ws = (float*)d_ws;
    float* XT0 = ws + 0;              // 6553600
    float* XT1 = ws + 6553600;        // 1638400
    float* XT2 = ws + 8192000;        // 409600
    float* SH = ws + 8601600;         // 6553600 (bf16 dw out overlays / f32 raw)
    float* FINA = ws + 17920000;      // 6553600
    float* FINB = ws + 24473600;      // 6553600
    float* FINC = ws + 31027200;      // 1638400
    float* WMF = ws + 32665600;       // 36864 (73728 bf16)
    float* DWT = ws + 32702464;       // 6912
    float* STATS = ws + 32709376;     // 896  (7 slots x 128)
    float* CMEAN = ws + 32710272;     // 7168 (7 slots x 1024)
    float* COEF = ws + 32717440;      // 4096 (reused per level)
    float* AF = ws + 32721536;        // 16

    unsigned short* SHB = (unsigned short*)SH;
    unsigned short* WMFB = (unsigned short*)WMF;

    float* out0 = (float*)d_out;
    float* out1 = out0 + 6553600;
    float* out2 = out0 + 8192000;

    // meta scratch carved from the (not-yet-written) output regions.
    float4* WM0 = (float4*)out0;
    ushort4* IM0 = (ushort4*)(out0 + 25600 * 144);
    float4* WM1 = (float4*)out1;
    ushort4* IM1 = (ushort4*)(out1 + 6400 * 144);
    float4* WM2 = (float4*)out2;
    ushort4* IM2 = (ushort4*)(out2 + 1600 * 144);

    k_prep<<<(4 * 32 * 576 + 6912 + 8064 + 255) / 256, 256, 0, stream>>>(
        off_w, dw_w_h, dw_w_m, dw_w_l, WMFB, DWT, STATS);

    k_transpose<<<dim3(4 * 80, 3, 8), 256, 0, stream>>>(x0, XT0, 80, 80);
    k_transpose<<<dim3(4 * 40, 2, 8), 256, 0, stream>>>(x1, XT1, 40, 40);
    k_transpose<<<dim3(4 * 20, 1, 8), 256, 0, stream>>>(x2, XT2, 20, 20);

    auto run_feat = [&](const float* xt, int Hs, int Ws, int stride, bool softmax,
                        const float* dwt, const float* dws, const float* dwb,
                        const float* gng, const float* gnb, int slot, float* fin, int Hf,
                        int Wf, float4* wm, ushort4* im) {
        int Ho = Hs / stride, Wo = Ws / stride;
        k_dw_silu<<<4 * Hs * Ws / 4, 256, 0, stream>>>(xt, dwt, dws, dwb, SHB, Hs, Ws);
        if (stride == 1) {
            if (Hs >= 40) {
                if (softmax)
                    k_offmask<1, true, 8, 8><<<dim3(4, Ho / 8, Wo / 8), 256, 0, stream>>>(
                        SHB, WMFB, off_b, wm, im, Hs, Ws, Ho, Wo);
                else
                    k_offmask<1, false, 8, 8><<<dim3(4, Ho / 8, Wo / 8), 256, 0, stream>>>(
                        SHB, WMFB, off_b, wm, im, Hs, Ws, Ho, Wo);
            } else {
                if (softmax)
                    k_offmask<1, true, 4, 4><<<dim3(4, Ho / 4, Wo / 4), 256, 0, stream>>>(
                        SHB, WMFB, off_b, wm, im, Hs, Ws, Ho, Wo);
                else
                    k_offmask<1, false, 4, 4><<<dim3(4, Ho / 4, Wo / 4), 256, 0, stream>>>(
                        SHB, WMFB, off_b, wm, im, Hs, Ws, Ho, Wo);
            }
        } else {
            k_offmask<2, true, 4, 4><<<dim3(4, Ho / 4, Wo / 4), 256, 0, stream>>>(
                SHB, WMFB, off_b, wm, im, Hs, Ws, Ho, Wo);
        }
        k_sample<<<4 * Ho * Wo / 8, 256, 0, stream>>>(xt, wm, im, SH, STATS + slot * 128,
                                                      Hs, Ws, Ho * Wo);
        int spn = (Hf * Wf + 63) / 64;
        k_gnup<<<4 * spn, 256, 0, stream>>>(SH, fin, STATS + slot * 128, CMEAN + slot * 1024,
                                            gng, gnb, Ho, Wo, Hf, Wf);
    };

    // ---- level 0 (80x80): mid(x0) + high(x1 up) ----
    run_feat(XT0, 80, 80, 1, false, DWT + 1 * 2304, dw_s_m, dw_b_m, gn_g_m, gn_b_m, 0, FINA,
             80, 80, WM0, IM0);
    run_feat(XT1, 40, 40, 1, true, DWT + 0 * 2304, dw_s_h, dw_b_h, gn_g_h, gn_b_h, 1, FINB,
             80, 80, WM0, IM0);
    k_coef<<<4, 256, 0, stream>>>(CMEAN, CMEAN + 1024, nullptr, 2, 0.5f, 1.f / 6400.f, sa_w,
                                  sa_b, fc1_w, fc1_b, fc2_w, fc2_b, COEF, AF);
    k_store<<<dim3(4, 100, 4), 256, 0, stream>>>(FINA, FINB, nullptr, 2, COEF, AF, out0,
                                                 6400);
    // ---- level 1 (40x40): mid(x1) + low(x0 s2) + high(x2 up) ----
    run_feat(XT1, 40, 40, 1, false, DWT + 1 * 2304, dw_s_m, dw_b_m, gn_g_m, gn_b_m, 2, FINA,
             40, 40, WM1, IM1);
    run_feat(XT0, 80, 80, 2, true, DWT + 2 * 2304, dw_s_l, dw_b_l, gn_g_l, gn_b_l, 3, FINB,
             40, 40, WM1, IM1);
    run_feat(XT2, 20, 20, 1, true, DWT + 0 * 2304, dw_s_h, dw_b_h, gn_g_h, gn_b_h, 4, FINC,
             40, 40, WM1, IM1);
    k_coef<<<4, 256, 0, stream>>>(CMEAN + 2 * 1024, CMEAN + 3 * 1024, CMEAN + 4 * 1024, 3,
                                  1.f / 3.f, 1.f / 1600.f, sa_w, sa_b, fc1_w, fc1_b, fc2_w,
                                  fc2_b, COEF, AF);
    k_store<<<dim3(4, 25, 4), 256, 0, stream>>>(FINA, FINB, FINC, 3, COEF, AF, out1, 1600);
    // ---- level 2 (20x20): mid(x2) + low(x1 s2) ----
    run_feat(XT2, 20, 20, 1, false, DWT + 1 * 2304, dw_s_m, dw_b_m, gn_g_m, gn_b_m, 5, FINA,
             20, 20, WM2, IM2);
    run_feat(XT1, 40, 40, 2, true, DWT + 2 * 2304, dw_s_l, dw_b_l, gn_g_l, gn_b_l, 6, FINB,
             20, 20, WM2, IM2);
    k_coef<<<4, 256, 0, stream>>>(CMEAN + 5 * 1024, CMEAN + 6 * 1024, nullptr, 2, 0.5f,
                                  1.f / 400.f, sa_w, sa_b, fc1_w, fc1_b, fc2_w, fc2_b, COEF,
                                  AF);
    k_store<<<dim3(4, 7, 4), 256, 0, stream>>>(FINA, FINB, nullptr, 2, COEF, AF, out2, 400);
}

// Round 7
// 626.936 us; speedup vs baseline: 3.0062x; 1.0986x over previous
//
#include <hip/hip_runtime.h>
#include <hip/hip_bf16.h>

#define C_ 256
#define G_ 4

typedef __attribute__((ext_vector_type(8))) short bf16x8;
typedef __attribute__((ext_vector_type(4))) float f32x4;

static __device__ __forceinline__ unsigned short f2bf(float x) {
    __hip_bfloat16 h = __float2bfloat16(x);
    return *(unsigned short*)&h;
}
static __device__ __forceinline__ float bf2f(unsigned short u) {
    return __uint_as_float((unsigned)u << 16);
}
static __device__ __forceinline__ float4 bf4(ushort4 u) {
    float4 r;
    r.x = bf2f(u.x);
    r.y = bf2f(u.y);
    r.z = bf2f(u.z);
    r.w = bf2f(u.w);
    return r;
}

// ---------------------------------------------------------------- prep ----
__global__ void k_prep(const float* __restrict__ off_w, const float* __restrict__ dwh,
                       const float* __restrict__ dwm, const float* __restrict__ dwl,
                       unsigned short* __restrict__ wmf, float* __restrict__ dwt,
                       float* __restrict__ zeros) {
    int i = blockIdx.x * 256 + threadIdx.x;
    const int NWM = 4 * 32 * 576;
    if (i < NWM) {
        int g = i / (32 * 576), rem = i % (32 * 576);
        int ol = rem / 576, kk = rem % 576;
        int tap = kk / 64, ic = kk % 64;
        float v = (ol < 27) ? off_w[((size_t)((g * 27 + ol) * 64 + ic)) * 9 + tap] : 0.f;
        wmf[i] = f2bf(v);
    }
    int j = i - NWM;
    if (j >= 0 && j < 3 * 2304) {
        int which = j / 2304, rem = j % 2304;
        int t = rem / 256, c = rem % 256;
        const float* src = (which == 0) ? dwh : (which == 1) ? dwm : dwl;
        dwt[j] = src[c * 9 + t];
    }
    int z = i - NWM - 3 * 2304;
    if (z >= 0 && z < 8064) zeros[z] = 0.f;
}

// ------------------------------------------------------------ transpose ----
// NCHW f32 -> NHWC bf16
__global__ __launch_bounds__(256) void k_transpose(const float* __restrict__ x,
                                                   unsigned short* __restrict__ xtb, int H,
                                                   int W) {
    __shared__ float tile[32][33];
    int nh = blockIdx.x;
    int n = nh / H, h = nh % H;
    int w0 = blockIdx.y * 32, c0 = blockIdx.z * 32;
    int tid = threadIdx.x;
    int i = tid / 32, j = tid % 32;
#pragma unroll
    for (int r = 0; r < 4; r++) {
        int c = c0 + i + r * 8;
        int w = w0 + j;
        tile[i + r * 8][j] = (w < W) ? x[((size_t)(n * C_ + c) * H + h) * W + w] : 0.f;
    }
    __syncthreads();
    int wj = tid >> 4, ci2 = (tid & 15) * 2;
#pragma unroll
    for (int r = 0; r < 2; r++) {
        int w = w0 + wj + r * 16;
        if (w < W) {
            ushort2 o;
            o.x = f2bf(tile[ci2][wj + r * 16]);
            o.y = f2bf(tile[ci2 + 1][wj + r * 16]);
            *(ushort2*)(xtb + ((size_t)(n * H + h) * W + w) * C_ + c0 + ci2) = o;
        }
    }
}

// -------------------------------------------------------- depthwise+SiLU ----
__global__ __launch_bounds__(256) void k_dw_silu(const unsigned short* __restrict__ xtb,
                                                 const float* __restrict__ wdt,
                                                 const float* __restrict__ sc,
                                                 const float* __restrict__ bi,
                                                 unsigned short* __restrict__ out, int H,
                                                 int W) {
    int tid = threadIdx.x;
    int pw = tid >> 6, lane = tid & 63;
    int ch4 = lane << 2;
    int pix = blockIdx.x * 4 + pw;
    int w = pix % W, h = (pix / W) % H, n = pix / (W * H);
    const float4 s4 = *(const float4*)(sc + ch4);
    const float4 b4 = *(const float4*)(bi + ch4);
    const unsigned short* xb = xtb + (size_t)n * H * W * C_ + ch4;
    float4 acc = {0.f, 0.f, 0.f, 0.f};
#pragma unroll
    for (int t = 0; t < 9; t++) {
        int hh = h + t / 3 - 1, ww = w + t % 3 - 1;
        if (hh >= 0 && hh < H && ww >= 0 && ww < W) {
            float4 wt = *(const float4*)(wdt + t * 256 + ch4);
            float4 xv = bf4(*(const ushort4*)(xb + (size_t)(hh * W + ww) * C_));
            acc.x += wt.x * xv.x;
            acc.y += wt.y * xv.y;
            acc.z += wt.z * xv.z;
            acc.w += wt.w * xv.w;
        }
    }
    float4 y;
    y.x = acc.x * s4.x + b4.x;
    y.y = acc.y * s4.y + b4.y;
    y.z = acc.z * s4.z + b4.z;
    y.w = acc.w * s4.w + b4.w;
    y.x = y.x / (1.f + __expf(-y.x));
    y.y = y.y / (1.f + __expf(-y.y));
    y.z = y.z / (1.f + __expf(-y.z));
    y.w = y.w / (1.f + __expf(-y.w));
    ushort4 o;
    o.x = f2bf(y.x);
    o.y = f2bf(y.y);
    o.z = f2bf(y.z);
    o.w = f2bf(y.w);
    *(ushort4*)(out + (size_t)pix * C_ + ch4) = o;
}

// ------------------------------------------------- grouped offset/mask conv ----
template <int STRIDE, bool SOFTMAX, int TH, int TW>
__global__ __launch_bounds__(256) void k_offmask(const unsigned short* __restrict__ dwb,
                                                 const unsigned short* __restrict__ wmf,
                                                 const float* __restrict__ bias,
                                                 float4* __restrict__ wmeta,
                                                 ushort4* __restrict__ imeta,
                                                 int Hs, int Ws, int Ho, int Wo) {
    constexpr int SR = STRIDE * (TH - 1) + 3;
    constexpr int SC = STRIDE * (TW - 1) + 3;
    constexpr int NV = SR * SC;
    constexpr int CP = 264;
    constexpr int TP = TH * TW;
    constexpr int NT = TP / 16;
    constexpr int MTW = 2 * NT;
    constexpr int PATCH_B = NV * CP * 2;
    constexpr int OMV_B = TP * 112 * 4;
    constexpr int LDS_B = PATCH_B > OMV_B ? PATCH_B : OMV_B;
    __shared__ __align__(16) char smem[LDS_B];
    unsigned short* patch = (unsigned short*)smem;
    float* omv = (float*)smem;

    int tid = threadIdx.x;
    int wv = tid >> 6, lane = tid & 63;
    int n16 = lane & 15, q = lane >> 4;
    int n = blockIdx.x;
    int ho0 = blockIdx.y * TH, wo0 = blockIdx.z * TW;
    int hs0 = ho0 * STRIDE - 1, ws0 = wo0 * STRIDE - 1;

    for (int idx = tid; idx < NV * 32; idx += 256) {
        int pp = idx >> 5;
        int c8 = (idx & 31) << 3;
        int hh = hs0 + pp / SC, ww = ws0 + pp % SC;
        uint4 v = {0u, 0u, 0u, 0u};
        if (hh >= 0 && hh < Hs && ww >= 0 && ww < Ws)
            v = *(const uint4*)(dwb + ((size_t)(n * Hs + hh) * Ws + ww) * C_ + c8);
        *(uint4*)(patch + pp * CP + c8) = v;
    }
    __syncthreads();

    int ntile = wv % NT;
    int mstart = (wv / NT) * MTW;
    int p = ntile * 16 + n16;
    int pr = p / TW, pc = p % TW;
    int pixbase = (pr * STRIDE) * SC + pc * STRIDE;
    int bchan = q << 3;

    f32x4 acc[MTW];
#pragma unroll
    for (int l = 0; l < MTW; l++) acc[l] = (f32x4){0.f, 0.f, 0.f, 0.f};

    for (int kk = 0; kk < 18; kk++) {
        int tap = kk >> 1;
        int ic0 = (kk & 1) << 5;
        int ty = tap / 3, tx = tap % 3;
        int ppix = pixbase + ty * SC + tx;
#pragma unroll
        for (int gi = 0; gi < MTW / 2; gi++) {
            int g = (mstart >> 1) + gi;
            bf16x8 b = *(const bf16x8*)(patch + ppix * CP + g * 64 + ic0 + bchan);
#pragma unroll
            for (int s = 0; s < 2; s++) {
                int row = g * 32 + s * 16 + n16;
                bf16x8 a = *(const bf16x8*)(wmf + (size_t)row * 576 + kk * 32 + bchan);
                acc[gi * 2 + s] =
                    __builtin_amdgcn_mfma_f32_16x16x32_bf16(a, b, acc[gi * 2 + s], 0, 0, 0);
            }
        }
    }
    __syncthreads();

#pragma unroll
    for (int l = 0; l < MTW; l++) {
        int mt = mstart + l;
        int g = mt >> 1;
        int olbase = (mt & 1) * 16 + q * 4;
#pragma unroll
        for (int r = 0; r < 4; r++) {
            int ol = olbase + r;
            if (ol < 27) omv[p * 112 + g * 27 + ol] = acc[l][r];
        }
    }
    __syncthreads();

    for (int flat = tid; flat < TP * G_; flat += 256) {
        int pp = flat >> 2, g = flat & 3;
        int ho = ho0 + pp / TW, wo = wo0 + pp % TW;
        size_t pix = (size_t)(n * Ho + ho) * Wo + wo;
        float mv[9];
        if (SOFTMAX) {
            float mx = -1e30f;
#pragma unroll
            for (int k = 0; k < 9; k++) {
                mv[k] = omv[pp * 112 + 72 + g * 9 + k] + bias[72 + g * 9 + k];
                mx = fmaxf(mx, mv[k]);
            }
            float ssum = 0.f;
#pragma unroll
            for (int k = 0; k < 9; k++) {
                mv[k] = __expf(mv[k] - mx);
                ssum += mv[k];
            }
            float inv = 1.f / ssum;
#pragma unroll
            for (int k = 0; k < 9; k++) mv[k] *= inv;
        } else {
#pragma unroll
            for (int k = 0; k < 9; k++) {
                float v = omv[pp * 112 + 72 + g * 9 + k] + bias[72 + g * 9 + k];
                mv[k] = 1.f / (1.f + __expf(-v));
            }
        }
#pragma unroll
        for (int k = 0; k < 9; k++) {
            float oy = omv[pp * 112 + g * 18 + 2 * k] + bias[g * 18 + 2 * k];
            float ox = omv[pp * 112 + g * 18 + 2 * k + 1] + bias[g * 18 + 2 * k + 1];
            float py = (float)(ho * STRIDE + k / 3 - 1) + oy;
            float px = (float)(wo * STRIDE + k % 3 - 1) + ox;
            float y0f = floorf(py), x0f = floorf(px);
            int y0 = (int)y0f, x0 = (int)x0f;
            float wy = py - y0f, wx = px - x0f;
            int y1 = y0 + 1, x1 = x0 + 1;
            float v0y = (y0 >= 0 && y0 < Hs) ? 1.f : 0.f;
            float v1y = (y1 >= 0 && y1 < Hs) ? 1.f : 0.f;
            float v0x = (x0 >= 0 && x0 < Ws) ? 1.f : 0.f;
            float v1x = (x1 >= 0 && x1 < Ws) ? 1.f : 0.f;
            int y0c = min(max(y0, 0), Hs - 1), y1c = min(max(y1, 0), Hs - 1);
            int x0c = min(max(x0, 0), Ws - 1), x1c = min(max(x1, 0), Ws - 1);
            float m_ = mv[k];
            float4 w4;
            w4.x = (1.f - wy) * (1.f - wx) * v0y * v0x * m_;
            w4.y = (1.f - wy) * wx * v0y * v1x * m_;
            w4.z = wy * (1.f - wx) * v1y * v0x * m_;
            w4.w = wy * wx * v1y * v1x * m_;
            ushort4 i4;
            i4.x = (unsigned short)(y0c * Ws + x0c);
            i4.y = (unsigned short)(y0c * Ws + x1c);
            i4.z = (unsigned short)(y1c * Ws + x0c);
            i4.w = (unsigned short)(y1c * Ws + x1c);
            wmeta[pix * 36 + g * 9 + k] = w4;
            imeta[pix * 36 + g * 9 + k] = i4;
        }
    }
}

// ------------------------------------------------------------- DCNv3 sample ----
// bf16 gather source; XCD band swizzle for L2 locality.
__global__ __launch_bounds__(256) void k_sample(const unsigned short* __restrict__ xtb,
                                                const float4* __restrict__ wmeta,
                                                const ushort4* __restrict__ imeta,
                                                float* __restrict__ raw,
                                                float* __restrict__ stats,
                                                int Hs, int Ws, int HoWo) {
    int tid = threadIdx.x;
    int wv = tid >> 6, lane = tid & 63;
    int g = lane >> 4;
    int ch4 = lane << 2;
    // round-robin -> contiguous band remap (XCD = blockIdx % 8 heuristic)
    int nb = gridDim.x;
    int per = nb >> 3, rem = nb & 7;
    int xcd = blockIdx.x & 7, bi = blockIdx.x >> 3;
    int logical = xcd * per + min(xcd, rem) + bi;
    int pix0 = logical * 8;
    int n = pix0 / HoWo;
    __shared__ float4 lw[288];
    __shared__ ushort4 li[288];
    __shared__ float lstat[32];
    const float4* wsrc = wmeta + (size_t)pix0 * 36;
    for (int idx = tid; idx < 288; idx += 256) lw[idx] = wsrc[idx];
    const uint4* isrc = (const uint4*)imeta + (size_t)pix0 * 18;
    if (tid < 144) ((uint4*)li)[tid] = isrc[tid];
    if (tid < 32) lstat[tid] = 0.f;
    __syncthreads();

    int pA = wv * 2, pB = wv * 2 + 1;
    const unsigned short* xb = xtb + (size_t)n * Hs * Ws * C_ + ch4;
    float4 aA = {0.f, 0.f, 0.f, 0.f}, aB = {0.f, 0.f, 0.f, 0.f};
#pragma unroll
    for (int k = 0; k < 9; k++) {
        float4 wA = lw[pA * 36 + g * 9 + k];
        ushort4 iA = li[pA * 36 + g * 9 + k];
        float4 wB = lw[pB * 36 + g * 9 + k];
        ushort4 iB = li[pB * 36 + g * 9 + k];
        float4 vA0 = bf4(*(const ushort4*)(xb + ((size_t)iA.x << 8)));
        float4 vA1 = bf4(*(const ushort4*)(xb + ((size_t)iA.y << 8)));
        float4 vA2 = bf4(*(const ushort4*)(xb + ((size_t)iA.z << 8)));
        float4 vA3 = bf4(*(const ushort4*)(xb + ((size_t)iA.w << 8)));
        float4 vB0 = bf4(*(const ushort4*)(xb + ((size_t)iB.x << 8)));
        float4 vB1 = bf4(*(const ushort4*)(xb + ((size_t)iB.y << 8)));
        float4 vB2 = bf4(*(const ushort4*)(xb + ((size_t)iB.z << 8)));
        float4 vB3 = bf4(*(const ushort4*)(xb + ((size_t)iB.w << 8)));
        aA.x += wA.x * vA0.x + wA.y * vA1.x + wA.z * vA2.x + wA.w * vA3.x;
        aA.y += wA.x * vA0.y + wA.y * vA1.y + wA.z * vA2.y + wA.w * vA3.y;
        aA.z += wA.x * vA0.z + wA.y * vA1.z + wA.z * vA2.z + wA.w * vA3.z;
        aA.w += wA.x * vA0.w + wA.y * vA1.w + wA.z * vA2.w + wA.w * vA3.w;
        aB.x += wB.x * vB0.x + wB.y * vB1.x + wB.z * vB2.x + wB.w * vB3.x;
        aB.y += wB.x * vB0.y + wB.y * vB1.y + wB.z * vB2.y + wB.w * vB3.y;
        aB.z += wB.x * vB0.z + wB.y * vB1.z + wB.z * vB2.z + wB.w * vB3.z;
        aB.w += wB.x * vB0.w + wB.y * vB1.w + wB.z * vB2.w + wB.w * vB3.w;
    }
    *(float4*)(raw + (size_t)(pix0 + pA) * C_ + ch4) = aA;
    *(float4*)(raw + (size_t)(pix0 + pB) * C_ + ch4) = aB;
    float gs = aA.x + aA.y + aA.z + aA.w + aB.x + aB.y + aB.z + aB.w;
    float gss = aA.x * aA.x + aA.y * aA.y + aA.z * aA.z + aA.w * aA.w + aB.x * aB.x +
                aB.y * aB.y + aB.z * aB.z + aB.w * aB.w;
#pragma unroll
    for (int o = 2; o; o >>= 1) {
        gs += __shfl_down(gs, o, 4);
        gss += __shfl_down(gss, o, 4);
    }
    if ((lane & 3) == 0) {
        atomicAdd(&lstat[(lane >> 2) * 2 + 0], gs);
        atomicAdd(&lstat[(lane >> 2) * 2 + 1], gss);
    }
    __syncthreads();
    if (tid < 32) atomicAdd(&stats[n * 32 + tid], lstat[tid]);
}

// ----------------------------------------- GN affine (+bilinear up) + ch-means ----
__global__ __launch_bounds__(256) void k_gnup(const float* __restrict__ raw,
                                              float* __restrict__ fin,
                                              const float* __restrict__ stats,
                                              float* __restrict__ cmean,
                                              const float* __restrict__ gamma,
                                              const float* __restrict__ beta,
                                              int Hr, int Wr, int Hf, int Wf) {
    int HWf = Hf * Wf;
    int spn = (HWf + 63) >> 6;
    int n = blockIdx.x / spn;
    int p0 = (blockIdx.x % spn) << 6;
    int tid = threadIdx.x;
    int wv = tid >> 6, lane = tid & 63;
    int ch4 = lane << 2;
    int gg = lane >> 2;
    float cnt = 16.f * Hr * Wr;
    float s1 = stats[(n * 16 + gg) * 2], s2 = stats[(n * 16 + gg) * 2 + 1];
    float mu = s1 / cnt;
    float var = s2 / cnt - mu * mu;
    float rs = rsqrtf(var + 1e-5f);
    float4 g4 = *(const float4*)(gamma + ch4);
    float4 b4 = *(const float4*)(beta + ch4);
    float4 ga, be;
    ga.x = g4.x * rs; be.x = b4.x - mu * ga.x;
    ga.y = g4.y * rs; be.y = b4.y - mu * ga.y;
    ga.z = g4.z * rs; be.z = b4.z - mu * ga.z;
    ga.w = g4.w * rs; be.w = b4.w - mu * ga.w;
    bool up = (Hf != Hr);
    float sys = up ? (float)((double)(Hr - 1) / (double)(Hf - 1)) : 0.f;
    float sxs = up ? (float)((double)(Wr - 1) / (double)(Wf - 1)) : 0.f;
    float4 csum = {0.f, 0.f, 0.f, 0.f};
    __shared__ float cs[4][256];
    const float* rb = raw + (size_t)n * Hr * Wr * C_ + ch4;
    for (int i = wv; i < 64; i += 4) {
        int p = p0 + i;
        if (p < HWf) {
            float4 v;
            if (up) {
                int ho = p / Wf, wo = p % Wf;
                float sy = ho * sys, sx = wo * sxs;
                int y0 = (int)sy, x0 = (int)sx;
                float fy = sy - y0, fx = sx - x0;
                int y1 = min(y0 + 1, Hr - 1), x1 = min(x0 + 1, Wr - 1);
                float4 v00 = *(const float4*)(rb + (size_t)(y0 * Wr + x0) * C_);
                float4 v01 = *(const float4*)(rb + (size_t)(y0 * Wr + x1) * C_);
                float4 v10 = *(const float4*)(rb + (size_t)(y1 * Wr + x0) * C_);
                float4 v11 = *(const float4*)(rb + (size_t)(y1 * Wr + x1) * C_);
                v.x = (v00.x * (1.f - fy) + v10.x * fy) * (1.f - fx) + (v01.x * (1.f - fy) + v11.x * fy) * fx;
                v.y = (v00.y * (1.f - fy) + v10.y * fy) * (1.f - fx) + (v01.y * (1.f - fy) + v11.y * fy) * fx;
                v.z = (v00.z * (1.f - fy) + v10.z * fy) * (1.f - fx) + (v01.z * (1.f - fy) + v11.z * fy) * fx;
                v.w = (v00.w * (1.f - fy) + v10.w * fy) * (1.f - fx) + (v01.w * (1.f - fy) + v11.w * fy) * fx;
            } else {
                v = *(const float4*)(raw + ((size_t)n * HWf + p) * C_ + ch4);
            }
            float4 y4;
            y4.x = v.x * ga.x + be.x;
            y4.y = v.y * ga.y + be.y;
            y4.z = v.z * ga.z + be.z;
            y4.w = v.w * ga.w + be.w;
            *(float4*)(fin + ((size_t)n * HWf + p) * C_ + ch4) = y4;
            csum.x += y4.x; csum.y += y4.y; csum.z += y4.z; csum.w += y4.w;
        }
    }
    cs[wv][ch4 + 0] = csum.x;
    cs[wv][ch4 + 1] = csum.y;
    cs[wv][ch4 + 2] = csum.z;
    cs[wv][ch4 + 3] = csum.w;
    __syncthreads();
    if (wv == 0) {
        float t0 = 0.f, t1 = 0.f, t2 = 0.f, t3 = 0.f;
#pragma unroll
        for (int r = 0; r < 4; r++) {
            t0 += cs[r][ch4 + 0];
            t1 += cs[r][ch4 + 1];
            t2 += cs[r][ch4 + 2];
            t3 += cs[r][ch4 + 3];
        }
        atomicAdd(&cmean[n * C_ + ch4 + 0], t0);
        atomicAdd(&cmean[n * C_ + ch4 + 1], t1);
        atomicAdd(&cmean[n * C_ + ch4 + 2], t2);
        atomicAdd(&cmean[n * C_ + ch4 + 3], t3);
    }
}

// ------------------------- per-(n,level) scale-attn + DyReLU coefficients ----
__global__ __launch_bounds__(256) void k_coef(const float* __restrict__ cmA,
                                              const float* __restrict__ cmB,
                                              const float* __restrict__ cmC,
                                              int nf, float inv_nl, float inv_hw,
                                              const float* __restrict__ sa_w,
                                              const float* __restrict__ sa_b,
                                              const float* __restrict__ fc1_w,
                                              const float* __restrict__ fc1_b,
                                              const float* __restrict__ fc2_w,
                                              const float* __restrict__ fc2_b,
                                              float* __restrict__ coef,
                                              float* __restrict__ af) {
    int n = blockIdx.x;
    int c = threadIdx.x;
    __shared__ float red[256];
    __shared__ float meanv[256];
    __shared__ float hv[64];
    __shared__ float sa_a[3];
    const float* cms[3] = {cmA, cmB, cmC};
    float cm[3] = {0.f, 0.f, 0.f};
    for (int f = 0; f < nf; f++) {
        cm[f] = cms[f][n * C_ + c] * inv_hw;
        red[c] = sa_w[c] * cm[f];
        __syncthreads();
        for (int s = 128; s; s >>= 1) {
            if (c < s) red[c] += red[c + s];
            __syncthreads();
        }
        if (c == 0) {
            float t = fmaxf(red[0] + sa_b[0], 0.f);
            sa_a[f] = fminf(fmaxf((t + 3.f) * (1.f / 6.f), 0.f), 1.f);
        }
        __syncthreads();
    }
    float mv = 0.f;
    for (int f = 0; f < nf; f++) mv += sa_a[f] * cm[f];
    mv *= inv_nl;
    meanv[c] = mv;
    __syncthreads();
    int j = c >> 2, t = c & 3;
    float partial = 0.f;
    for (int k = t * 64; k < t * 64 + 64; k++) partial += fc1_w[j * 256 + k] * meanv[k];
    partial += __shfl_down(partial, 2, 4);
    partial += __shfl_down(partial, 1, 4);
    if (t == 0) hv[j] = fmaxf(partial + fc1_b[j], 0.f);
    __syncthreads();
    float zz[4];
#pragma unroll
    for (int i = 0; i < 4; i++) {
        float z = fc2_b[i * 256 + c];
        for (int k = 0; k < 64; k++) z += fc2_w[(size_t)(i * 256 + c) * 64 + k] * hv[k];
        zz[i] = fminf(fmaxf(z + 3.f, 0.f), 6.f) * (1.f / 6.f);
    }
    coef[n * 1024 + 0 * 256 + c] = (zz[0] - 0.5f) * 2.f + 1.f;
    coef[n * 1024 + 1 * 256 + c] = zz[1] - 0.5f;
    coef[n * 1024 + 2 * 256 + c] = (zz[2] - 0.5f) * 2.f;
    coef[n * 1024 + 3 * 256 + c] = zz[3] - 0.5f;
    if (c < 4) af[n * 4 + c] = (c < nf) ? sa_a[c] * inv_nl : 0.f;
}

// ------------------- streaming combine + DyReLU + NHWC->NCHW store ----
__global__ __launch_bounds__(256) void k_store(const float* __restrict__ fA,
                                               const float* __restrict__ fB,
                                               const float* __restrict__ fC,
                                               int nf, const float* __restrict__ coef,
                                               const float* __restrict__ af,
                                               float* __restrict__ out, int HW) {
    __shared__ float tile[64][65];
    int n = blockIdx.x;
    int pt = blockIdx.y;
    int c0 = blockIdx.z * 64;
    int tid = threadIdx.x;
    int lane16 = tid & 15, prow = tid >> 4;
    int ch4 = c0 + lane16 * 4;
    float a0 = af[n * 4 + 0], a1f = af[n * 4 + 1], a2f = af[n * 4 + 2];
    float4 ca1 = *(const float4*)(coef + n * 1024 + 0 + ch4);
    float4 cb1 = *(const float4*)(coef + n * 1024 + 256 + ch4);
    float4 ca2 = *(const float4*)(coef + n * 1024 + 512 + ch4);
    float4 cb2 = *(const float4*)(coef + n * 1024 + 768 + ch4);
#pragma unroll
    for (int pass = 0; pass < 4; pass++) {
        int px = pass * 16 + prow;
        int p = pt * 64 + px;
        if (p < HW) {
            size_t base = ((size_t)n * HW + p) * C_ + ch4;
            float4 v = *(const float4*)(fA + base);
            float4 fv;
            fv.x = v.x * a0;
            fv.y = v.y * a0;
            fv.z = v.z * a0;
            fv.w = v.w * a0;
            if (nf > 1) {
                float4 vb = *(const float4*)(fB + base);
                fv.x += vb.x * a1f;
                fv.y += vb.y * a1f;
                fv.z += vb.z * a1f;
                fv.w += vb.w * a1f;
            }
            if (nf > 2) {
                float4 vc = *(const float4*)(fC + base);
                fv.x += vc.x * a2f;
                fv.y += vc.y * a2f;
                fv.z += vc.z * a2f;
                fv.w += vc.w * a2f;
            }
            int cr = lane16 * 4;
            tile[cr + 0][px] = fmaxf(fv.x * ca1.x + cb1.x, fv.x * ca2.x + cb2.x);
            tile[cr + 1][px] = fmaxf(fv.y * ca1.y + cb1.y, fv.y * ca2.y + cb2.y);
            tile[cr + 2][px] = fmaxf(fv.z * ca1.z + cb1.z, fv.z * ca2.z + cb2.z);
            tile[cr + 3][px] = fmaxf(fv.w * ca1.w + cb1.w, fv.w * ca2.w + cb2.w);
        }
    }
    __syncthreads();
#pragma unroll
    for (int wp = 0; wp < 4; wp++) {
        int row = wp * 16 + (tid >> 4);
        int px4 = (tid & 15) * 4;
        int p = pt * 64 + px4;
        if (p < HW) {
            float4 r;
            r.x = tile[row][px4 + 0];
            r.y = tile[row][px4 + 1];
            r.z = tile[row][px4 + 2];
            r.w = tile[row][px4 + 3];
            *(float4*)(out + (size_t)(n * C_ + c0 + row) * HW + p) = r;
        }
    }
}

// --------------------------------------------------------------------- host ----
extern "C" void kernel_launch(void* const* d_in, const int* in_sizes, int n_in,
                              void* d_out, int out_size, void* d_ws, size_t ws_size,
                              hipStream_t stream) {
    (void)in_sizes; (void)n_in; (void)out_size; (void)ws_size;
    const float* x0 = (const float*)d_in[0];
    const float* x1 = (const float*)d_in[1];
    const float* x2 = (const float*)d_in[2];
    const float* dw_w_h = (const float*)d_in[3];
    const float* dw_s_h = (const float*)d_in[4];
    const float* dw_b_h = (const float*)d_in[5];
    const float* dw_w_m = (const float*)d_in[6];
    const float* dw_s_m = (const float*)d_in[7];
    const float* dw_b_m = (const float*)d_in[8];
    const float* dw_w_l = (const float*)d_in[9];
    const float* dw_s_l = (const float*)d_in[10];
    const float* dw_b_l = (const float*)d_in[11];
    const float* off_w = (const float*)d_in[12];
    const float* off_b = (const float*)d_in[13];
    const float* gn_g_h = (const float*)d_in[14];
    const float* gn_b_h = (const float*)d_in[15];
    const float* gn_g_m = (const float*)d_in[16];
    const float* gn_b_m = (const float*)d_in[17];
    const float* gn_g_l = (const float*)d_in[18];
    const float* gn_b_l = (const float*)d_in[19];
    const float* sa_w = (const float*)d_in[20];
    const float* sa_b = (const float*)d_in[21];
    const float* fc1_w = (const float*)d_in[22];
    const float* fc1_b = (const float*)d_in[23];
    const float* fc2_w = (const float*)d_in[24];
    const float* fc2_b = (const float*)d_in[25];

    float* ws = (float*)d_ws;
    unsigned short* XTB0 = (unsigned short*)(ws + 0);        // 3276800 f
    unsigned short* XTB1 = (unsigned short*)(ws + 3276800);  // 819200 f
    unsigned short* XTB2 = (unsigned short*)(ws + 4096000);  // 204800 f
    float* SH = ws + 4300800;      // 6553600 (bf16 dw out overlays / f32 raw)
    float* FINA = ws + 10854400;   // 6553600
    float* FINB = ws + 17408000;   // 6553600
    float* FINC = ws + 23961600;   // 1638400
    float* WMF = ws + 25600000;    // 36864
    float* DWT = ws + 25636864;    // 6912
    float* STATS = ws + 25643776;  // 896
    float* CMEAN = ws + 25644672;  // 7168
    float* COEF = ws + 25651840;   // 4096
    float* AF = ws + 25655936;     // 16

    unsigned short* SHB = (unsigned short*)SH;
    unsigned short* WMFB = (unsigned short*)WMF;

    float* out0 = (float*)d_out;
    float* out1 = out0 + 6553600;
    float* out2 = out0 + 8192000;

    float4* WM0 = (float4*)out0;
    ushort4* IM0 = (ushort4*)(out0 + 25600 * 144);
    float4* WM1 = (float4*)out1;
    ushort4* IM1 = (ushort4*)(out1 + 6400 * 144);
    float4* WM2 = (float4*)out2;
    ushort4* IM2 = (ushort4*)(out2 + 1600 * 144);

    k_prep<<<(4 * 32 * 576 + 6912 + 8064 + 255) / 256, 256, 0, stream>>>(
        off_w, dw_w_h, dw_w_m, dw_w_l, WMFB, DWT, STATS);

    k_transpose<<<dim3(4 * 80, 3, 8), 256, 0, stream>>>(x0, XTB0, 80, 80);
    k_transpose<<<dim3(4 * 40, 2, 8), 256, 0, stream>>>(x1, XTB1, 40, 40);
    k_transpose<<<dim3(4 * 20, 1, 8), 256, 0, stream>>>(x2, XTB2, 20, 20);

    auto run_feat = [&](const unsigned short* xtb, int Hs, int Ws, int stride, bool softmax,
                        const float* dwt, const float* dws, const float* dwb,
                        const float* gng, const float* gnb, int slot, float* fin, int Hf,
                        int Wf, float4* wm, ushort4* im) {
        int Ho = Hs / stride, Wo = Ws / stride;
        k_dw_silu<<<4 * Hs * Ws / 4, 256, 0, stream>>>(xtb, dwt, dws, dwb, SHB, Hs, Ws);
        if (stride == 1) {
            if (Hs >= 40) {
                if (softmax)
                    k_offmask<1, true, 8, 8><<<dim3(4, Ho / 8, Wo / 8), 256, 0, stream>>>(
                        SHB, WMFB, off_b, wm, im, Hs, Ws, Ho, Wo);
                else
                    k_offmask<1, false, 8, 8><<<dim3(4, Ho / 8, Wo / 8), 256, 0, stream>>>(
                        SHB, WMFB, off_b, wm, im, Hs, Ws, Ho, Wo);
            } else {
                if (softmax)
                    k_offmask<1, true, 4, 4><<<dim3(4, Ho / 4, Wo / 4), 256, 0, stream>>>(
                        SHB, WMFB, off_b, wm, im, Hs, Ws, Ho, Wo);
                else
                    k_offmask<1, false, 4, 4><<<dim3(4, Ho / 4, Wo / 4), 256, 0, stream>>>(
                        SHB, WMFB, off_b, wm, im, Hs, Ws, Ho, Wo);
            }
        } else {
            k_offmask<2, true, 4, 4><<<dim3(4, Ho / 4, Wo / 4), 256, 0, stream>>>(
                SHB, WMFB, off_b, wm, im, Hs, Ws, Ho, Wo);
        }
        k_sample<<<4 * Ho * Wo / 8, 256, 0, stream>>>(xtb, wm, im, SH, STATS + slot * 128,
                                                      Hs, Ws, Ho * Wo);
        int spn = (Hf * Wf + 63) / 64;
        k_gnup<<<4 * spn, 256, 0, stream>>>(SH, fin, STATS + slot * 128, CMEAN + slot * 1024,
                                            gng, gnb, Ho, Wo, Hf, Wf);
    };

    // ---- level 0 (80x80): mid(x0) + high(x1 up) ----
    run_feat(XTB0, 80, 80, 1, false, DWT + 1 * 2304, dw_s_m, dw_b_m, gn_g_m, gn_b_m, 0, FINA,
             80, 80, WM0, IM0);
    run_feat(XTB1, 40, 40, 1, true, DWT + 0 * 2304, dw_s_h, dw_b_h, gn_g_h, gn_b_h, 1, FINB,
             80, 80, WM0, IM0);
    k_coef<<<4, 256, 0, stream>>>(CMEAN, CMEAN + 1024, nullptr, 2, 0.5f, 1.f / 6400.f, sa_w,
                                  sa_b, fc1_w, fc1_b, fc2_w, fc2_b, COEF, AF);
    k_store<<<dim3(4, 100, 4), 256, 0, stream>>>(FINA, FINB, nullptr, 2, COEF, AF, out0,
                                                 6400);
    // ---- level 1 (40x40): mid(x1) + low(x0 s2) + high(x2 up) ----
    run_feat(XTB1, 40, 40, 1, false, DWT + 1 * 2304, dw_s_m, dw_b_m, gn_g_m, gn_b_m, 2, FINA,
             40, 40, WM1, IM1);
    run_feat(XTB0, 80, 80, 2, true, DWT + 2 * 2304, dw_s_l, dw_b_l, gn_g_l, gn_b_l, 3, FINB,
             40, 40, WM1, IM1);
    run_feat(XTB2, 20, 20, 1, true, DWT + 0 * 2304, dw_s_h, dw_b_h, gn_g_h, gn_b_h, 4, FINC,
             40, 40, WM1, IM1);
    k_coef<<<4, 256, 0, stream>>>(CMEAN + 2 * 1024, CMEAN + 3 * 1024, CMEAN + 4 * 1024, 3,
                                  1.f / 3.f, 1.f / 1600.f, sa_w, sa_b, fc1_w, fc1_b, fc2_w,
                                  fc2_b, COEF, AF);
    k_store<<<dim3(4, 25, 4), 256, 0, stream>>>(FINA, FINB, FINC, 3, COEF, AF, out1, 1600);
    // ---- level 2 (20x20): mid(x2) + low(x1 s2) ----
    run_feat(XTB2, 20, 20, 1, false, DWT + 1 * 2304, dw_s_m, dw_b_m, gn_g_m, gn_b_m, 5, FINA,
             20, 20, WM2, IM2);
    run_feat(XTB1, 40, 40, 2, true, DWT + 2 * 2304, dw_s_l, dw_b_l, gn_g_l, gn_b_l, 6, FINB,
             20, 20, WM2, IM2);
    k_coef<<<4, 256, 0, stream>>>(CMEAN + 5 * 1024, CMEAN + 6 * 1024, nullptr, 2, 0.5f,
                                  1.f / 400.f, sa_w, sa_b, fc1_w, fc1_b, fc2_w, fc2_b, COEF,
                                  AF);
    k_store<<<dim3(4, 7, 4), 256, 0, stream>>>(FINA, FINB, nullptr, 2, COEF, AF, out2, 400);
}

// Round 8
// 575.130 us; speedup vs baseline: 3.2770x; 1.0901x over previous
//
#include <hip/hip_runtime.h>
#include <hip/hip_bf16.h>

#define C_ 256
#define G_ 4

typedef __attribute__((ext_vector_type(8))) short bf16x8;
typedef __attribute__((ext_vector_type(4))) float f32x4;

static __device__ __forceinline__ unsigned short f2bf(float x) {
    __hip_bfloat16 h = __float2bfloat16(x);
    return *(unsigned short*)&h;
}
static __device__ __forceinline__ float bf2f(unsigned short u) {
    return __uint_as_float((unsigned)u << 16);
}
static __device__ __forceinline__ float4 bf4(ushort4 u) {
    float4 r;
    r.x = bf2f(u.x);
    r.y = bf2f(u.y);
    r.z = bf2f(u.z);
    r.w = bf2f(u.w);
    return r;
}

// ---------------------------------------------------------------- prep ----
__global__ void k_prep(const float* __restrict__ off_w, const float* __restrict__ dwh,
                       const float* __restrict__ dwm, const float* __restrict__ dwl,
                       unsigned short* __restrict__ wmf, float* __restrict__ dwt,
                       float* __restrict__ zeros) {
    int i = blockIdx.x * 256 + threadIdx.x;
    const int NWM = 4 * 32 * 576;
    if (i < NWM) {
        int g = i / (32 * 576), rem = i % (32 * 576);
        int ol = rem / 576, kk = rem % 576;
        int tap = kk / 64, ic = kk % 64;
        float v = (ol < 27) ? off_w[((size_t)((g * 27 + ol) * 64 + ic)) * 9 + tap] : 0.f;
        wmf[i] = f2bf(v);
    }
    int j = i - NWM;
    if (j >= 0 && j < 3 * 2304) {
        int which = j / 2304, rem = j % 2304;
        int t = rem / 256, c = rem % 256;
        const float* src = (which == 0) ? dwh : (which == 1) ? dwm : dwl;
        dwt[j] = src[c * 9 + t];
    }
    int z = i - NWM - 3 * 2304;
    if (z >= 0 && z < 8064) zeros[z] = 0.f;
}

// ------------------------------------------------------------ transpose ----
__global__ __launch_bounds__(256) void k_transpose(const float* __restrict__ x,
                                                   unsigned short* __restrict__ xtb, int H,
                                                   int W) {
    __shared__ float tile[32][33];
    int nh = blockIdx.x;
    int n = nh / H, h = nh % H;
    int w0 = blockIdx.y * 32, c0 = blockIdx.z * 32;
    int tid = threadIdx.x;
    int i = tid / 32, j = tid % 32;
#pragma unroll
    for (int r = 0; r < 4; r++) {
        int c = c0 + i + r * 8;
        int w = w0 + j;
        tile[i + r * 8][j] = (w < W) ? x[((size_t)(n * C_ + c) * H + h) * W + w] : 0.f;
    }
    __syncthreads();
    int wj = tid >> 4, ci2 = (tid & 15) * 2;
#pragma unroll
    for (int r = 0; r < 2; r++) {
        int w = w0 + wj + r * 16;
        if (w < W) {
            ushort2 o;
            o.x = f2bf(tile[ci2][wj + r * 16]);
            o.y = f2bf(tile[ci2 + 1][wj + r * 16]);
            *(ushort2*)(xtb + ((size_t)(n * H + h) * W + w) * C_ + c0 + ci2) = o;
        }
    }
}

// -------------------------------------------------------- depthwise+SiLU ----
__global__ __launch_bounds__(256) void k_dw_silu(const unsigned short* __restrict__ xtb,
                                                 const float* __restrict__ wdt,
                                                 const float* __restrict__ sc,
                                                 const float* __restrict__ bi,
                                                 unsigned short* __restrict__ out, int H,
                                                 int W) {
    int tid = threadIdx.x;
    int pw = tid >> 6, lane = tid & 63;
    int ch4 = lane << 2;
    int pix = blockIdx.x * 4 + pw;
    int w = pix % W, h = (pix / W) % H, n = pix / (W * H);
    const float4 s4 = *(const float4*)(sc + ch4);
    const float4 b4 = *(const float4*)(bi + ch4);
    const unsigned short* xb = xtb + (size_t)n * H * W * C_ + ch4;
    float4 acc = {0.f, 0.f, 0.f, 0.f};
#pragma unroll
    for (int t = 0; t < 9; t++) {
        int hh = h + t / 3 - 1, ww = w + t % 3 - 1;
        if (hh >= 0 && hh < H && ww >= 0 && ww < W) {
            float4 wt = *(const float4*)(wdt + t * 256 + ch4);
            float4 xv = bf4(*(const ushort4*)(xb + (size_t)(hh * W + ww) * C_));
            acc.x += wt.x * xv.x;
            acc.y += wt.y * xv.y;
            acc.z += wt.z * xv.z;
            acc.w += wt.w * xv.w;
        }
    }
    float4 y;
    y.x = acc.x * s4.x + b4.x;
    y.y = acc.y * s4.y + b4.y;
    y.z = acc.z * s4.z + b4.z;
    y.w = acc.w * s4.w + b4.w;
    y.x = y.x / (1.f + __expf(-y.x));
    y.y = y.y / (1.f + __expf(-y.y));
    y.z = y.z / (1.f + __expf(-y.z));
    y.w = y.w / (1.f + __expf(-y.w));
    ushort4 o;
    o.x = f2bf(y.x);
    o.y = f2bf(y.y);
    o.z = f2bf(y.z);
    o.w = f2bf(y.w);
    *(ushort4*)(out + (size_t)pix * C_ + ch4) = o;
}

// ------------------------------------------------- grouped offset/mask conv ----
// Per-group GEMM block: one (n, g, tile). Writes raw conv to OM[g][n][pix][28].
template <int STRIDE, int TH, int TW>
__global__ __launch_bounds__(256) void k_offmask(const unsigned short* __restrict__ dwb,
                                                 const unsigned short* __restrict__ wmf,
                                                 float* __restrict__ om,
                                                 int Hs, int Ws, int Ho, int Wo) {
    constexpr int SR = STRIDE * (TH - 1) + 3;
    constexpr int SC = STRIDE * (TW - 1) + 3;
    constexpr int NV = SR * SC;
    constexpr int CP = 72;  // bf16 pitch per pixel (64 ch + pad), 144 B
    constexpr int TP = TH * TW;
    constexpr int NTILES = TP / 8;  // 2 m-tiles x TP/16 n-tiles
    constexpr int PATCH_B = NV * CP * 2;
    constexpr int OMV_B = TP * 28 * 4;
    constexpr int LDS_B = PATCH_B > OMV_B ? PATCH_B : OMV_B;
    __shared__ __align__(16) char smem[LDS_B];
    unsigned short* patch = (unsigned short*)smem;
    float* omv = (float*)smem;

    int tid = threadIdx.x;
    int wv = tid >> 6, lane = tid & 63;
    int n16 = lane & 15, q = lane >> 4;
    int bx = blockIdx.x;
    int n = bx >> 2, g = bx & 3;
    int ho0 = blockIdx.y * TH, wo0 = blockIdx.z * TW;
    int hs0 = ho0 * STRIDE - 1, ws0 = wo0 * STRIDE - 1;
    int HoWo = Ho * Wo;

    // stage this group's 64 channels of the halo patch
    for (int idx = tid; idx < NV * 8; idx += 256) {
        int pp = idx >> 3;
        int c8 = (idx & 7) << 3;
        int hh = hs0 + pp / SC, ww = ws0 + pp % SC;
        uint4 v = {0u, 0u, 0u, 0u};
        if (hh >= 0 && hh < Hs && ww >= 0 && ww < Ws)
            v = *(const uint4*)(dwb + ((size_t)(n * Hs + hh) * Ws + ww) * C_ + g * 64 + c8);
        *(uint4*)(patch + pp * CP + c8) = v;
    }
    __syncthreads();

    int bchan = q << 3;
    const unsigned short* wg = wmf + (size_t)g * 32 * 576;

    if constexpr (NTILES >= 8) {
        // 8x8 tile: wave = one n-tile, both m-tiles (shared B)
        int ntile = wv;
        int p = ntile * 16 + n16;
        int pr = p / TW, pc = p % TW;
        int pixbase = (pr * STRIDE) * SC + pc * STRIDE;
        f32x4 a0 = {0.f, 0.f, 0.f, 0.f}, a1 = {0.f, 0.f, 0.f, 0.f};
        for (int kk = 0; kk < 18; kk++) {
            int tap = kk >> 1;
            int ic0 = (kk & 1) << 5;
            int ppix = pixbase + (tap / 3) * SC + tap % 3;
            bf16x8 b = *(const bf16x8*)(patch + ppix * CP + ic0 + bchan);
            bf16x8 wa0 = *(const bf16x8*)(wg + (size_t)n16 * 576 + kk * 32 + bchan);
            bf16x8 wa1 = *(const bf16x8*)(wg + (size_t)(16 + n16) * 576 + kk * 32 + bchan);
            a0 = __builtin_amdgcn_mfma_f32_16x16x32_bf16(wa0, b, a0, 0, 0, 0);
            a1 = __builtin_amdgcn_mfma_f32_16x16x32_bf16(wa1, b, a1, 0, 0, 0);
        }
        __syncthreads();
#pragma unroll
        for (int r = 0; r < 4; r++) {
            int ol0 = q * 4 + r;
            omv[p * 28 + ol0] = a0[r];
            int ol1 = 16 + q * 4 + r;
            if (ol1 < 28) omv[p * 28 + ol1] = a1[r];
        }
    } else {
        int t = wv;
        bool active = t < NTILES;
        int ntile = t >> 1, mtile = t & 1;
        int p = ntile * 16 + n16;
        int pr = p / TW, pc = p % TW;
        int pixbase = (pr * STRIDE) * SC + pc * STRIDE;
        f32x4 acc = {0.f, 0.f, 0.f, 0.f};
        if (active) {
            for (int kk = 0; kk < 18; kk++) {
                int tap = kk >> 1;
                int ic0 = (kk & 1) << 5;
                int ppix = pixbase + (tap / 3) * SC + tap % 3;
                bf16x8 b = *(const bf16x8*)(patch + ppix * CP + ic0 + bchan);
                bf16x8 wa = *(const bf16x8*)(wg + (size_t)(mtile * 16 + n16) * 576 +
                                             kk * 32 + bchan);
                acc = __builtin_amdgcn_mfma_f32_16x16x32_bf16(wa, b, acc, 0, 0, 0);
            }
        }
        __syncthreads();
        if (active) {
#pragma unroll
            for (int r = 0; r < 4; r++) {
                int ol = mtile * 16 + q * 4 + r;
                if (ol < 28) omv[p * 28 + ol] = acc[r];
            }
        }
    }
    __syncthreads();

    // coalesced OM write: per pixel 28 floats (27 used) at [g][n][pixn][28]
    float* omg = om + ((size_t)(g * 4 + n)) * HoWo * 28;
    for (int idx = tid; idx < TP * 7; idx += 256) {
        int p = idx / 7, c4 = idx % 7;
        int ho = ho0 + p / TW, wo = wo0 + p % TW;
        int pixn = ho * Wo + wo;
        *(float4*)(omg + (size_t)pixn * 28 + c4 * 4) = *(float4*)(omv + p * 28 + c4 * 4);
    }
}

// ------------------------------------------------------------- DCNv3 sample ----
// Stages raw conv OM + bias, computes softmax/sigmoid + bilinear meta in LDS,
// then gathers bf16 source. XCD band swizzle for L2 locality.
__global__ __launch_bounds__(256) void k_sample(const unsigned short* __restrict__ xtb,
                                                const float* __restrict__ om,
                                                const float* __restrict__ bias,
                                                float* __restrict__ raw,
                                                float* __restrict__ stats,
                                                int Hs, int Ws, int Wo, int HoWo,
                                                int stride, int softmax) {
    int tid = threadIdx.x;
    int wv = tid >> 6, lane = tid & 63;
    int g = lane >> 4;
    int ch4 = lane << 2;
    int nb = gridDim.x;
    int per = nb >> 3, rem = nb & 7;
    int xcd = blockIdx.x & 7, bi = blockIdx.x >> 3;
    int logical = xcd * per + min(xcd, rem) + bi;
    int pix0 = logical * 8;
    int n = pix0 / HoWo;
    int pixn0 = pix0 - n * HoWo;

    __shared__ float lom[8 * 112];
    __shared__ float lb[108];
    __shared__ float sm[32][9];
    __shared__ float4 lw[288];
    __shared__ ushort4 li[288];
    __shared__ float lstat[32];

    // stage OM: 4 group chunks x 8 pixels x 28 floats
    if (tid < 224) {
        int gc = tid / 56, r2 = tid % 56;
        int pp = r2 / 7, c4 = r2 % 7;
        float4 v = *(const float4*)(om + ((size_t)(gc * 4 + n) * HoWo + pixn0 + pp) * 28 +
                                    c4 * 4);
        ((float4*)lom)[pp * 28 + gc * 7 + c4] = v;
    }
    if (tid < 108) lb[tid] = bias[tid];
    if (tid < 32) lstat[tid] = 0.f;
    __syncthreads();

    // masks (softmax / sigmoid) per (pixel, sampling group)
    if (tid < 32) {
        int pp = tid >> 2, gs = tid & 3;
        float mv[9];
#pragma unroll
        for (int k = 0; k < 9; k++) {
            int ch = 72 + gs * 9 + k;
            int gc = ch / 27;
            mv[k] = lom[pp * 112 + gc * 28 + (ch - gc * 27)] + lb[ch];
        }
        if (softmax) {
            float mx = -1e30f;
#pragma unroll
            for (int k = 0; k < 9; k++) mx = fmaxf(mx, mv[k]);
            float ssum = 0.f;
#pragma unroll
            for (int k = 0; k < 9; k++) {
                mv[k] = __expf(mv[k] - mx);
                ssum += mv[k];
            }
            float inv = 1.f / ssum;
#pragma unroll
            for (int k = 0; k < 9; k++) sm[tid][k] = mv[k] * inv;
        } else {
#pragma unroll
            for (int k = 0; k < 9; k++) sm[tid][k] = 1.f / (1.f + __expf(-mv[k]));
        }
    }
    __syncthreads();

    // bilinear weights + clamped indices per (pixel, group, tap)
    for (int idx = tid; idx < 288; idx += 256) {
        int pg = idx / 9, k = idx % 9;
        int pp = pg >> 2, gs = pg & 3;
        int chy = gs * 18 + 2 * k, chx = chy + 1;
        int gcy = chy / 27, gcx = chx / 27;
        float oy = lom[pp * 112 + gcy * 28 + (chy - gcy * 27)] + lb[chy];
        float ox = lom[pp * 112 + gcx * 28 + (chx - gcx * 27)] + lb[chx];
        int pixn = pixn0 + pp;
        int ho = pixn / Wo, wo = pixn % Wo;
        float py = (float)(ho * stride + k / 3 - 1) + oy;
        float px = (float)(wo * stride + k % 3 - 1) + ox;
        float y0f = floorf(py), x0f = floorf(px);
        int y0 = (int)y0f, x0 = (int)x0f;
        float wy = py - y0f, wx = px - x0f;
        int y1 = y0 + 1, x1 = x0 + 1;
        float v0y = (y0 >= 0 && y0 < Hs) ? 1.f : 0.f;
        float v1y = (y1 >= 0 && y1 < Hs) ? 1.f : 0.f;
        float v0x = (x0 >= 0 && x0 < Ws) ? 1.f : 0.f;
        float v1x = (x1 >= 0 && x1 < Ws) ? 1.f : 0.f;
        int y0c = min(max(y0, 0), Hs - 1), y1c = min(max(y1, 0), Hs - 1);
        int x0c = min(max(x0, 0), Ws - 1), x1c = min(max(x1, 0), Ws - 1);
        float m_ = sm[pg][k];
        float4 w4;
        w4.x = (1.f - wy) * (1.f - wx) * v0y * v0x * m_;
        w4.y = (1.f - wy) * wx * v0y * v1x * m_;
        w4.z = wy * (1.f - wx) * v1y * v0x * m_;
        w4.w = wy * wx * v1y * v1x * m_;
        ushort4 i4;
        i4.x = (unsigned short)(y0c * Ws + x0c);
        i4.y = (unsigned short)(y0c * Ws + x1c);
        i4.z = (unsigned short)(y1c * Ws + x0c);
        i4.w = (unsigned short)(y1c * Ws + x1c);
        lw[pp * 36 + gs * 9 + k] = w4;
        li[pp * 36 + gs * 9 + k] = i4;
    }
    __syncthreads();

    int pA = wv * 2, pB = wv * 2 + 1;
    const unsigned short* xb = xtb + (size_t)n * Hs * Ws * C_ + ch4;
    float4 aA = {0.f, 0.f, 0.f, 0.f}, aB = {0.f, 0.f, 0.f, 0.f};
#pragma unroll
    for (int k = 0; k < 9; k++) {
        float4 wA = lw[pA * 36 + g * 9 + k];
        ushort4 iA = li[pA * 36 + g * 9 + k];
        float4 wB = lw[pB * 36 + g * 9 + k];
        ushort4 iB = li[pB * 36 + g * 9 + k];
        float4 vA0 = bf4(*(const ushort4*)(xb + ((size_t)iA.x << 8)));
        float4 vA1 = bf4(*(const ushort4*)(xb + ((size_t)iA.y << 8)));
        float4 vA2 = bf4(*(const ushort4*)(xb + ((size_t)iA.z << 8)));
        float4 vA3 = bf4(*(const ushort4*)(xb + ((size_t)iA.w << 8)));
        float4 vB0 = bf4(*(const ushort4*)(xb + ((size_t)iB.x << 8)));
        float4 vB1 = bf4(*(const ushort4*)(xb + ((size_t)iB.y << 8)));
        float4 vB2 = bf4(*(const ushort4*)(xb + ((size_t)iB.z << 8)));
        float4 vB3 = bf4(*(const ushort4*)(xb + ((size_t)iB.w << 8)));
        aA.x += wA.x * vA0.x + wA.y * vA1.x + wA.z * vA2.x + wA.w * vA3.x;
        aA.y += wA.x * vA0.y + wA.y * vA1.y + wA.z * vA2.y + wA.w * vA3.y;
        aA.z += wA.x * vA0.z + wA.y * vA1.z + wA.z * vA2.z + wA.w * vA3.z;
        aA.w += wA.x * vA0.w + wA.y * vA1.w + wA.z * vA2.w + wA.w * vA3.w;
        aB.x += wB.x * vB0.x + wB.y * vB1.x + wB.z * vB2.x + wB.w * vB3.x;
        aB.y += wB.x * vB0.y + wB.y * vB1.y + wB.z * vB2.y + wB.w * vB3.y;
        aB.z += wB.x * vB0.z + wB.y * vB1.z + wB.z * vB2.z + wB.w * vB3.z;
        aB.w += wB.x * vB0.w + wB.y * vB1.w + wB.z * vB2.w + wB.w * vB3.w;
    }
    *(float4*)(raw + (size_t)(pix0 + pA) * C_ + ch4) = aA;
    *(float4*)(raw + (size_t)(pix0 + pB) * C_ + ch4) = aB;
    float gs = aA.x + aA.y + aA.z + aA.w + aB.x + aB.y + aB.z + aB.w;
    float gss = aA.x * aA.x + aA.y * aA.y + aA.z * aA.z + aA.w * aA.w + aB.x * aB.x +
                aB.y * aB.y + aB.z * aB.z + aB.w * aB.w;
#pragma unroll
    for (int o = 2; o; o >>= 1) {
        gs += __shfl_down(gs, o, 4);
        gss += __shfl_down(gss, o, 4);
    }
    if ((lane & 3) == 0) {
        atomicAdd(&lstat[(lane >> 2) * 2 + 0], gs);
        atomicAdd(&lstat[(lane >> 2) * 2 + 1], gss);
    }
    __syncthreads();
    if (tid < 32) atomicAdd(&stats[n * 32 + tid], lstat[tid]);
}

// ----------------------------------------- GN affine (+bilinear up) + ch-means ----
__global__ __launch_bounds__(256) void k_gnup(const float* __restrict__ raw,
                                              float* __restrict__ fin,
                                              const float* __restrict__ stats,
                                              float* __restrict__ cmean,
                                              const float* __restrict__ gamma,
                                              const float* __restrict__ beta,
                                              int Hr, int Wr, int Hf, int Wf) {
    int HWf = Hf * Wf;
    int spn = (HWf + 63) >> 6;
    int n = blockIdx.x / spn;
    int p0 = (blockIdx.x % spn) << 6;
    int tid = threadIdx.x;
    int wv = tid >> 6, lane = tid & 63;
    int ch4 = lane << 2;
    int gg = lane >> 2;
    float cnt = 16.f * Hr * Wr;
    float s1 = stats[(n * 16 + gg) * 2], s2 = stats[(n * 16 + gg) * 2 + 1];
    float mu = s1 / cnt;
    float var = s2 / cnt - mu * mu;
    float rs = rsqrtf(var + 1e-5f);
    float4 g4 = *(const float4*)(gamma + ch4);
    float4 b4 = *(const float4*)(beta + ch4);
    float4 ga, be;
    ga.x = g4.x * rs; be.x = b4.x - mu * ga.x;
    ga.y = g4.y * rs; be.y = b4.y - mu * ga.y;
    ga.z = g4.z * rs; be.z = b4.z - mu * ga.z;
    ga.w = g4.w * rs; be.w = b4.w - mu * ga.w;
    bool up = (Hf != Hr);
    float sys = up ? (float)((double)(Hr - 1) / (double)(Hf - 1)) : 0.f;
    float sxs = up ? (float)((double)(Wr - 1) / (double)(Wf - 1)) : 0.f;
    float4 csum = {0.f, 0.f, 0.f, 0.f};
    __shared__ float cs[4][256];
    const float* rb = raw + (size_t)n * Hr * Wr * C_ + ch4;
    for (int i = wv; i < 64; i += 4) {
        int p = p0 + i;
        if (p < HWf) {
            float4 v;
            if (up) {
                int ho = p / Wf, wo = p % Wf;
                float sy = ho * sys, sx = wo * sxs;
                int y0 = (int)sy, x0 = (int)sx;
                float fy = sy - y0, fx = sx - x0;
                int y1 = min(y0 + 1, Hr - 1), x1 = min(x0 + 1, Wr - 1);
                float4 v00 = *(const float4*)(rb + (size_t)(y0 * Wr + x0) * C_);
                float4 v01 = *(const float4*)(rb + (size_t)(y0 * Wr + x1) * C_);
                float4 v10 = *(const float4*)(rb + (size_t)(y1 * Wr + x0) * C_);
                float4 v11 = *(const float4*)(rb + (size_t)(y1 * Wr + x1) * C_);
                v.x = (v00.x * (1.f - fy) + v10.x * fy) * (1.f - fx) + (v01.x * (1.f - fy) + v11.x * fy) * fx;
                v.y = (v00.y * (1.f - fy) + v10.y * fy) * (1.f - fx) + (v01.y * (1.f - fy) + v11.y * fy) * fx;
                v.z = (v00.z * (1.f - fy) + v10.z * fy) * (1.f - fx) + (v01.z * (1.f - fy) + v11.z * fy) * fx;
                v.w = (v00.w * (1.f - fy) + v10.w * fy) * (1.f - fx) + (v01.w * (1.f - fy) + v11.w * fy) * fx;
            } else {
                v = *(const float4*)(raw + ((size_t)n * HWf + p) * C_ + ch4);
            }
            float4 y4;
            y4.x = v.x * ga.x + be.x;
            y4.y = v.y * ga.y + be.y;
            y4.z = v.z * ga.z + be.z;
            y4.w = v.w * ga.w + be.w;
            *(float4*)(fin + ((size_t)n * HWf + p) * C_ + ch4) = y4;
            csum.x += y4.x; csum.y += y4.y; csum.z += y4.z; csum.w += y4.w;
        }
    }
    cs[wv][ch4 + 0] = csum.x;
    cs[wv][ch4 + 1] = csum.y;
    cs[wv][ch4 + 2] = csum.z;
    cs[wv][ch4 + 3] = csum.w;
    __syncthreads();
    if (wv == 0) {
        float t0 = 0.f, t1 = 0.f, t2 = 0.f, t3 = 0.f;
#pragma unroll
        for (int r = 0; r < 4; r++) {
            t0 += cs[r][ch4 + 0];
            t1 += cs[r][ch4 + 1];
            t2 += cs[r][ch4 + 2];
            t3 += cs[r][ch4 + 3];
        }
        atomicAdd(&cmean[n * C_ + ch4 + 0], t0);
        atomicAdd(&cmean[n * C_ + ch4 + 1], t1);
        atomicAdd(&cmean[n * C_ + ch4 + 2], t2);
        atomicAdd(&cmean[n * C_ + ch4 + 3], t3);
    }
}

// ------------------------- per-(n,level) scale-attn + DyReLU coefficients ----
__global__ __launch_bounds__(256) void k_coef(const float* __restrict__ cmA,
                                              const float* __restrict__ cmB,
                                              const float* __restrict__ cmC,
                                              int nf, float inv_nl, float inv_hw,
                                              const float* __restrict__ sa_w,
                                              const float* __restrict__ sa_b,
                                              const float* __restrict__ fc1_w,
                                              const float* __restrict__ fc1_b,
                                              const float* __restrict__ fc2_w,
                                              const float* __restrict__ fc2_b,
                                              float* __restrict__ coef,
                                              float* __restrict__ af) {
    int n = blockIdx.x;
    int c = threadIdx.x;
    __shared__ float red[256];
    __shared__ float meanv[256];
    __shared__ float hv[64];
    __shared__ float sa_a[3];
    const float* cms[3] = {cmA, cmB, cmC};
    float cm[3] = {0.f, 0.f, 0.f};
    for (int f = 0; f < nf; f++) {
        cm[f] = cms[f][n * C_ + c] * inv_hw;
        red[c] = sa_w[c] * cm[f];
        __syncthreads();
        for (int s = 128; s; s >>= 1) {
            if (c < s) red[c] += red[c + s];
            __syncthreads();
        }
        if (c == 0) {
            float t = fmaxf(red[0] + sa_b[0], 0.f);
            sa_a[f] = fminf(fmaxf((t + 3.f) * (1.f / 6.f), 0.f), 1.f);
        }
        __syncthreads();
    }
    float mv = 0.f;
    for (int f = 0; f < nf; f++) mv += sa_a[f] * cm[f];
    mv *= inv_nl;
    meanv[c] = mv;
    __syncthreads();
    int j = c >> 2, t = c & 3;
    float partial = 0.f;
    for (int k = t * 64; k < t * 64 + 64; k++) partial += fc1_w[j * 256 + k] * meanv[k];
    partial += __shfl_down(partial, 2, 4);
    partial += __shfl_down(partial, 1, 4);
    if (t == 0) hv[j] = fmaxf(partial + fc1_b[j], 0.f);
    __syncthreads();
    float zz[4];
#pragma unroll
    for (int i = 0; i < 4; i++) {
        float z = fc2_b[i * 256 + c];
        for (int k = 0; k < 64; k++) z += fc2_w[(size_t)(i * 256 + c) * 64 + k] * hv[k];
        zz[i] = fminf(fmaxf(z + 3.f, 0.f), 6.f) * (1.f / 6.f);
    }
    coef[n * 1024 + 0 * 256 + c] = (zz[0] - 0.5f) * 2.f + 1.f;
    coef[n * 1024 + 1 * 256 + c] = zz[1] - 0.5f;
    coef[n * 1024 + 2 * 256 + c] = (zz[2] - 0.5f) * 2.f;
    coef[n * 1024 + 3 * 256 + c] = zz[3] - 0.5f;
    if (c < 4) af[n * 4 + c] = (c < nf) ? sa_a[c] * inv_nl : 0.f;
}

// ------------------- streaming combine + DyReLU + NHWC->NCHW store ----
__global__ __launch_bounds__(256) void k_store(const float* __restrict__ fA,
                                               const float* __restrict__ fB,
                                               const float* __restrict__ fC,
                                               int nf, const float* __restrict__ coef,
                                               const float* __restrict__ af,
                                               float* __restrict__ out, int HW) {
    __shared__ float tile[64][65];
    int n = blockIdx.x;
    int pt = blockIdx.y;
    int c0 = blockIdx.z * 64;
    int tid = threadIdx.x;
    int lane16 = tid & 15, prow = tid >> 4;
    int ch4 = c0 + lane16 * 4;
    float a0 = af[n * 4 + 0], a1f = af[n * 4 + 1], a2f = af[n * 4 + 2];
    float4 ca1 = *(const float4*)(coef + n * 1024 + 0 + ch4);
    float4 cb1 = *(const float4*)(coef + n * 1024 + 256 + ch4);
    float4 ca2 = *(const float4*)(coef + n * 1024 + 512 + ch4);
    float4 cb2 = *(const float4*)(coef + n * 1024 + 768 + ch4);
#pragma unroll
    for (int pass = 0; pass < 4; pass++) {
        int px = pass * 16 + prow;
        int p = pt * 64 + px;
        if (p < HW) {
            size_t base = ((size_t)n * HW + p) * C_ + ch4;
            float4 v = *(const float4*)(fA + base);
            float4 fv;
            fv.x = v.x * a0;
            fv.y = v.y * a0;
            fv.z = v.z * a0;
            fv.w = v.w * a0;
            if (nf > 1) {
                float4 vb = *(const float4*)(fB + base);
                fv.x += vb.x * a1f;
                fv.y += vb.y * a1f;
                fv.z += vb.z * a1f;
                fv.w += vb.w * a1f;
            }
            if (nf > 2) {
                float4 vc = *(const float4*)(fC + base);
                fv.x += vc.x * a2f;
                fv.y += vc.y * a2f;
                fv.z += vc.z * a2f;
                fv.w += vc.w * a2f;
            }
            int cr = lane16 * 4;
            tile[cr + 0][px] = fmaxf(fv.x * ca1.x + cb1.x, fv.x * ca2.x + cb2.x);
            tile[cr + 1][px] = fmaxf(fv.y * ca1.y + cb1.y, fv.y * ca2.y + cb2.y);
            tile[cr + 2][px] = fmaxf(fv.z * ca1.z + cb1.z, fv.z * ca2.z + cb2.z);
            tile[cr + 3][px] = fmaxf(fv.w * ca1.w + cb1.w, fv.w * ca2.w + cb2.w);
        }
    }
    __syncthreads();
#pragma unroll
    for (int wp = 0; wp < 4; wp++) {
        int row = wp * 16 + (tid >> 4);
        int px4 = (tid & 15) * 4;
        int p = pt * 64 + px4;
        if (p < HW) {
            float4 r;
            r.x = tile[row][px4 + 0];
            r.y = tile[row][px4 + 1];
            r.z = tile[row][px4 + 2];
            r.w = tile[row][px4 + 3];
            *(float4*)(out + (size_t)(n * C_ + c0 + row) * HW + p) = r;
        }
    }
}

// --------------------------------------------------------------------- host ----
extern "C" void kernel_launch(void* const* d_in, const int* in_sizes, int n_in,
                              void* d_out, int out_size, void* d_ws, size_t ws_size,
                              hipStream_t stream) {
    (void)in_sizes; (void)n_in; (void)out_size; (void)ws_size;
    const float* x0 = (const float*)d_in[0];
    const float* x1 = (const float*)d_in[1];
    const float* x2 = (const float*)d_in[2];
    const float* dw_w_h = (const float*)d_in[3];
    const float* dw_s_h = (const float*)d_in[4];
    const float* dw_b_h = (const float*)d_in[5];
    const float* dw_w_m = (const float*)d_in[6];
    const float* dw_s_m = (const float*)d_in[7];
    const float* dw_b_m = (const float*)d_in[8];
    const float* dw_w_l = (const float*)d_in[9];
    const float* dw_s_l = (const float*)d_in[10];
    const float* dw_b_l = (const float*)d_in[11];
    const float* off_w = (const float*)d_in[12];
    const float* off_b = (const float*)d_in[13];
    const float* gn_g_h = (const float*)d_in[14];
    const float* gn_b_h = (const float*)d_in[15];
    const float* gn_g_m = (const float*)d_in[16];
    const float* gn_b_m = (const float*)d_in[17];
    const float* gn_g_l = (const float*)d_in[18];
    const float* gn_b_l = (const float*)d_in[19];
    const float* sa_w = (const float*)d_in[20];
    const float* sa_b = (const float*)d_in[21];
    const float* fc1_w = (const float*)d_in[22];
    const float* fc1_b = (const float*)d_in[23];
    const float* fc2_w = (const float*)d_in[24];
    const float* fc2_b = (const float*)d_in[25];

    float* ws = (float*)d_ws;
    unsigned short* XTB0 = (unsigned short*)(ws + 0);
    unsigned short* XTB1 = (unsigned short*)(ws + 3276800);
    unsigned short* XTB2 = (unsigned short*)(ws + 4096000);
    float* SH = ws + 4300800;      // 6553600 (bf16 dw out overlays / f32 raw)
    float* FINA = ws + 10854400;   // 6553600
    float* FINB = ws + 17408000;   // 6553600
    float* FINC = ws + 23961600;   // 1638400
    float* WMF = ws + 25600000;    // 36864
    float* DWT = ws + 25636864;    // 6912
    float* STATS = ws + 25643776;  // 896
    float* CMEAN = ws + 25644672;  // 7168
    float* COEF = ws + 25651840;   // 4096
    float* AF = ws + 25655936;     // 16

    unsigned short* SHB = (unsigned short*)SH;
    unsigned short* WMFB = (unsigned short*)WMF;

    float* out0 = (float*)d_out;
    float* out1 = out0 + 6553600;
    float* out2 = out0 + 8192000;

    // raw conv scratch carved from not-yet-written outputs: [g][n][pix][28]
    float* OM0 = out0;  // 16*6400*28 = 2867200 <= 6553600
    float* OM1 = out1;  // 16*1600*28 = 716800 <= 1638400
    float* OM2 = out2;  // 16*400*28  = 179200 <= 409600

    k_prep<<<(4 * 32 * 576 + 6912 + 8064 + 255) / 256, 256, 0, stream>>>(
        off_w, dw_w_h, dw_w_m, dw_w_l, WMFB, DWT, STATS);

    k_transpose<<<dim3(4 * 80, 3, 8), 256, 0, stream>>>(x0, XTB0, 80, 80);
    k_transpose<<<dim3(4 * 40, 2, 8), 256, 0, stream>>>(x1, XTB1, 40, 40);
    k_transpose<<<dim3(4 * 20, 1, 8), 256, 0, stream>>>(x2, XTB2, 20, 20);

    auto run_feat = [&](const unsigned short* xtb, int Hs, int Ws, int stride, bool softmax,
                        const float* dwt, const float* dws, const float* dwb,
                        const float* gng, const float* gnb, int slot, float* fin, int Hf,
                        int Wf, float* om) {
        int Ho = Hs / stride, Wo = Ws / stride;
        k_dw_silu<<<4 * Hs * Ws / 4, 256, 0, stream>>>(xtb, dwt, dws, dwb, SHB, Hs, Ws);
        if (stride == 1) {
            if (Hs >= 80)
                k_offmask<1, 8, 8><<<dim3(16, Ho / 8, Wo / 8), 256, 0, stream>>>(
                    SHB, WMFB, om, Hs, Ws, Ho, Wo);
            else if (Hs >= 40)
                k_offmask<1, 4, 8><<<dim3(16, Ho / 4, Wo / 8), 256, 0, stream>>>(
                    SHB, WMFB, om, Hs, Ws, Ho, Wo);
            else
                k_offmask<1, 4, 4><<<dim3(16, Ho / 4, Wo / 4), 256, 0, stream>>>(
                    SHB, WMFB, om, Hs, Ws, Ho, Wo);
        } else {
            if (Hs >= 80)
                k_offmask<2, 4, 8><<<dim3(16, Ho / 4, Wo / 8), 256, 0, stream>>>(
                    SHB, WMFB, om, Hs, Ws, Ho, Wo);
            else
                k_offmask<2, 4, 4><<<dim3(16, Ho / 4, Wo / 4), 256, 0, stream>>>(
                    SHB, WMFB, om, Hs, Ws, Ho, Wo);
        }
        k_sample<<<4 * Ho * Wo / 8, 256, 0, stream>>>(xtb, om, off_b, SH,
                                                      STATS + slot * 128, Hs, Ws, Wo,
                                                      Ho * Wo, stride, softmax ? 1 : 0);
        int spn = (Hf * Wf + 63) / 64;
        k_gnup<<<4 * spn, 256, 0, stream>>>(SH, fin, STATS + slot * 128, CMEAN + slot * 1024,
                                            gng, gnb, Ho, Wo, Hf, Wf);
    };

    // ---- level 0 (80x80): mid(x0) + high(x1 up) ----
    run_feat(XTB0, 80, 80, 1, false, DWT + 1 * 2304, dw_s_m, dw_b_m, gn_g_m, gn_b_m, 0, FINA,
             80, 80, OM0);
    run_feat(XTB1, 40, 40, 1, true, DWT + 0 * 2304, dw_s_h, dw_b_h, gn_g_h, gn_b_h, 1, FINB,
             80, 80, OM0);
    k_coef<<<4, 256, 0, stream>>>(CMEAN, CMEAN + 1024, nullptr, 2, 0.5f, 1.f / 6400.f, sa_w,
                                  sa_b, fc1_w, fc1_b, fc2_w, fc2_b, COEF, AF);
    k_store<<<dim3(4, 100, 4), 256, 0, stream>>>(FINA, FINB, nullptr, 2, COEF, AF, out0,
                                                 6400);
    // ---- level 1 (40x40): mid(x1) + low(x0 s2) + high(x2 up) ----
    run_feat(XTB1, 40, 40, 1, false, DWT + 1 * 2304, dw_s_m, dw_b_m, gn_g_m, gn_b_m, 2, FINA,
             40, 40, OM1);
    run_feat(XTB0, 80, 80, 2, true, DWT + 2 * 2304, dw_s_l, dw_b_l, gn_g_l, gn_b_l, 3, FINB,
             40, 40, OM1);
    run_feat(XTB2, 20, 20, 1, true, DWT + 0 * 2304, dw_s_h, dw_b_h, gn_g_h, gn_b_h, 4, FINC,
             40, 40, OM1);
    k_coef<<<4, 256, 0, stream>>>(CMEAN + 2 * 1024, CMEAN + 3 * 1024, CMEAN + 4 * 1024, 3,
                                  1.f / 3.f, 1.f / 1600.f, sa_w, sa_b, fc1_w, fc1_b, fc2_w,
                                  fc2_b, COEF, AF);
    k_store<<<dim3(4, 25, 4), 256, 0, stream>>>(FINA, FINB, FINC, 3, COEF, AF, out1, 1600);
    // ---- level 2 (20x20): mid(x2) + low(x1 s2) ----
    run_feat(XTB2, 20, 20, 1, false, DWT + 1 * 2304, dw_s_m, dw_b_m, gn_g_m, gn_b_m, 5, FINA,
             20, 20, OM2);
    run_feat(XTB1, 40, 40, 2, true, DWT + 2 * 2304, dw_s_l, dw_b_l, gn_g_l, gn_b_l, 6, FINB,
             20, 20, OM2);
    k_coef<<<4, 256, 0, stream>>>(CMEAN + 5 * 1024, CMEAN + 6 * 1024, nullptr, 2, 0.5f,
                                  1.f / 400.f, sa_w, sa_b, fc1_w, fc1_b, fc2_w, fc2_b, COEF,
                                  AF);
    k_store<<<dim3(4, 7, 4), 256, 0, stream>>>(FINA, FINB, nullptr, 2, COEF, AF, out2, 400);
}